// Round 1
// baseline (1904.435 us; speedup 1.0000x reference)
//
#include <hip/hip_runtime.h>

// ---------------- problem constants ----------------
#define NPTS   100000
#define DIMD   256
#define BQ     256
#define KNB    16
#define NQROWS 4096
#define PCHUNK 128
#define NPCH   782           // ceil(100000/128)
#define NCAND  (NPCH*16)     // candidates per query for final merge
#define NS_ITERS 26
#define KSPLIT  32
#define KSLICE  3136         // 32*3136 = 100352 >= 100000

// scal[] slots
#define SC_LM   0
#define SC_TRCX 1
#define SC_TRCT 2
#define SC_FROB 3
#define SC_KNN  4
#define SC_REG  5
#define SC_LD   6

#define BIGF 3.4e38f

typedef __attribute__((ext_vector_type(4))) float f32x4;
typedef __attribute__((ext_vector_type(8))) unsigned short u16x8;
typedef __attribute__((ext_vector_type(8))) __bf16 bf16x8;

static __device__ __forceinline__ unsigned short f2bf(float f) {
    unsigned u = __float_as_uint(f);
    unsigned r = (u + 0x7fffu + ((u >> 16) & 1u)) >> 16;   // RNE
    return (unsigned short)r;
}
static __device__ __forceinline__ float bf2f(unsigned short h) {
    return __uint_as_float(((unsigned)h) << 16);
}
static __device__ __forceinline__ f32x4 mfma16(u16x8 a, u16x8 b, f32x4 c) {
    return __builtin_amdgcn_mfma_f32_16x16x32_bf16(
        __builtin_bit_cast(bf16x8, a), __builtin_bit_cast(bf16x8, b), c, 0, 0, 0);
}

// ---------------- zero init ----------------
__global__ __launch_bounds__(256) void zero_kernel(float* ws) {
    int idx = blockIdx.x * 256 + threadIdx.x;
    if (idx < 66560) ws[idx] = 0.0f;   // mu_sum + scal + pad + covX accumulator
}

// ---------------- X stats: column sums (for mu_X) + row sq-norms ----------------
__global__ __launch_bounds__(256) void statsx_kernel(const float* __restrict__ X,
                                                     float* __restrict__ xsq,
                                                     float* __restrict__ mu_sum) {
    int w    = threadIdx.x >> 6;   // wave 0..3
    int lane = threadIdx.x & 63;
    int rbase = blockIdx.x * 1024;
    float cs0 = 0.f, cs1 = 0.f, cs2 = 0.f, cs3 = 0.f;
    for (int m = 0; m < 256; ++m) {
        int r = rbase + w + 4 * m;
        if (r < NPTS) {
            float4 v = *(const float4*)&X[r * DIMD + 4 * lane];
            cs0 += v.x; cs1 += v.y; cs2 += v.z; cs3 += v.w;
            float ss = v.x * v.x + v.y * v.y + v.z * v.z + v.w * v.w;
            for (int off = 32; off; off >>= 1) ss += __shfl_down(ss, off);
            if (lane == 0) xsq[r] = ss;
        }
    }
    atomicAdd(&mu_sum[4 * lane + 0], cs0);
    atomicAdd(&mu_sum[4 * lane + 1], cs1);
    atomicAdd(&mu_sum[4 * lane + 2], cs2);
    atomicAdd(&mu_sum[4 * lane + 3], cs3);
}

// ---------------- covX accumulate: acc += X^T X over K-slice ----------------
__global__ __launch_bounds__(256) void covx_kernel(const float* __restrict__ X,
                                                   float* __restrict__ acc_out) {
    __shared__ float Ais[16][64];
    __shared__ float Ajs[16][64];
    int t = threadIdx.x;
    int i0 = blockIdx.x * 64, j0 = blockIdx.y * 64;
    int ks = blockIdx.z * KSLICE;
    int lr = t >> 4, lc = (t & 15) * 4;
    int tx = t & 15, ty = t >> 4;
    float acc[4][4] = {};
    for (int kb = 0; kb < KSLICE; kb += 16) {
        int k = ks + kb + lr;
        if (k < NPTS) {
            float4 vi = *(const float4*)&X[k * DIMD + i0 + lc];
            float4 vj = *(const float4*)&X[k * DIMD + j0 + lc];
            *(float4*)&Ais[lr][lc] = vi;
            *(float4*)&Ajs[lr][lc] = vj;
        } else {
            float4 z = {0.f, 0.f, 0.f, 0.f};
            *(float4*)&Ais[lr][lc] = z;
            *(float4*)&Ajs[lr][lc] = z;
        }
        __syncthreads();
#pragma unroll
        for (int kk = 0; kk < 16; ++kk) {
            float4 a = *(float4*)&Ais[kk][tx * 4];
            float4 b = *(float4*)&Ajs[kk][ty * 4];
            float av[4] = {a.x, a.y, a.z, a.w};
            float bv[4] = {b.x, b.y, b.z, b.w};
#pragma unroll
            for (int m = 0; m < 4; ++m)
#pragma unroll
                for (int n = 0; n < 4; ++n) acc[m][n] += av[m] * bv[n];
        }
        __syncthreads();
    }
#pragma unroll
    for (int m = 0; m < 4; ++m)
#pragma unroll
        for (int n = 0; n < 4; ++n)
            atomicAdd(&acc_out[(i0 + 4 * tx + m) * DIMD + j0 + 4 * ty + n], acc[m][n]);
}

// ---------------- covX finalize ----------------
__global__ __launch_bounds__(256) void covxfin_kernel(float* __restrict__ covX,
                                                      const float* __restrict__ mu_sum,
                                                      float* __restrict__ scal) {
    int idx = blockIdx.x * 256 + threadIdx.x;
    int i = idx >> 8, j = idx & 255;
    const float invN = 1.0f / (float)NPTS;
    float v = covX[idx] * invN - (mu_sum[i] * invN) * (mu_sum[j] * invN) + ((i == j) ? 1e-4f : 0.0f);
    covX[idx] = v;
    if (i == j) atomicAdd(&scal[SC_TRCX], v);
}

// ---------------- generic 256x256x256 matmul, 32x32 tiles ----------------
// mode 0: C = A@B
// mode 1: C = A@B, also atomicAdd sum(C^2) -> scal[SC_FROB]
// mode 2: C = (A^T@B)/256 - mu_i*mu_j + 1e-4*I, trace -> scal[SC_TRCT]
// mode 3: C = 1.5*D - 0.5*(A@B); with gridDim.z==2, z==1 uses (A2,B2,C2,D2)
__global__ __launch_bounds__(256) void mm32_kernel(const float* A, const float* B, float* C, const float* D,
                                                   const float* A2, const float* B2, float* C2, const float* D2,
                                                   int mode, const float* mu, float* scal) {
    if (mode == 3 && blockIdx.z == 1) { A = A2; B = B2; C = C2; D = D2; }
    __shared__ float As[32][32];
    __shared__ float Bs[32][32];
    __shared__ float red[256];
    int t = threadIdx.x;
    int tx = t & 15, ty = t >> 4;
    int i0 = blockIdx.x * 32, j0 = blockIdx.y * 32;
    int lr = t >> 3, lc = (t & 7) * 4;
    float acc[2][2] = {};
    for (int kb = 0; kb < 256; kb += 32) {
        if (mode == 2) {
            float4 v = *(const float4*)&A[(kb + lr) * DIMD + i0 + lc];
            *(float4*)&As[lr][lc] = v;
        } else {
            float4 v = *(const float4*)&A[(i0 + lr) * DIMD + kb + lc];
            As[lc + 0][lr] = v.x; As[lc + 1][lr] = v.y; As[lc + 2][lr] = v.z; As[lc + 3][lr] = v.w;
        }
        {
            float4 v = *(const float4*)&B[(kb + lr) * DIMD + j0 + lc];
            *(float4*)&Bs[lr][lc] = v;
        }
        __syncthreads();
#pragma unroll
        for (int kk = 0; kk < 32; ++kk) {
            float a0 = As[kk][2 * tx], a1 = As[kk][2 * tx + 1];
            float b0 = Bs[kk][2 * ty], b1 = Bs[kk][2 * ty + 1];
            acc[0][0] += a0 * b0; acc[0][1] += a0 * b1;
            acc[1][0] += a1 * b0; acc[1][1] += a1 * b1;
        }
        __syncthreads();
    }
    float fr = 0.f;
#pragma unroll
    for (int ii = 0; ii < 2; ++ii)
#pragma unroll
        for (int jj = 0; jj < 2; ++jj) {
            int i = i0 + 2 * tx + ii, j = j0 + 2 * ty + jj;
            float v = acc[ii][jj];
            if (mode == 2) {
                v = v * (1.0f / 256.0f) - mu[i] * mu[j] + ((i == j) ? 1e-4f : 0.0f);
                if (i == j) atomicAdd(&scal[SC_TRCT], v);
            } else if (mode == 3) {
                v = 1.5f * D[i * DIMD + j] - 0.5f * v;
            }
            C[i * DIMD + j] = v;
            if (mode == 1) fr += v * v;
        }
    if (mode == 1) {
        red[t] = fr; __syncthreads();
        for (int s2 = 128; s2 > 0; s2 >>= 1) { if (t < s2) red[t] += red[t + s2]; __syncthreads(); }
        if (t == 0) atomicAdd(&scal[SC_FROB], red[0]);
    }
}

// ---------------- T stats: mu_T + loss_mean ----------------
__global__ __launch_bounds__(256) void tstats_kernel(const float* __restrict__ Tm,
                                                     const float* __restrict__ mu_sum,
                                                     float* __restrict__ mu_T,
                                                     float* __restrict__ scal) {
    __shared__ float red[256];
    int j = threadIdx.x;
    float s = 0.f;
    for (int b = 0; b < BQ; ++b) s += Tm[b * DIMD + j];
    float mt = s * (1.0f / 256.0f);
    mu_T[j] = mt;
    float d = mt - mu_sum[j] * (1.0f / (float)NPTS);
    red[j] = d * d;
    __syncthreads();
    for (int s2 = 128; s2 > 0; s2 >>= 1) { if (j < s2) red[j] += red[j + s2]; __syncthreads(); }
    if (j == 0) scal[SC_LM] = red[0];
}

// ---------------- init Y = G/||G||_F, Z = I ----------------
__global__ __launch_bounds__(256) void inityz_kernel(const float* __restrict__ G,
                                                     const float* __restrict__ scal,
                                                     float* __restrict__ Y, float* __restrict__ Z) {
    int idx = blockIdx.x * 256 + threadIdx.x;
    float invs = rsqrtf(scal[SC_FROB]);   // 1/sqrt(sum G^2) = 1/||G||_F
    Y[idx] = G[idx] * invs;
    Z[idx] = ((idx >> 8) == (idx & 255)) ? 1.0f : 0.0f;
}

// ---------------- finalize loss_dist ----------------
__global__ __launch_bounds__(256) void findist_kernel(const float* __restrict__ Yfin,
                                                      float* __restrict__ scal) {
    __shared__ float red[256];
    int t = threadIdx.x;
    red[t] = Yfin[t * (DIMD + 1)];
    __syncthreads();
    for (int s2 = 128; s2 > 0; s2 >>= 1) { if (t < s2) red[t] += red[t + s2]; __syncthreads(); }
    if (t == 0) {
        float frobsq = scal[SC_FROB];
        float tr_sqrt = powf(frobsq, 0.25f) * red[0];   // sqrt(s)*trace(Y), s=sqrt(frobsq)
        float lc = scal[SC_TRCX] + scal[SC_TRCT] - 2.0f * tr_sqrt;
        scal[SC_LD] = fmaxf(0.0f, scal[SC_LM] + lc);
    }
}

// ---------------- reg: sum(W^2) ----------------
__global__ __launch_bounds__(256) void reg_kernel(const float* __restrict__ W, float* __restrict__ scal) {
    __shared__ float red[256];
    int t = threadIdx.x;
    float s = 0.f;
    int base = blockIdx.x * 1024;
    for (int m = 0; m < 4; ++m) { float w = W[base + m * 256 + t]; s += w * w; }
    red[t] = s;
    __syncthreads();
    for (int s2 = 128; s2 > 0; s2 >>= 1) { if (t < s2) red[t] += red[t + s2]; __syncthreads(); }
    if (t == 0) atomicAdd(&scal[SC_REG], red[0]);
}

// ---------------- KNN: MFMA split-bf16 GEMM + per-block top-16 ----------------
// Per block: 128 queries (blockIdx.y in {0,1}) x 128 points (blockIdx.x of NPCH).
// S = T @ X^T via 3-pass bf16 hi/lo MFMA (16x16x32): S ~ Ah*Bh + Ah*Bl + Al*Bh.
// Wave w owns queries q0 + w*16 .. +15; D-frag: col(point)=lane&15, row(query)=(lane>>4)*4+reg.
// LDS (50.7 KB): region0 = stage XH/XL[32][264] OVERLAID with kt[128][67]; region1 = tk/ti[16][128].
// Selection algorithm + ck/ci layout identical to the previous fp32 version (merge unchanged).

static __device__ __forceinline__ void knn_load(const float* __restrict__ X, int p0, int pc, int t,
                                                float4 s0[2], float4 s1[2]) {
#pragma unroll
    for (int rep = 0; rep < 2; ++rep) {
        int g = t + rep * 512;
        int row = g >> 5, c0 = (g & 31) * 8;
        int p = p0 + pc * 32 + row;
        if (p < NPTS) {
            s0[rep] = *(const float4*)&X[p * DIMD + c0];
            s1[rep] = *(const float4*)&X[p * DIMD + c0 + 4];
        } else {
            float4 z = {0.f, 0.f, 0.f, 0.f};
            s0[rep] = z; s1[rep] = z;
        }
    }
}

static __device__ __forceinline__ void knn_write(unsigned short* XH, unsigned short* XL, int t,
                                                 const float4 s0[2], const float4 s1[2]) {
#pragma unroll
    for (int rep = 0; rep < 2; ++rep) {
        int g = t + rep * 512;
        int row = g >> 5, c0 = (g & 31) * 8;
        float f[8] = {s0[rep].x, s0[rep].y, s0[rep].z, s0[rep].w,
                      s1[rep].x, s1[rep].y, s1[rep].z, s1[rep].w};
        u16x8 h, lo;
#pragma unroll
        for (int j = 0; j < 8; ++j) {
            unsigned short hb = f2bf(f[j]);
            h[j] = hb;
            lo[j] = f2bf(f[j] - bf2f(hb));
        }
        *(u16x8*)&XH[row * 264 + c0] = h;
        *(u16x8*)&XL[row * 264 + c0] = lo;
    }
}

__global__ __launch_bounds__(512, 2) void knn_kernel(const float* __restrict__ Tm,
                                                     const float* __restrict__ X,
                                                     const float* __restrict__ xsq,
                                                     float* __restrict__ ck, int* __restrict__ ci) {
    __shared__ __align__(16) unsigned char smem[50688];
    unsigned short* XH = (unsigned short*)smem;            // [32][264] bf16 hi
    unsigned short* XL = (unsigned short*)(smem + 16896);  // [32][264] bf16 lo
    float* ktf = (float*)smem;                             // [128][67] overlay (stage dead)
    float* tk  = (float*)(smem + 34304);                   // [16][128]
    int*   ti  = (int*)  (smem + 42496);                   // [16][128]

    const int t    = threadIdx.x;
    const int w    = t >> 6;        // wave 0..7
    const int lane = t & 63;
    const int l15  = lane & 15;
    const int l4   = lane >> 4;     // 0..3
    const int p0   = blockIdx.x * PCHUNK;
    const int q0   = blockIdx.y * 128;

    // --- A-fragments: T rows for this wave's 16 queries, converted to bf16 hi/lo ---
    u16x8 aH[8], aL[8];
    {
        const int q = q0 + w * 16 + l15;
        const float* tq = Tm + q * DIMD + l4 * 8;
#pragma unroll
        for (int ks = 0; ks < 8; ++ks) {
            float4 v0 = *(const float4*)(tq + ks * 32);
            float4 v1 = *(const float4*)(tq + ks * 32 + 4);
            float f[8] = {v0.x, v0.y, v0.z, v0.w, v1.x, v1.y, v1.z, v1.w};
            u16x8 h, lo;
#pragma unroll
            for (int j = 0; j < 8; ++j) {
                unsigned short hb = f2bf(f[j]);
                h[j] = hb;
                lo[j] = f2bf(f[j] - bf2f(hb));
            }
            aH[ks] = h; aL[ks] = lo;
        }
    }

    float worst = BIGF; int wslot = 0;   // selection state (t<128 threads)

    // --- stage pchunk 0 ---
    float4 s0[2], s1[2];
    knn_load(X, p0, 0, t, s0, s1);
    knn_write(XH, XL, t, s0, s1);

#pragma unroll
    for (int h = 0; h < 2; ++h) {
        f32x4 acc[4];
#pragma unroll
        for (int a2 = 0; a2 < 4; ++a2) { f32x4 z = {0.f, 0.f, 0.f, 0.f}; acc[a2] = z; }

#pragma unroll
        for (int pc2 = 0; pc2 < 2; ++pc2) {
            const int pc = 2 * h + pc2;
            __syncthreads();                      // staged pchunk pc visible
            if (pc < 3) knn_load(X, p0, pc + 1, t, s0, s1);   // prefetch next (hides HBM latency)
#pragma unroll
            for (int ks = 0; ks < 8; ++ks) {
#pragma unroll
                for (int pt = 0; pt < 2; ++pt) {
                    const int off = (pt * 16 + l15) * 264 + ks * 32 + l4 * 8;
                    u16x8 bh = *(const u16x8*)&XH[off];
                    u16x8 bl = *(const u16x8*)&XL[off];
                    acc[pc2 * 2 + pt] = mfma16(aH[ks], bh, acc[pc2 * 2 + pt]);
                    acc[pc2 * 2 + pt] = mfma16(aH[ks], bl, acc[pc2 * 2 + pt]);
                    acc[pc2 * 2 + pt] = mfma16(aL[ks], bh, acc[pc2 * 2 + pt]);
                }
            }
            __syncthreads();                      // all LDS reads of this pchunk done
            if (pc2 == 0 && pc < 3) knn_write(XH, XL, t, s0, s1);  // stage pc+1
        }

        // --- kt write for this half (64 points): overlays dead stage buffer ---
#pragma unroll
        for (int pc2 = 0; pc2 < 2; ++pc2) {
#pragma unroll
            for (int pt = 0; pt < 2; ++pt) {
                const int pl = pc2 * 32 + pt * 16 + l15;
                const int p  = p0 + h * 64 + pl;
                const float xv = (p < NPTS) ? xsq[p] : 0.f;
#pragma unroll
                for (int i = 0; i < 4; ++i) {
                    float key = (p < NPTS) ? (xv - 2.0f * acc[pc2 * 2 + pt][i]) : BIGF;
                    ktf[(w * 16 + l4 * 4 + i) * 67 + pl] = key;
                }
            }
        }
        __syncthreads();

        // --- per-query scan over this half's 64 candidates ---
        if (t < 128) {
            if (h == 0) {
#pragma unroll
                for (int s = 0; s < 16; ++s) { tk[s * 128 + t] = BIGF; ti[s * 128 + t] = 0x7fffffff; }
            }
            for (int c = 0; c < 64; ++c) {
                float key = ktf[t * 67 + c];
                if (key < worst) {
                    tk[wslot * 128 + t] = key; ti[wslot * 128 + t] = p0 + h * 64 + c;
                    worst = tk[t]; wslot = 0;
#pragma unroll
                    for (int s = 1; s < 16; ++s) {
                        float v = tk[s * 128 + t];
                        if (v > worst) { worst = v; wslot = s; }
                    }
                }
            }
        }
        __syncthreads();                          // scan done before region0 is re-staged
        if (h == 0) knn_write(XH, XL, t, s0, s1); // stage pchunk 2
    }

    if (t < 128) {
        int base = (q0 + t) * NCAND + blockIdx.x * 16;
        for (int s = 0; s < 16; ++s) { ck[base + s] = tk[s * 128 + t]; ci[base + s] = ti[s * 128 + t]; }
    }
}

// ---------------- global top-16 merge per query ----------------
__global__ __launch_bounds__(256) void merge_kernel(const float* __restrict__ ck,
                                                    const int* __restrict__ ci,
                                                    int* __restrict__ post_idx) {
    __shared__ float tk[16][256];
    __shared__ int   ti[16][256];
    __shared__ float rk[256];
    __shared__ int   ri[256];
    __shared__ int   rt2[256];
    __shared__ int   rs2[256];
    int q = blockIdx.x, t = threadIdx.x;
    for (int s = 0; s < 16; ++s) { tk[s][t] = BIGF; ti[s][t] = 0x7fffffff; }
    float worst = BIGF; int wslot = 0;
    for (int e = t; e < NCAND; e += 256) {
        float key = ck[q * NCAND + e];
        if (key < worst) {
            tk[wslot][t] = key; ti[wslot][t] = ci[q * NCAND + e];
            worst = tk[0][t]; wslot = 0;
            for (int s = 1; s < 16; ++s)
                if (tk[s][t] > worst) { worst = tk[s][t]; wslot = s; }
        }
    }
    __syncthreads();
    for (int r = 0; r < 16; ++r) {
        float bk = tk[0][t]; int bi = ti[0][t], bs = 0;
        for (int s = 1; s < 16; ++s) {
            float k2 = tk[s][t]; int i2 = ti[s][t];
            if (k2 < bk || (k2 == bk && i2 < bi)) { bk = k2; bi = i2; bs = s; }
        }
        rk[t] = bk; ri[t] = bi; rt2[t] = t; rs2[t] = bs;
        __syncthreads();
        for (int s2 = 128; s2 > 0; s2 >>= 1) {
            if (t < s2) {
                float ko = rk[t + s2]; int io = ri[t + s2];
                if (ko < rk[t] || (ko == rk[t] && io < ri[t])) {
                    rk[t] = ko; ri[t] = io; rt2[t] = rt2[t + s2]; rs2[t] = rs2[t + s2];
                }
            }
            __syncthreads();
        }
        if (t == rt2[0]) { tk[rs2[0]][t] = BIGF; ti[rs2[0]][t] = 0x7fffffff; }
        if (t == 0) post_idx[q * 16 + r] = ri[0];
        __syncthreads();
    }
}

// ---------------- exact l2 + softmax weights ----------------
__global__ __launch_bounds__(256) void l2sm_kernel(const float* __restrict__ Tm,
                                                   const float* __restrict__ X,
                                                   const int* __restrict__ post_idx,
                                                   float* __restrict__ post_w) {
    __shared__ float l2s[16];
    int b = blockIdx.x, t = threadIdx.x;
    int k = t >> 4, j = t & 15;
    int idx = post_idx[b * 16 + k];
    float s = 0.f;
    for (int i = 0; i < 16; ++i) {
        int d = j + 16 * i;
        float df = Tm[b * DIMD + d] - X[idx * DIMD + d];
        s += df * df;
    }
    for (int off = 8; off; off >>= 1) s += __shfl_down(s, off, 16);
    if (j == 0) l2s[k] = s;
    __syncthreads();
    if (t < 16) {
        float x = -l2s[t] * 10.0f;   // -l2 / TAU, TAU = 0.1
        float m = x;
        for (int mm = 8; mm; mm >>= 1) m = fmaxf(m, __shfl_xor(m, mm, 16));
        float e = expf(x - m);
        float ssum = e;
        for (int mm = 8; mm; mm >>= 1) ssum += __shfl_xor(ssum, mm, 16);
        post_w[b * 16 + t] = e / ssum;
    }
}

// ---------------- KL per sample (exact reference semantics) ----------------
__global__ __launch_bounds__(256) void kl_kernel(const int* __restrict__ q_indices,
                                                 const int* __restrict__ pre_indices,
                                                 const float* __restrict__ pre_weights,
                                                 const int* __restrict__ post_idx,
                                                 const float* __restrict__ post_w,
                                                 float* __restrict__ scal) {
    int b = threadIdx.x;
    int qi = q_indices[b];
    int pid[16]; float pw[16]; int sid[16]; float sw[16];
    for (int k = 0; k < 16; ++k) {
        pid[k] = pre_indices[qi * 16 + k];
        pw[k]  = pre_weights[qi * 16 + k];
        sid[k] = post_idx[b * 16 + k];
        sw[k]  = post_w[b * 16 + k];
    }
    float psum = 0.f, qsum = 0.f, kl = 0.f;
    for (int pass = 0; pass < 2; ++pass) {
        for (int i = 0; i < 32; ++i) {
            int c = (i < 16) ? pid[i] : sid[i - 16];
            bool first = true;
            for (int jj = 0; jj < i; ++jj) {
                int cj = (jj < 16) ? pid[jj] : sid[jj - 16];
                if (cj == c) { first = false; break; }
            }
            if (!first) continue;
            float p = 0.f, q = 0.f;
            for (int k2 = 0; k2 < 16; ++k2) {
                if (pid[k2] == c) p += pw[k2];
                if (sid[k2] == c) q += sw[k2];
            }
            p = fmaxf(p, 1e-8f); q = fmaxf(q, 1e-8f);
            if (pass == 0) { psum += p; qsum += q; }
            else {
                float pn = p / psum, qn = q / qsum;
                kl += pn * (logf(pn) - logf(qn));
            }
        }
    }
    atomicAdd(&scal[SC_KNN], kl * (1.0f / 256.0f));
}

// ---------------- final assembly ----------------
__global__ void assemble_kernel(const float* __restrict__ scal, float* __restrict__ out) {
    if (threadIdx.x == 0) {
        float ld = scal[SC_LD], lk = scal[SC_KNN], reg = scal[SC_REG];
        out[0] = ld + lk + 1e-4f * 0.5f * reg;
        out[1] = ld;
        out[2] = lk;
    }
}

extern "C" void kernel_launch(void* const* d_in, const int* in_sizes, int n_in,
                              void* d_out, int out_size, void* d_ws, size_t ws_size,
                              hipStream_t stream) {
    (void)in_sizes; (void)n_in; (void)out_size; (void)ws_size;
    const float* X           = (const float*)d_in[0];
    const float* W           = (const float*)d_in[1];
    const float* q_batch     = (const float*)d_in[2];
    const float* pre_weights = (const float*)d_in[3];
    const int*   q_indices   = (const int*)d_in[4];
    const int*   pre_indices = (const int*)d_in[5];
    float* out = (float*)d_out;
    float* ws  = (float*)d_ws;

    float* mu_sum = ws + 0;
    float* scal   = ws + 256;
    float* mu_T   = ws + 512;
    float* covX   = ws + 1024;
    float* Tm     = ws + 66560;
    float* cov    = ws + 132096;
    float* G      = ws + 197632;
    float* Ya     = ws + 263168;
    float* Za     = ws + 328704;
    float* Yb     = ws + 394240;
    float* Zb     = ws + 459776;
    float* P      = ws + 525312;
    float* xsq    = ws + 590848;
    float* post_w = ws + 691200;
    int*   post_idx = (int*)(ws + 695296);
    float* ck     = ws + 699392;
    int*   ci     = (int*)(ws + 3902464);

    // 0. zero accumulators (mu_sum, scal, covX)
    zero_kernel<<<260, 256, 0, stream>>>(ws);
    // reg term (independent)
    reg_kernel<<<64, 256, 0, stream>>>(W, scal);
    // 1. X stats
    statsx_kernel<<<98, 256, 0, stream>>>(X, xsq, mu_sum);
    // 2. covX
    covx_kernel<<<dim3(4, 4, KSPLIT), 256, 0, stream>>>(X, covX);
    covxfin_kernel<<<256, 256, 0, stream>>>(covX, mu_sum, scal);
    // 3. T = q_batch @ W
    mm32_kernel<<<dim3(8, 8, 1), 256, 0, stream>>>(q_batch, W, Tm, nullptr,
                                                   nullptr, nullptr, nullptr, nullptr, 0, nullptr, scal);
    // 4. T stats + loss_mean
    tstats_kernel<<<1, 256, 0, stream>>>(Tm, mu_sum, mu_T, scal);
    // 5. cov = T^T T /256 - muT muT^T + dI  (+trace)
    mm32_kernel<<<dim3(8, 8, 1), 256, 0, stream>>>(Tm, Tm, cov, nullptr,
                                                   nullptr, nullptr, nullptr, nullptr, 2, mu_T, scal);
    // 6. G = cov @ covX (+frobenius)
    mm32_kernel<<<dim3(8, 8, 1), 256, 0, stream>>>(cov, covX, G, nullptr,
                                                   nullptr, nullptr, nullptr, nullptr, 1, nullptr, scal);
    // 7. Newton-Schulz: trace(sqrt(G))
    inityz_kernel<<<256, 256, 0, stream>>>(G, scal, Ya, Za);
    float *Yc = Ya, *Zc = Za, *Yn = Yb, *Zn = Zb;
    for (int it = 0; it < NS_ITERS; ++it) {
        mm32_kernel<<<dim3(8, 8, 1), 256, 0, stream>>>(Zc, Yc, P, nullptr,
                                                       nullptr, nullptr, nullptr, nullptr, 0, nullptr, scal);
        mm32_kernel<<<dim3(8, 8, 2), 256, 0, stream>>>(Yc, P, Yn, Yc,
                                                       P, Zc, Zn, Zc, 3, nullptr, scal);
        float* ty_ = Yc; Yc = Yn; Yn = ty_;
        float* tz_ = Zc; Zc = Zn; Zn = tz_;
    }
    findist_kernel<<<1, 256, 0, stream>>>(Yc, scal);
    // 8. KNN: MFMA distances + block top-16, then global merge (layout unchanged)
    knn_kernel<<<dim3(NPCH, 2, 1), 512, 0, stream>>>(Tm, X, xsq, ck, ci);
    merge_kernel<<<256, 256, 0, stream>>>(ck, ci, post_idx);
    // 9. exact l2 + softmax
    l2sm_kernel<<<256, 256, 0, stream>>>(Tm, X, post_idx, post_w);
    // 10. KL
    kl_kernel<<<1, 256, 0, stream>>>(q_indices, pre_indices, pre_weights, post_idx, post_w, scal);
    // 11. assemble outputs
    assemble_kernel<<<1, 64, 0, stream>>>(scal, out);
}

// Round 2
// 1749.855 us; speedup vs baseline: 1.0883x; 1.0883x over previous
//
#include <hip/hip_runtime.h>

// ---------------- problem constants ----------------
#define NPTS   100000
#define DIMD   256
#define BQ     256
#define KNB    16
#define NQROWS 4096
#define PCHUNK 128
#define NPCH   782           // ceil(100000/128)
#define NCAND  (NPCH*16)     // candidates per query for final merge
#define NS_ITERS 26
#define KSPLIT  32
#define KSLICE  3136         // 32*3136 = 100352 >= 100000

// scal[] slots
#define SC_LM   0
#define SC_TRCX 1
#define SC_TRCT 2
#define SC_FROB 3
#define SC_KNN  4
#define SC_REG  5
#define SC_LD   6

#define BIGF 3.4e38f

typedef __attribute__((ext_vector_type(4))) float f32x4;
typedef __attribute__((ext_vector_type(8))) unsigned short u16x8;
typedef __attribute__((ext_vector_type(4))) unsigned int u32x4;
typedef __attribute__((ext_vector_type(8))) __bf16 bf16x8;

static __device__ __forceinline__ unsigned short f2bf(float f) {
    unsigned u = __float_as_uint(f);
    unsigned r = (u + 0x7fffu + ((u >> 16) & 1u)) >> 16;   // RNE
    return (unsigned short)r;
}
static __device__ __forceinline__ float bf2f(unsigned short h) {
    return __uint_as_float(((unsigned)h) << 16);
}
// truncation-based split: f = hi + lo + O(2^-16 |f|); hi/lo exact bit ops (cheap)
static __device__ __forceinline__ unsigned pack_hi(float a, float b) {
    return (__float_as_uint(a) >> 16) | (__float_as_uint(b) & 0xffff0000u);
}
static __device__ __forceinline__ float trunc_bf(float a) {
    return __uint_as_float(__float_as_uint(a) & 0xffff0000u);
}
static __device__ __forceinline__ f32x4 mfma16(u16x8 a, u16x8 b, f32x4 c) {
    return __builtin_amdgcn_mfma_f32_16x16x32_bf16(
        __builtin_bit_cast(bf16x8, a), __builtin_bit_cast(bf16x8, b), c, 0, 0, 0);
}

// sorted-insert into register top-16 (ascending; sk[15] = worst). All indices static.
#define INS16(kk, idv) do { \
    float _k = (kk); int _id = (idv); \
    if (_k < sk[15]) { \
        _Pragma("unroll") \
        for (int _j = 15; _j > 0; --_j) { \
            bool _a = _k < sk[_j-1]; \
            bool _b = _k < sk[_j]; \
            float _nk = _a ? sk[_j-1] : (_b ? _k : sk[_j]); \
            int   _ni = _a ? si[_j-1] : (_b ? _id : si[_j]); \
            sk[_j] = _nk; si[_j] = _ni; \
        } \
        bool _c = _k < sk[0]; \
        float _nk0 = _c ? _k : sk[0]; int _ni0 = _c ? _id : si[0]; \
        sk[0] = _nk0; si[0] = _ni0; \
    } \
} while (0)

// ---------------- zero init ----------------
__global__ __launch_bounds__(256) void zero_kernel(float* ws) {
    int idx = blockIdx.x * 256 + threadIdx.x;
    if (idx < 66560) ws[idx] = 0.0f;   // mu_sum + scal + pad + covX accumulator
}

// ---------------- X stats: column sums + row sq-norms + (opt) swizzled bf16 hi/lo image ----
// XHs/XLs global layout (when non-null): row r (512 B of bf16) stores 16-B group j at
// slot j ^ (r&7)  -> knn2 stages linearly and reads with the same XOR (bank-friendly).
__global__ __launch_bounds__(256) void statsx_kernel(const float* __restrict__ X,
                                                     float* __restrict__ xsq,
                                                     float* __restrict__ mu_sum,
                                                     unsigned short* __restrict__ XHs,
                                                     unsigned short* __restrict__ XLs) {
    int w    = threadIdx.x >> 6;   // wave 0..3
    int lane = threadIdx.x & 63;
    int rbase = blockIdx.x * 512;
    float cs0 = 0.f, cs1 = 0.f, cs2 = 0.f, cs3 = 0.f;
    for (int m = 0; m < 128; ++m) {
        int r = rbase + w + 4 * m;
        if (r < NPTS) {
            float4 v = *(const float4*)&X[r * DIMD + 4 * lane];
            cs0 += v.x; cs1 += v.y; cs2 += v.z; cs3 += v.w;
            float ss = v.x * v.x + v.y * v.y + v.z * v.z + v.w * v.w;
            for (int off = 32; off; off >>= 1) ss += __shfl_down(ss, off);
            if (lane == 0) xsq[r] = ss;
            if (XHs) {
                int g = (lane >> 1) ^ (r & 7);
                int h = lane & 1;
                uint2 hv = { pack_hi(v.x, v.y), pack_hi(v.z, v.w) };
                uint2 lv = { pack_hi(v.x - trunc_bf(v.x), v.y - trunc_bf(v.y)),
                             pack_hi(v.z - trunc_bf(v.z), v.w - trunc_bf(v.w)) };
                *(uint2*)(XHs + (size_t)r * 256 + g * 8 + h * 4) = hv;
                *(uint2*)(XLs + (size_t)r * 256 + g * 8 + h * 4) = lv;
            }
        } else if (XHs) {
            int g = (lane >> 1) ^ (r & 7);
            int h = lane & 1;
            uint2 z2 = {0u, 0u};
            *(uint2*)(XHs + (size_t)r * 256 + g * 8 + h * 4) = z2;
            *(uint2*)(XLs + (size_t)r * 256 + g * 8 + h * 4) = z2;
        }
    }
    atomicAdd(&mu_sum[4 * lane + 0], cs0);
    atomicAdd(&mu_sum[4 * lane + 1], cs1);
    atomicAdd(&mu_sum[4 * lane + 2], cs2);
    atomicAdd(&mu_sum[4 * lane + 3], cs3);
}

// ---------------- covX accumulate: acc += X^T X over K-slice ----------------
__global__ __launch_bounds__(256) void covx_kernel(const float* __restrict__ X,
                                                   float* __restrict__ acc_out) {
    __shared__ float Ais[16][64];
    __shared__ float Ajs[16][64];
    int t = threadIdx.x;
    int i0 = blockIdx.x * 64, j0 = blockIdx.y * 64;
    int ks = blockIdx.z * KSLICE;
    int lr = t >> 4, lc = (t & 15) * 4;
    int tx = t & 15, ty = t >> 4;
    float acc[4][4] = {};
    for (int kb = 0; kb < KSLICE; kb += 16) {
        int k = ks + kb + lr;
        if (k < NPTS) {
            float4 vi = *(const float4*)&X[k * DIMD + i0 + lc];
            float4 vj = *(const float4*)&X[k * DIMD + j0 + lc];
            *(float4*)&Ais[lr][lc] = vi;
            *(float4*)&Ajs[lr][lc] = vj;
        } else {
            float4 z = {0.f, 0.f, 0.f, 0.f};
            *(float4*)&Ais[lr][lc] = z;
            *(float4*)&Ajs[lr][lc] = z;
        }
        __syncthreads();
#pragma unroll
        for (int kk = 0; kk < 16; ++kk) {
            float4 a = *(float4*)&Ais[kk][tx * 4];
            float4 b = *(float4*)&Ajs[kk][ty * 4];
            float av[4] = {a.x, a.y, a.z, a.w};
            float bv[4] = {b.x, b.y, b.z, b.w};
#pragma unroll
            for (int m = 0; m < 4; ++m)
#pragma unroll
                for (int n = 0; n < 4; ++n) acc[m][n] += av[m] * bv[n];
        }
        __syncthreads();
    }
#pragma unroll
    for (int m = 0; m < 4; ++m)
#pragma unroll
        for (int n = 0; n < 4; ++n)
            atomicAdd(&acc_out[(i0 + 4 * tx + m) * DIMD + j0 + 4 * ty + n], acc[m][n]);
}

// ---------------- covX finalize ----------------
__global__ __launch_bounds__(256) void covxfin_kernel(float* __restrict__ covX,
                                                      const float* __restrict__ mu_sum,
                                                      float* __restrict__ scal) {
    int idx = blockIdx.x * 256 + threadIdx.x;
    int i = idx >> 8, j = idx & 255;
    const float invN = 1.0f / (float)NPTS;
    float v = covX[idx] * invN - (mu_sum[i] * invN) * (mu_sum[j] * invN) + ((i == j) ? 1e-4f : 0.0f);
    covX[idx] = v;
    if (i == j) atomicAdd(&scal[SC_TRCX], v);
}

// ---------------- generic 256x256x256 matmul, 32x32 tiles (fp32) ----------------
// mode 0: C = A@B  (if C2 non-null: also emit bf16 trunc-split pair C2=hi, D2=lo, row-major)
// mode 1: C = A@B, also atomicAdd sum(C^2) -> scal[SC_FROB]
// mode 2: C = (A^T@B)/256 - mu_i*mu_j + 1e-4*I, trace -> scal[SC_TRCT]
// mode 3: C = 1.5*D - 0.5*(A@B); with gridDim.z==2, z==1 uses (A2,B2,C2,D2)
__global__ __launch_bounds__(256) void mm32_kernel(const float* A, const float* B, float* C, const float* D,
                                                   const float* A2, const float* B2, float* C2, const float* D2,
                                                   int mode, const float* mu, float* scal) {
    if (mode == 3 && blockIdx.z == 1) { A = A2; B = B2; C = C2; D = D2; }
    __shared__ float As[32][32];
    __shared__ float Bs[32][32];
    __shared__ float red[256];
    int t = threadIdx.x;
    int tx = t & 15, ty = t >> 4;
    int i0 = blockIdx.x * 32, j0 = blockIdx.y * 32;
    int lr = t >> 3, lc = (t & 7) * 4;
    float acc[2][2] = {};
    for (int kb = 0; kb < 256; kb += 32) {
        if (mode == 2) {
            float4 v = *(const float4*)&A[(kb + lr) * DIMD + i0 + lc];
            *(float4*)&As[lr][lc] = v;
        } else {
            float4 v = *(const float4*)&A[(i0 + lr) * DIMD + kb + lc];
            As[lc + 0][lr] = v.x; As[lc + 1][lr] = v.y; As[lc + 2][lr] = v.z; As[lc + 3][lr] = v.w;
        }
        {
            float4 v = *(const float4*)&B[(kb + lr) * DIMD + j0 + lc];
            *(float4*)&Bs[lr][lc] = v;
        }
        __syncthreads();
#pragma unroll
        for (int kk = 0; kk < 32; ++kk) {
            float a0 = As[kk][2 * tx], a1 = As[kk][2 * tx + 1];
            float b0 = Bs[kk][2 * ty], b1 = Bs[kk][2 * ty + 1];
            acc[0][0] += a0 * b0; acc[0][1] += a0 * b1;
            acc[1][0] += a1 * b0; acc[1][1] += a1 * b1;
        }
        __syncthreads();
    }
    float fr = 0.f;
#pragma unroll
    for (int ii = 0; ii < 2; ++ii)
#pragma unroll
        for (int jj = 0; jj < 2; ++jj) {
            int i = i0 + 2 * tx + ii, j = j0 + 2 * ty + jj;
            float v = acc[ii][jj];
            if (mode == 2) {
                v = v * (1.0f / 256.0f) - mu[i] * mu[j] + ((i == j) ? 1e-4f : 0.0f);
                if (i == j) atomicAdd(&scal[SC_TRCT], v);
            } else if (mode == 3) {
                v = 1.5f * D[i * DIMD + j] - 0.5f * v;
            }
            C[i * DIMD + j] = v;
            if (mode == 1) fr += v * v;
        }
    if (mode == 0 && C2 != nullptr) {
        unsigned short* TH = (unsigned short*)C2;
        unsigned short* TL = (unsigned short*)const_cast<float*>(D2);
#pragma unroll
        for (int ii = 0; ii < 2; ++ii) {
            int i = i0 + 2 * tx + ii;
            int jc = j0 + 2 * ty;
            float x0 = acc[ii][0], x1 = acc[ii][1];
            *(unsigned*)&TH[i * DIMD + jc] = pack_hi(x0, x1);
            *(unsigned*)&TL[i * DIMD + jc] = pack_hi(x0 - trunc_bf(x0), x1 - trunc_bf(x1));
        }
    }
    if (mode == 1) {
        red[t] = fr; __syncthreads();
        for (int s2 = 128; s2 > 0; s2 >>= 1) { if (t < s2) red[t] += red[t + s2]; __syncthreads(); }
        if (t == 0) atomicAdd(&scal[SC_FROB], red[0]);
    }
}

// ---------------- Newton-Schulz GEMM on matrix cores (split-bf16, 3-pass) ----------------
// mode 0: C = A@B ; mode 3: C = 1.5*D - 0.5*(A@B), gridDim.z==2 packs the (Y,Z) pair.
// 64x64 tile per block, 4 waves, wave = 16 rows x 64 cols. B staged once into LDS as
// transposed bf16 hi/lo [col][264]; A-fragments trunc-split in registers from fp32 rows.
__global__ __launch_bounds__(256, 2) void nsmm_kernel(const float* A, const float* B, float* C, const float* D,
                                                      const float* A2, const float* B2, float* C2, const float* D2,
                                                      int mode) {
    if (blockIdx.z == 1) { A = A2; B = B2; C = C2; D = D2; }
    __shared__ __align__(16) unsigned short BH[64 * 264];
    __shared__ __align__(16) unsigned short BL[64 * 264];
    const int t = threadIdx.x;
    const int i0 = blockIdx.x * 64, j0 = blockIdx.y * 64;
    {
        const int c = t & 63, kp = t >> 6;
#pragma unroll 1
        for (int m = 0; m < 32; ++m) {
            const int k = m * 8 + kp * 2;
            float v0 = B[k * DIMD + j0 + c];
            float v1 = B[(k + 1) * DIMD + j0 + c];
            *(unsigned*)&BH[c * 264 + k] = pack_hi(v0, v1);
            *(unsigned*)&BL[c * 264 + k] = pack_hi(v0 - trunc_bf(v0), v1 - trunc_bf(v1));
        }
    }
    __syncthreads();
    const int w = t >> 6, lane = t & 63, l15 = lane & 15, l4 = lane >> 4;
    f32x4 acc[4];
#pragma unroll
    for (int cf = 0; cf < 4; ++cf) { f32x4 z = {0.f, 0.f, 0.f, 0.f}; acc[cf] = z; }
#pragma unroll
    for (int ks = 0; ks < 8; ++ks) {
        const float* ap = A + (i0 + w * 16 + l15) * DIMD + ks * 32 + l4 * 8;
        float4 a0 = *(const float4*)ap;
        float4 a1 = *(const float4*)(ap + 4);
        u32x4 hv = { pack_hi(a0.x, a0.y), pack_hi(a0.z, a0.w),
                     pack_hi(a1.x, a1.y), pack_hi(a1.z, a1.w) };
        u32x4 lv = { pack_hi(a0.x - trunc_bf(a0.x), a0.y - trunc_bf(a0.y)),
                     pack_hi(a0.z - trunc_bf(a0.z), a0.w - trunc_bf(a0.w)),
                     pack_hi(a1.x - trunc_bf(a1.x), a1.y - trunc_bf(a1.y)),
                     pack_hi(a1.z - trunc_bf(a1.z), a1.w - trunc_bf(a1.w)) };
        u16x8 ah = __builtin_bit_cast(u16x8, hv);
        u16x8 al = __builtin_bit_cast(u16x8, lv);
#pragma unroll
        for (int cf = 0; cf < 4; ++cf) {
            const int bo = (cf * 16 + l15) * 264 + ks * 32 + l4 * 8;
            u16x8 bh = *(const u16x8*)&BH[bo];
            u16x8 bl = *(const u16x8*)&BL[bo];
            acc[cf] = mfma16(ah, bh, acc[cf]);
            acc[cf] = mfma16(ah, bl, acc[cf]);
            acc[cf] = mfma16(al, bh, acc[cf]);
        }
    }
#pragma unroll
    for (int cf = 0; cf < 4; ++cf)
#pragma unroll
        for (int i = 0; i < 4; ++i) {
            const int r = i0 + w * 16 + l4 * 4 + i;
            const int col = j0 + cf * 16 + l15;
            float v = acc[cf][i];
            if (mode == 3) v = 1.5f * D[r * DIMD + col] - 0.5f * v;
            C[r * DIMD + col] = v;
        }
}

// ---------------- T stats: mu_T + loss_mean ----------------
__global__ __launch_bounds__(256) void tstats_kernel(const float* __restrict__ Tm,
                                                     const float* __restrict__ mu_sum,
                                                     float* __restrict__ mu_T,
                                                     float* __restrict__ scal) {
    __shared__ float red[256];
    int j = threadIdx.x;
    float s = 0.f;
    for (int b = 0; b < BQ; ++b) s += Tm[b * DIMD + j];
    float mt = s * (1.0f / 256.0f);
    mu_T[j] = mt;
    float d = mt - mu_sum[j] * (1.0f / (float)NPTS);
    red[j] = d * d;
    __syncthreads();
    for (int s2 = 128; s2 > 0; s2 >>= 1) { if (j < s2) red[j] += red[j + s2]; __syncthreads(); }
    if (j == 0) scal[SC_LM] = red[0];
}

// ---------------- init Y = G/||G||_F, Z = I ----------------
__global__ __launch_bounds__(256) void inityz_kernel(const float* __restrict__ G,
                                                     const float* __restrict__ scal,
                                                     float* __restrict__ Y, float* __restrict__ Z) {
    int idx = blockIdx.x * 256 + threadIdx.x;
    float invs = rsqrtf(scal[SC_FROB]);   // 1/sqrt(sum G^2) = 1/||G||_F
    Y[idx] = G[idx] * invs;
    Z[idx] = ((idx >> 8) == (idx & 255)) ? 1.0f : 0.0f;
}

// ---------------- finalize loss_dist ----------------
__global__ __launch_bounds__(256) void findist_kernel(const float* __restrict__ Yfin,
                                                      float* __restrict__ scal) {
    __shared__ float red[256];
    int t = threadIdx.x;
    red[t] = Yfin[t * (DIMD + 1)];
    __syncthreads();
    for (int s2 = 128; s2 > 0; s2 >>= 1) { if (t < s2) red[t] += red[t + s2]; __syncthreads(); }
    if (t == 0) {
        float frobsq = scal[SC_FROB];
        float tr_sqrt = powf(frobsq, 0.25f) * red[0];   // sqrt(s)*trace(Y), s=sqrt(frobsq)
        float lc = scal[SC_TRCX] + scal[SC_TRCT] - 2.0f * tr_sqrt;
        scal[SC_LD] = fmaxf(0.0f, scal[SC_LM] + lc);
    }
}

// ---------------- reg: sum(W^2) ----------------
__global__ __launch_bounds__(256) void reg_kernel(const float* __restrict__ W, float* __restrict__ scal) {
    __shared__ float red[256];
    int t = threadIdx.x;
    float s = 0.f;
    int base = blockIdx.x * 1024;
    for (int m = 0; m < 4; ++m) { float w = W[base + m * 256 + t]; s += w * w; }
    red[t] = s;
    __syncthreads();
    for (int s2 = 128; s2 > 0; s2 >>= 1) { if (t < s2) red[t] += red[t + s2]; __syncthreads(); }
    if (t == 0) atomicAdd(&scal[SC_REG], red[0]);
}

// ---------------- KNN v2: precomputed bf16 image + MFMA + register top-16 ----------------
// Block: 256 thr / 4 waves; covers ALL 256 queries x 128 points (4 pchunks of 32).
// Wave w owns queries w*64..w*64+63 (4 q-frags) x 32 points (2 pt-frags):
// 12 MFMA per 2 ds_read_b128. Stage = plain uint4 copy of the pre-swizzled global image.
// Selection: register-sorted top-16 per query (branchless insert), no LDS chains.
__global__ __launch_bounds__(256, 2) void knn2_kernel(const unsigned short* __restrict__ TmH,
                                                      const unsigned short* __restrict__ TmL,
                                                      const unsigned short* __restrict__ XHs,
                                                      const unsigned short* __restrict__ XLs,
                                                      const float* __restrict__ xsq,
                                                      float* __restrict__ ck, int* __restrict__ ci) {
    __shared__ __align__(16) unsigned char sm2[77824];   // XH 16K | XL 16K | kt[256][44] 45056
    float* kt = (float*)(sm2 + 32768);
    const int t = threadIdx.x;
    const int w = t >> 6, lane = t & 63;
    const int l15 = lane & 15, l4 = lane >> 4;
    const int p0 = blockIdx.x * PCHUNK;
    const int swz = (l15 & 7) << 4;   // byte XOR for swizzled B reads

    float sk[16]; int si[16];
#pragma unroll
    for (int s = 0; s < 16; ++s) { sk[s] = BIGF; si[s] = 0x7fffffff; }

#pragma unroll 1
    for (int pc = 0; pc < 4; ++pc) {
        const int pbase = p0 + pc * 32;
        {
            const uint4* gh = (const uint4*)(XHs + (size_t)pbase * 256);
            const uint4* gl = (const uint4*)(XLs + (size_t)pbase * 256);
#pragma unroll
            for (int r = 0; r < 4; ++r) {
                int slot = r * 256 + t;
                *(uint4*)(sm2 + slot * 16) = gh[slot];
                *(uint4*)(sm2 + 16384 + slot * 16) = gl[slot];
            }
        }
        __syncthreads();
        f32x4 acc[4][2];
#pragma unroll
        for (int f = 0; f < 4; ++f)
#pragma unroll
            for (int pt = 0; pt < 2; ++pt) { f32x4 z = {0.f, 0.f, 0.f, 0.f}; acc[f][pt] = z; }

#pragma unroll
        for (int ks = 0; ks < 8; ++ks) {
            u16x8 ah[4], al[4];
#pragma unroll
            for (int f = 0; f < 4; ++f) {
                const size_t off = (size_t)(w * 64 + f * 16 + l15) * 256 + ks * 32 + l4 * 8;
                ah[f] = *(const u16x8*)(TmH + off);
                al[f] = *(const u16x8*)(TmL + off);
            }
#pragma unroll
            for (int pt = 0; pt < 2; ++pt) {
                const int boff = (pt * 16 + l15) * 512 + ((((ks * 4 + l4) << 4)) ^ swz);
                u16x8 bh = *(const u16x8*)(sm2 + boff);
                u16x8 bl = *(const u16x8*)(sm2 + 16384 + boff);
#pragma unroll
                for (int f = 0; f < 4; ++f) {
                    acc[f][pt] = mfma16(ah[f], bh, acc[f][pt]);
                    acc[f][pt] = mfma16(ah[f], bl, acc[f][pt]);
                    acc[f][pt] = mfma16(al[f], bh, acc[f][pt]);
                }
            }
        }
        // kt write (kt region is disjoint from stage region; barrier below orders vs scan)
#pragma unroll
        for (int pt = 0; pt < 2; ++pt) {
            const int p = pbase + pt * 16 + l15;
            const float xv = xsq[p];
            const bool ok = (p < NPTS);
#pragma unroll
            for (int f = 0; f < 4; ++f)
#pragma unroll
                for (int i = 0; i < 4; ++i) {
                    const int qrow = w * 64 + f * 16 + l4 * 4 + i;
                    kt[qrow * 44 + pt * 16 + l15] = ok ? (xv - 2.0f * acc[f][pt][i]) : BIGF;
                }
        }
        __syncthreads();
        // all 256 threads scan their query's 32 new candidates
        {
            const int cb = pbase;
#pragma unroll 1
            for (int c4 = 0; c4 < 8; ++c4) {
                float4 v = *(const float4*)&kt[t * 44 + c4 * 4];
                INS16(v.x, cb + c4 * 4 + 0);
                INS16(v.y, cb + c4 * 4 + 1);
                INS16(v.z, cb + c4 * 4 + 2);
                INS16(v.w, cb + c4 * 4 + 3);
            }
        }
        __syncthreads();
    }
    const int base = t * NCAND + blockIdx.x * 16;
#pragma unroll
    for (int s = 0; s < 16; ++s) { ck[base + s] = sk[s]; ci[base + s] = si[s]; }
}

// ---------------- KNN (fallback when workspace too small): round-1 version ----------------
static __device__ __forceinline__ void knn_load(const float* __restrict__ X, int p0, int pc, int t,
                                                float4 s0[2], float4 s1[2]) {
#pragma unroll
    for (int rep = 0; rep < 2; ++rep) {
        int g = t + rep * 512;
        int row = g >> 5, c0 = (g & 31) * 8;
        int p = p0 + pc * 32 + row;
        if (p < NPTS) {
            s0[rep] = *(const float4*)&X[p * DIMD + c0];
            s1[rep] = *(const float4*)&X[p * DIMD + c0 + 4];
        } else {
            float4 z = {0.f, 0.f, 0.f, 0.f};
            s0[rep] = z; s1[rep] = z;
        }
    }
}

static __device__ __forceinline__ void knn_write(unsigned short* XH, unsigned short* XL, int t,
                                                 const float4 s0[2], const float4 s1[2]) {
#pragma unroll
    for (int rep = 0; rep < 2; ++rep) {
        int g = t + rep * 512;
        int row = g >> 5, c0 = (g & 31) * 8;
        float f[8] = {s0[rep].x, s0[rep].y, s0[rep].z, s0[rep].w,
                      s1[rep].x, s1[rep].y, s1[rep].z, s1[rep].w};
        u16x8 h, lo;
#pragma unroll
        for (int j = 0; j < 8; ++j) {
            unsigned short hb = f2bf(f[j]);
            h[j] = hb;
            lo[j] = f2bf(f[j] - bf2f(hb));
        }
        *(u16x8*)&XH[row * 264 + c0] = h;
        *(u16x8*)&XL[row * 264 + c0] = lo;
    }
}

__global__ __launch_bounds__(512, 2) void knn_kernel(const float* __restrict__ Tm,
                                                     const float* __restrict__ X,
                                                     const float* __restrict__ xsq,
                                                     float* __restrict__ ck, int* __restrict__ ci) {
    __shared__ __align__(16) unsigned char smem[50688];
    unsigned short* XH = (unsigned short*)smem;
    unsigned short* XL = (unsigned short*)(smem + 16896);
    float* ktf = (float*)smem;
    float* tk  = (float*)(smem + 34304);
    int*   ti  = (int*)  (smem + 42496);

    const int t    = threadIdx.x;
    const int w    = t >> 6;
    const int lane = t & 63;
    const int l15  = lane & 15;
    const int l4   = lane >> 4;
    const int p0   = blockIdx.x * PCHUNK;
    const int q0   = blockIdx.y * 128;

    u16x8 aH[8], aL[8];
    {
        const int q = q0 + w * 16 + l15;
        const float* tq = Tm + q * DIMD + l4 * 8;
#pragma unroll
        for (int ks = 0; ks < 8; ++ks) {
            float4 v0 = *(const float4*)(tq + ks * 32);
            float4 v1 = *(const float4*)(tq + ks * 32 + 4);
            float f[8] = {v0.x, v0.y, v0.z, v0.w, v1.x, v1.y, v1.z, v1.w};
            u16x8 h, lo;
#pragma unroll
            for (int j = 0; j < 8; ++j) {
                unsigned short hb = f2bf(f[j]);
                h[j] = hb;
                lo[j] = f2bf(f[j] - bf2f(hb));
            }
            aH[ks] = h; aL[ks] = lo;
        }
    }

    float worst = BIGF; int wslot = 0;

    float4 s0[2], s1[2];
    knn_load(X, p0, 0, t, s0, s1);
    knn_write(XH, XL, t, s0, s1);

#pragma unroll
    for (int h = 0; h < 2; ++h) {
        f32x4 acc[4];
#pragma unroll
        for (int a2 = 0; a2 < 4; ++a2) { f32x4 z = {0.f, 0.f, 0.f, 0.f}; acc[a2] = z; }

#pragma unroll
        for (int pc2 = 0; pc2 < 2; ++pc2) {
            const int pc = 2 * h + pc2;
            __syncthreads();
            if (pc < 3) knn_load(X, p0, pc + 1, t, s0, s1);
#pragma unroll
            for (int ks = 0; ks < 8; ++ks) {
#pragma unroll
                for (int pt = 0; pt < 2; ++pt) {
                    const int off = (pt * 16 + l15) * 264 + ks * 32 + l4 * 8;
                    u16x8 bh = *(const u16x8*)&XH[off];
                    u16x8 bl = *(const u16x8*)&XL[off];
                    acc[pc2 * 2 + pt] = mfma16(aH[ks], bh, acc[pc2 * 2 + pt]);
                    acc[pc2 * 2 + pt] = mfma16(aH[ks], bl, acc[pc2 * 2 + pt]);
                    acc[pc2 * 2 + pt] = mfma16(aL[ks], bh, acc[pc2 * 2 + pt]);
                }
            }
            __syncthreads();
            if (pc2 == 0 && pc < 3) knn_write(XH, XL, t, s0, s1);
        }

#pragma unroll
        for (int pc2 = 0; pc2 < 2; ++pc2) {
#pragma unroll
            for (int pt = 0; pt < 2; ++pt) {
                const int pl = pc2 * 32 + pt * 16 + l15;
                const int p  = p0 + h * 64 + pl;
                const float xv = (p < NPTS) ? xsq[p] : 0.f;
#pragma unroll
                for (int i = 0; i < 4; ++i) {
                    float key = (p < NPTS) ? (xv - 2.0f * acc[pc2 * 2 + pt][i]) : BIGF;
                    ktf[(w * 16 + l4 * 4 + i) * 67 + pl] = key;
                }
            }
        }
        __syncthreads();

        if (t < 128) {
            if (h == 0) {
#pragma unroll
                for (int s = 0; s < 16; ++s) { tk[s * 128 + t] = BIGF; ti[s * 128 + t] = 0x7fffffff; }
            }
            for (int c = 0; c < 64; ++c) {
                float key = ktf[t * 67 + c];
                if (key < worst) {
                    tk[wslot * 128 + t] = key; ti[wslot * 128 + t] = p0 + h * 64 + c;
                    worst = tk[t]; wslot = 0;
#pragma unroll
                    for (int s = 1; s < 16; ++s) {
                        float v = tk[s * 128 + t];
                        if (v > worst) { worst = v; wslot = s; }
                    }
                }
            }
        }
        __syncthreads();
        if (h == 0) knn_write(XH, XL, t, s0, s1);
    }

    if (t < 128) {
        int base = (q0 + t) * NCAND + blockIdx.x * 16;
        for (int s = 0; s < 16; ++s) { ck[base + s] = tk[s * 128 + t]; ci[base + s] = ti[s * 128 + t]; }
    }
}

// ---------------- global top-16 merge per query ----------------
__global__ __launch_bounds__(256) void merge_kernel(const float* __restrict__ ck,
                                                    const int* __restrict__ ci,
                                                    int* __restrict__ post_idx) {
    __shared__ float tk[16][256];
    __shared__ int   ti[16][256];
    __shared__ float rk[256];
    __shared__ int   ri[256];
    __shared__ int   rt2[256];
    __shared__ int   rs2[256];
    int q = blockIdx.x, t = threadIdx.x;
    for (int s = 0; s < 16; ++s) { tk[s][t] = BIGF; ti[s][t] = 0x7fffffff; }
    float worst = BIGF; int wslot = 0;
    for (int e = t; e < NCAND; e += 256) {
        float key = ck[q * NCAND + e];
        if (key < worst) {
            tk[wslot][t] = key; ti[wslot][t] = ci[q * NCAND + e];
            worst = tk[0][t]; wslot = 0;
            for (int s = 1; s < 16; ++s)
                if (tk[s][t] > worst) { worst = tk[s][t]; wslot = s; }
        }
    }
    __syncthreads();
    for (int r = 0; r < 16; ++r) {
        float bk = tk[0][t]; int bi = ti[0][t], bs = 0;
        for (int s = 1; s < 16; ++s) {
            float k2 = tk[s][t]; int i2 = ti[s][t];
            if (k2 < bk || (k2 == bk && i2 < bi)) { bk = k2; bi = i2; bs = s; }
        }
        rk[t] = bk; ri[t] = bi; rt2[t] = t; rs2[t] = bs;
        __syncthreads();
        for (int s2 = 128; s2 > 0; s2 >>= 1) {
            if (t < s2) {
                float ko = rk[t + s2]; int io = ri[t + s2];
                if (ko < rk[t] || (ko == rk[t] && io < ri[t])) {
                    rk[t] = ko; ri[t] = io; rt2[t] = rt2[t + s2]; rs2[t] = rs2[t + s2];
                }
            }
            __syncthreads();
        }
        if (t == rt2[0]) { tk[rs2[0]][t] = BIGF; ti[rs2[0]][t] = 0x7fffffff; }
        if (t == 0) post_idx[q * 16 + r] = ri[0];
        __syncthreads();
    }
}

// ---------------- exact l2 + softmax weights ----------------
__global__ __launch_bounds__(256) void l2sm_kernel(const float* __restrict__ Tm,
                                                   const float* __restrict__ X,
                                                   const int* __restrict__ post_idx,
                                                   float* __restrict__ post_w) {
    __shared__ float l2s[16];
    int b = blockIdx.x, t = threadIdx.x;
    int k = t >> 4, j = t & 15;
    int idx = post_idx[b * 16 + k];
    float s = 0.f;
    for (int i = 0; i < 16; ++i) {
        int d = j + 16 * i;
        float df = Tm[b * DIMD + d] - X[idx * DIMD + d];
        s += df * df;
    }
    for (int off = 8; off; off >>= 1) s += __shfl_down(s, off, 16);
    if (j == 0) l2s[k] = s;
    __syncthreads();
    if (t < 16) {
        float x = -l2s[t] * 10.0f;   // -l2 / TAU, TAU = 0.1
        float m = x;
        for (int mm = 8; mm; mm >>= 1) m = fmaxf(m, __shfl_xor(m, mm, 16));
        float e = expf(x - m);
        float ssum = e;
        for (int mm = 8; mm; mm >>= 1) ssum += __shfl_xor(ssum, mm, 16);
        post_w[b * 16 + t] = e / ssum;
    }
}

// ---------------- KL per sample (exact reference semantics) ----------------
__global__ __launch_bounds__(256) void kl_kernel(const int* __restrict__ q_indices,
                                                 const int* __restrict__ pre_indices,
                                                 const float* __restrict__ pre_weights,
                                                 const int* __restrict__ post_idx,
                                                 const float* __restrict__ post_w,
                                                 float* __restrict__ scal) {
    int b = threadIdx.x;
    int qi = q_indices[b];
    int pid[16]; float pw[16]; int sid[16]; float sw[16];
    for (int k = 0; k < 16; ++k) {
        pid[k] = pre_indices[qi * 16 + k];
        pw[k]  = pre_weights[qi * 16 + k];
        sid[k] = post_idx[b * 16 + k];
        sw[k]  = post_w[b * 16 + k];
    }
    float psum = 0.f, qsum = 0.f, kl = 0.f;
    for (int pass = 0; pass < 2; ++pass) {
        for (int i = 0; i < 32; ++i) {
            int c = (i < 16) ? pid[i] : sid[i - 16];
            bool first = true;
            for (int jj = 0; jj < i; ++jj) {
                int cj = (jj < 16) ? pid[jj] : sid[jj - 16];
                if (cj == c) { first = false; break; }
            }
            if (!first) continue;
            float p = 0.f, q = 0.f;
            for (int k2 = 0; k2 < 16; ++k2) {
                if (pid[k2] == c) p += pw[k2];
                if (sid[k2] == c) q += sw[k2];
            }
            p = fmaxf(p, 1e-8f); q = fmaxf(q, 1e-8f);
            if (pass == 0) { psum += p; qsum += q; }
            else {
                float pn = p / psum, qn = q / qsum;
                kl += pn * (logf(pn) - logf(qn));
            }
        }
    }
    atomicAdd(&scal[SC_KNN], kl * (1.0f / 256.0f));
}

// ---------------- final assembly ----------------
__global__ void assemble_kernel(const float* __restrict__ scal, float* __restrict__ out) {
    if (threadIdx.x == 0) {
        float ld = scal[SC_LD], lk = scal[SC_KNN], reg = scal[SC_REG];
        out[0] = ld + lk + 1e-4f * 0.5f * reg;
        out[1] = ld;
        out[2] = lk;
    }
}

extern "C" void kernel_launch(void* const* d_in, const int* in_sizes, int n_in,
                              void* d_out, int out_size, void* d_ws, size_t ws_size,
                              hipStream_t stream) {
    (void)in_sizes; (void)n_in; (void)out_size;
    const float* X           = (const float*)d_in[0];
    const float* W           = (const float*)d_in[1];
    const float* q_batch     = (const float*)d_in[2];
    const float* pre_weights = (const float*)d_in[3];
    const int*   q_indices   = (const int*)d_in[4];
    const int*   pre_indices = (const int*)d_in[5];
    float* out = (float*)d_out;
    float* ws  = (float*)d_ws;

    float* mu_sum = ws + 0;
    float* scal   = ws + 256;
    float* mu_T   = ws + 512;
    float* covX   = ws + 1024;
    float* Tm     = ws + 66560;
    float* cov    = ws + 132096;
    float* G      = ws + 197632;
    float* Ya     = ws + 263168;
    float* Za     = ws + 328704;
    float* Yb     = ws + 394240;
    float* Zb     = ws + 459776;
    float* P      = ws + 525312;
    float* xsq    = ws + 590848;
    float* post_w = ws + 691200;
    int*   post_idx = (int*)(ws + 695296);
    float* ck     = ws + 699392;
    int*   ci     = (int*)(ws + 3902464);
    // fast-path extras (bf16 trunc-split images)
    unsigned short* XHs = (unsigned short*)(ws + 7105536);   // 100352 x 256 bf16 (swizzled rows)
    unsigned short* XLs = (unsigned short*)(ws + 19950592);
    unsigned short* TmH = (unsigned short*)(ws + 32795648);  // 256 x 256 bf16 row-major
    unsigned short* TmL = (unsigned short*)(ws + 32828416);
    const bool fast = (ws_size >= (size_t)131444736);        // 131.4 MB needed

    // 0. zero accumulators (mu_sum, scal, covX)
    zero_kernel<<<260, 256, 0, stream>>>(ws);
    // reg term (independent)
    reg_kernel<<<64, 256, 0, stream>>>(W, scal);
    // 1. X stats (+ bf16 image on fast path)
    statsx_kernel<<<196, 256, 0, stream>>>(X, xsq, mu_sum,
                                           fast ? XHs : nullptr, fast ? XLs : nullptr);
    // 2. covX
    covx_kernel<<<dim3(4, 4, KSPLIT), 256, 0, stream>>>(X, covX);
    covxfin_kernel<<<256, 256, 0, stream>>>(covX, mu_sum, scal);
    // 3. T = q_batch @ W (+ TmH/TmL epilogue on fast path)
    mm32_kernel<<<dim3(8, 8, 1), 256, 0, stream>>>(q_batch, W, Tm, nullptr,
                                                   nullptr, nullptr,
                                                   fast ? (float*)TmH : nullptr,
                                                   fast ? (float*)TmL : nullptr, 0, nullptr, scal);
    // 4. T stats + loss_mean
    tstats_kernel<<<1, 256, 0, stream>>>(Tm, mu_sum, mu_T, scal);
    // 5. cov = T^T T /256 - muT muT^T + dI  (+trace)
    mm32_kernel<<<dim3(8, 8, 1), 256, 0, stream>>>(Tm, Tm, cov, nullptr,
                                                   nullptr, nullptr, nullptr, nullptr, 2, mu_T, scal);
    // 6. G = cov @ covX (+frobenius)
    mm32_kernel<<<dim3(8, 8, 1), 256, 0, stream>>>(cov, covX, G, nullptr,
                                                   nullptr, nullptr, nullptr, nullptr, 1, nullptr, scal);
    // 7. Newton-Schulz on matrix cores: trace(sqrt(G))
    inityz_kernel<<<256, 256, 0, stream>>>(G, scal, Ya, Za);
    float *Yc = Ya, *Zc = Za, *Yn = Yb, *Zn = Zb;
    for (int it = 0; it < NS_ITERS; ++it) {
        nsmm_kernel<<<dim3(4, 4, 1), 256, 0, stream>>>(Zc, Yc, P, nullptr,
                                                       nullptr, nullptr, nullptr, nullptr, 0);
        nsmm_kernel<<<dim3(4, 4, 2), 256, 0, stream>>>(Yc, P, Yn, Yc,
                                                       P, Zc, Zn, Zc, 3);
        float* ty_ = Yc; Yc = Yn; Yn = ty_;
        float* tz_ = Zc; Zc = Zn; Zn = tz_;
    }
    findist_kernel<<<1, 256, 0, stream>>>(Yc, scal);
    // 8. KNN distances + per-block top-16, then global merge (ck/ci layout unchanged)
    if (fast) {
        knn2_kernel<<<NPCH, 256, 0, stream>>>(TmH, TmL, XHs, XLs, xsq, ck, ci);
    } else {
        knn_kernel<<<dim3(NPCH, 2, 1), 512, 0, stream>>>(Tm, X, xsq, ck, ci);
    }
    merge_kernel<<<256, 256, 0, stream>>>(ck, ci, post_idx);
    // 9. exact l2 + softmax
    l2sm_kernel<<<256, 256, 0, stream>>>(Tm, X, post_idx, post_w);
    // 10. KL
    kl_kernel<<<1, 256, 0, stream>>>(q_indices, pre_indices, pre_weights, post_idx, post_w, scal);
    // 11. assemble outputs
    assemble_kernel<<<1, 64, 0, stream>>>(scal, out);
}

// Round 4
// 1704.468 us; speedup vs baseline: 1.1173x; 1.0266x over previous
//
#include <hip/hip_runtime.h>

// ---------------- problem constants ----------------
#define NPTS   100000
#define DIMD   256
#define BQ     256
#define PCHUNK 128
#define NPCH   782           // ceil(100000/128)
#define NCAND  (NPCH*16)     // candidates per query for final merge
#define NS_ITERS 26
#define KSPLIT  32
#define KSLICE  3136         // old covx: 32*3136 >= 100000
#define KS2    576           // covx2 k-slice (multiple of 32)
#define NZ2    175           // ceil(100352/576)

// scal[] slots
#define SC_LM   0
#define SC_TRCX 1
#define SC_TRCT 2
#define SC_FROB 3
#define SC_KNN  4
#define SC_REG  5
#define SC_LD   6

#define BIGF 3.4e38f

typedef __attribute__((ext_vector_type(4))) float f32x4;
typedef __attribute__((ext_vector_type(8))) unsigned short u16x8;
typedef __attribute__((ext_vector_type(8))) __bf16 bf16x8;

static __device__ __forceinline__ unsigned short f2bf(float f) {
    unsigned u = __float_as_uint(f);
    unsigned r = (u + 0x7fffu + ((u >> 16) & 1u)) >> 16;   // RNE
    return (unsigned short)r;
}
static __device__ __forceinline__ float bf2f(unsigned short h) {
    return __uint_as_float(((unsigned)h) << 16);
}
// truncation-based split: f = hi + lo + O(2^-16 |f|)
static __device__ __forceinline__ unsigned pack_hi(float a, float b) {
    return (__float_as_uint(a) >> 16) | (__float_as_uint(b) & 0xffff0000u);
}
static __device__ __forceinline__ float trunc_bf(float a) {
    return __uint_as_float(__float_as_uint(a) & 0xffff0000u);
}
static __device__ __forceinline__ unsigned short top16(float v) {
    return (unsigned short)(__float_as_uint(v) >> 16);
}
static __device__ __forceinline__ f32x4 mfma16(u16x8 a, u16x8 b, f32x4 c) {
    return __builtin_amdgcn_mfma_f32_16x16x32_bf16(
        __builtin_bit_cast(bf16x8, a), __builtin_bit_cast(bf16x8, b), c, 0, 0, 0);
}

// sortable float<->uint (monotone increasing)
static __device__ __forceinline__ unsigned enc_f32(float f) {
    unsigned u = __float_as_uint(f);
    return u ^ (unsigned)(((int)u >> 31) | 0x80000000);
}
static __device__ __forceinline__ float dec_f32(unsigned e) {
    unsigned u = e ^ ((e & 0x80000000u) ? 0x80000000u : 0xFFFFFFFFu);
    return __uint_as_float(u);
}
static __device__ __forceinline__ unsigned umin32(unsigned a, unsigned b) { return a < b ? a : b; }
static __device__ __forceinline__ void ceu(unsigned& a, unsigned& b) {
    unsigned lo = a < b ? a : b;
    unsigned hi = a < b ? b : a;
    a = lo; b = hi;
}
// bitonic sort ascending, 16 elems, fully static
static __device__ __forceinline__ void sort16(unsigned* r) {
#pragma unroll
    for (int k = 2; k <= 16; k <<= 1)
#pragma unroll
        for (int j = k >> 1; j > 0; j >>= 1)
#pragma unroll
            for (int i = 0; i < 16; ++i) {
                int l = i ^ j;
                if (l > i) {
                    if ((i & k) == 0) ceu(r[i], r[l]);
                    else              ceu(r[l], r[i]);
                }
            }
}
// clean a bitonic 16-sequence into ascending order
static __device__ __forceinline__ void clean16(unsigned* r) {
#pragma unroll
    for (int j = 8; j > 0; j >>= 1)
#pragma unroll
        for (int i = 0; i < 16; ++i) {
            int l = i ^ j;
            if (l > i) ceu(r[i], r[l]);
        }
}

// ---------------- zero init ----------------
__global__ __launch_bounds__(256) void zero_kernel(float* ws) {
    int idx = blockIdx.x * 256 + threadIdx.x;
    if (idx < 66560) ws[idx] = 0.0f;   // mu_sum + scal + pad + covX accumulator
}

// ---------------- X stats: column sums + row sq-norms + (opt) swizzled bf16 hi/lo image ----
__global__ __launch_bounds__(256) void statsx_kernel(const float* __restrict__ X,
                                                     float* __restrict__ xsq,
                                                     float* __restrict__ mu_sum,
                                                     unsigned short* __restrict__ XHs,
                                                     unsigned short* __restrict__ XLs) {
    int w    = threadIdx.x >> 6;   // wave 0..3
    int lane = threadIdx.x & 63;
    int rbase = blockIdx.x * 512;
    float cs0 = 0.f, cs1 = 0.f, cs2 = 0.f, cs3 = 0.f;
    for (int m = 0; m < 128; ++m) {
        int r = rbase + w + 4 * m;
        if (r < NPTS) {
            float4 v = *(const float4*)&X[r * DIMD + 4 * lane];
            cs0 += v.x; cs1 += v.y; cs2 += v.z; cs3 += v.w;
            float ss = v.x * v.x + v.y * v.y + v.z * v.z + v.w * v.w;
            for (int off = 32; off; off >>= 1) ss += __shfl_down(ss, off);
            if (lane == 0) xsq[r] = ss;
            if (XHs) {
                int g = (lane >> 1) ^ (r & 7);
                int h = lane & 1;
                uint2 hv = { pack_hi(v.x, v.y), pack_hi(v.z, v.w) };
                uint2 lv = { pack_hi(v.x - trunc_bf(v.x), v.y - trunc_bf(v.y)),
                             pack_hi(v.z - trunc_bf(v.z), v.w - trunc_bf(v.w)) };
                *(uint2*)(XHs + (size_t)r * 256 + g * 8 + h * 4) = hv;
                *(uint2*)(XLs + (size_t)r * 256 + g * 8 + h * 4) = lv;
            }
        } else if (XHs) {
            int g = (lane >> 1) ^ (r & 7);
            int h = lane & 1;
            uint2 z2 = {0u, 0u};
            *(uint2*)(XHs + (size_t)r * 256 + g * 8 + h * 4) = z2;
            *(uint2*)(XLs + (size_t)r * 256 + g * 8 + h * 4) = z2;
        }
    }
    atomicAdd(&mu_sum[4 * lane + 0], cs0);
    atomicAdd(&mu_sum[4 * lane + 1], cs1);
    atomicAdd(&mu_sum[4 * lane + 2], cs2);
    atomicAdd(&mu_sum[4 * lane + 3], cs3);
}

// ---------------- transpose bf16 image: XHs[r][d] -> XTH[d][r] (and L) ----------------
__global__ __launch_bounds__(256) void xtk_kernel(const unsigned short* __restrict__ XHs,
                                                  const unsigned short* __restrict__ XLs,
                                                  unsigned short* __restrict__ XTH,
                                                  unsigned short* __restrict__ XTL) {
    __shared__ unsigned short LH[32][268];
    __shared__ unsigned short LL[32][268];
    const int t = threadIdx.x;
#pragma unroll 1
    for (int st = 0; st < 8; ++st) {
        const int r0 = blockIdx.x * 256 + st * 32;
        const int row = t >> 3;
        const int r = r0 + row;
#pragma unroll
        for (int gg = 0; gg < 4; ++gg) {
            int glog = (t & 7) + gg * 8;
            int gphys = glog ^ (r & 7);
            u16x8 h = *(const u16x8*)(XHs + (size_t)r * 256 + gphys * 8);
            u16x8 l = *(const u16x8*)(XLs + (size_t)r * 256 + gphys * 8);
            *(u16x8*)&LH[row][glog * 8] = h;
            *(u16x8*)&LL[row][glog * 8] = l;
        }
        __syncthreads();
        // thread t owns dim d = t; write 32 consecutive points (one full 64B line per img)
        {
            unsigned pk[16];
#pragma unroll
            for (int m = 0; m < 16; ++m)
                pk[m] = (unsigned)LH[2 * m][t] | ((unsigned)LH[2 * m + 1][t] << 16);
            uint4* oh = (uint4*)(XTH + (size_t)t * 100352 + r0);
#pragma unroll
            for (int q = 0; q < 4; ++q)
                oh[q] = make_uint4(pk[4 * q], pk[4 * q + 1], pk[4 * q + 2], pk[4 * q + 3]);
#pragma unroll
            for (int m = 0; m < 16; ++m)
                pk[m] = (unsigned)LL[2 * m][t] | ((unsigned)LL[2 * m + 1][t] << 16);
            uint4* ol = (uint4*)(XTL + (size_t)t * 100352 + r0);
#pragma unroll
            for (int q = 0; q < 4; ++q)
                ol[q] = make_uint4(pk[4 * q], pk[4 * q + 1], pk[4 * q + 2], pk[4 * q + 3]);
        }
        __syncthreads();
    }
}

// ---------------- covX via MFMA (split-bf16, reads transposed image) ----------------
// grid (4 quadrants, NZ2 k-slices); block = 128x128 quadrant, 4 waves (32 rows x 128 cols each)
__global__ __launch_bounds__(256) void covx2_kernel(const unsigned short* __restrict__ XTH,
                                                    const unsigned short* __restrict__ XTL,
                                                    float* __restrict__ acc_out) {
    const int quad = blockIdx.x;
    const int qi = quad >> 1, qj = quad & 1;
    const int t = threadIdx.x, w = t >> 6, lane = t & 63;
    const int l15 = lane & 15, l4 = lane >> 4;
    const int k0 = blockIdx.y * KS2;
    const int kend = (k0 + KS2 < 100352) ? (k0 + KS2) : 100352;
    f32x4 acc[2][8];
#pragma unroll
    for (int f = 0; f < 2; ++f)
#pragma unroll
        for (int cf = 0; cf < 8; ++cf) { f32x4 z = {0.f, 0.f, 0.f, 0.f}; acc[f][cf] = z; }
    const size_t rowA0 = (size_t)(qi * 128 + w * 32 + l15) * 100352;
    const size_t rowA1 = (size_t)(qi * 128 + w * 32 + 16 + l15) * 100352;
#pragma unroll 1
    for (int k = k0; k < kend; k += 32) {
        const int ko = k + l4 * 8;
        u16x8 ah0 = *(const u16x8*)(XTH + rowA0 + ko);
        u16x8 al0 = *(const u16x8*)(XTL + rowA0 + ko);
        u16x8 ah1 = *(const u16x8*)(XTH + rowA1 + ko);
        u16x8 al1 = *(const u16x8*)(XTL + rowA1 + ko);
#pragma unroll
        for (int cf = 0; cf < 8; ++cf) {
            const size_t rb = (size_t)(qj * 128 + cf * 16 + l15) * 100352 + ko;
            u16x8 bh = *(const u16x8*)(XTH + rb);
            u16x8 bl = *(const u16x8*)(XTL + rb);
            acc[0][cf] = mfma16(ah0, bh, acc[0][cf]);
            acc[0][cf] = mfma16(ah0, bl, acc[0][cf]);
            acc[0][cf] = mfma16(al0, bh, acc[0][cf]);
            acc[1][cf] = mfma16(ah1, bh, acc[1][cf]);
            acc[1][cf] = mfma16(ah1, bl, acc[1][cf]);
            acc[1][cf] = mfma16(al1, bh, acc[1][cf]);
        }
    }
#pragma unroll
    for (int f = 0; f < 2; ++f)
#pragma unroll
        for (int cf = 0; cf < 8; ++cf)
#pragma unroll
            for (int i = 0; i < 4; ++i) {
                const int r = qi * 128 + w * 32 + f * 16 + l4 * 4 + i;
                const int c = qj * 128 + cf * 16 + l15;
                atomicAdd(&acc_out[r * DIMD + c], acc[f][cf][i]);
            }
}

// ---------------- old covX accumulate (fallback, fp32 VALU) ----------------
__global__ __launch_bounds__(256) void covx_kernel(const float* __restrict__ X,
                                                   float* __restrict__ acc_out) {
    __shared__ float Ais[16][64];
    __shared__ float Ajs[16][64];
    int t = threadIdx.x;
    int i0 = blockIdx.x * 64, j0 = blockIdx.y * 64;
    int ks = blockIdx.z * KSLICE;
    int lr = t >> 4, lc = (t & 15) * 4;
    int tx = t & 15, ty = t >> 4;
    float acc[4][4] = {};
    for (int kb = 0; kb < KSLICE; kb += 16) {
        int k = ks + kb + lr;
        if (k < NPTS) {
            float4 vi = *(const float4*)&X[k * DIMD + i0 + lc];
            float4 vj = *(const float4*)&X[k * DIMD + j0 + lc];
            *(float4*)&Ais[lr][lc] = vi;
            *(float4*)&Ajs[lr][lc] = vj;
        } else {
            float4 z = {0.f, 0.f, 0.f, 0.f};
            *(float4*)&Ais[lr][lc] = z;
            *(float4*)&Ajs[lr][lc] = z;
        }
        __syncthreads();
#pragma unroll
        for (int kk = 0; kk < 16; ++kk) {
            float4 a = *(float4*)&Ais[kk][tx * 4];
            float4 b = *(float4*)&Ajs[kk][ty * 4];
            float av[4] = {a.x, a.y, a.z, a.w};
            float bv[4] = {b.x, b.y, b.z, b.w};
#pragma unroll
            for (int m = 0; m < 4; ++m)
#pragma unroll
                for (int n = 0; n < 4; ++n) acc[m][n] += av[m] * bv[n];
        }
        __syncthreads();
    }
#pragma unroll
    for (int m = 0; m < 4; ++m)
#pragma unroll
        for (int n = 0; n < 4; ++n)
            atomicAdd(&acc_out[(i0 + 4 * tx + m) * DIMD + j0 + 4 * ty + n], acc[m][n]);
}

// ---------------- covX finalize: acc -> covXf (+trace) ----------------
__global__ __launch_bounds__(256) void covxfin2_kernel(const float* __restrict__ acc,
                                                       const float* __restrict__ mu_sum,
                                                       float* __restrict__ covXf,
                                                       float* __restrict__ scal) {
    int idx = blockIdx.x * 256 + threadIdx.x;
    int i = idx >> 8, j = idx & 255;
    const float invN = 1.0f / (float)NPTS;
    float v = acc[idx] * invN - (mu_sum[i] * invN) * (mu_sum[j] * invN) + ((i == j) ? 1e-4f : 0.0f);
    covXf[idx] = v;
    if (i == j) atomicAdd(&scal[SC_TRCX], v);
}

// ---------------- generic 256x256x256 matmul, 32x32 tiles (fp32) ----------------
// mode 0: C = A@B  (if C2 non-null: also emit bf16 trunc-split pair C2=hi, D2=lo)
// mode 1: C = A@B, also sum(C^2) -> scal[SC_FROB]
// mode 2: C = (A^T@B)/256 - mu_i*mu_j + 1e-4*I, trace -> scal[SC_TRCT]
__global__ __launch_bounds__(256) void mm32_kernel(const float* A, const float* B, float* C, const float* D,
                                                   const float* A2, const float* B2, float* C2, const float* D2,
                                                   int mode, const float* mu, float* scal) {
    __shared__ float As[32][32];
    __shared__ float Bs[32][32];
    __shared__ float red[256];
    int t = threadIdx.x;
    int tx = t & 15, ty = t >> 4;
    int i0 = blockIdx.x * 32, j0 = blockIdx.y * 32;
    int lr = t >> 3, lc = (t & 7) * 4;
    float acc[2][2] = {};
    for (int kb = 0; kb < 256; kb += 32) {
        if (mode == 2) {
            float4 v = *(const float4*)&A[(kb + lr) * DIMD + i0 + lc];
            *(float4*)&As[lr][lc] = v;
        } else {
            float4 v = *(const float4*)&A[(i0 + lr) * DIMD + kb + lc];
            As[lc + 0][lr] = v.x; As[lc + 1][lr] = v.y; As[lc + 2][lr] = v.z; As[lc + 3][lr] = v.w;
        }
        {
            float4 v = *(const float4*)&B[(kb + lr) * DIMD + j0 + lc];
            *(float4*)&Bs[lr][lc] = v;
        }
        __syncthreads();
#pragma unroll
        for (int kk = 0; kk < 32; ++kk) {
            float a0 = As[kk][2 * tx], a1 = As[kk][2 * tx + 1];
            float b0 = Bs[kk][2 * ty], b1 = Bs[kk][2 * ty + 1];
            acc[0][0] += a0 * b0; acc[0][1] += a0 * b1;
            acc[1][0] += a1 * b0; acc[1][1] += a1 * b1;
        }
        __syncthreads();
    }
    float fr = 0.f;
#pragma unroll
    for (int ii = 0; ii < 2; ++ii)
#pragma unroll
        for (int jj = 0; jj < 2; ++jj) {
            int i = i0 + 2 * tx + ii, j = j0 + 2 * ty + jj;
            float v = acc[ii][jj];
            if (mode == 2) {
                v = v * (1.0f / 256.0f) - mu[i] * mu[j] + ((i == j) ? 1e-4f : 0.0f);
                if (i == j) atomicAdd(&scal[SC_TRCT], v);
            }
            C[i * DIMD + j] = v;
            if (mode == 1) fr += v * v;
        }
    if (mode == 0 && C2 != nullptr) {
        unsigned short* TH = (unsigned short*)C2;
        unsigned short* TL = (unsigned short*)const_cast<float*>(D2);
#pragma unroll
        for (int ii = 0; ii < 2; ++ii) {
            int i = i0 + 2 * tx + ii;
            int jc = j0 + 2 * ty;
            float x0 = acc[ii][0], x1 = acc[ii][1];
            *(unsigned*)&TH[i * DIMD + jc] = pack_hi(x0, x1);
            *(unsigned*)&TL[i * DIMD + jc] = pack_hi(x0 - trunc_bf(x0), x1 - trunc_bf(x1));
        }
    }
    if (mode == 1) {
        red[t] = fr; __syncthreads();
        for (int s2 = 128; s2 > 0; s2 >>= 1) { if (t < s2) red[t] += red[t + s2]; __syncthreads(); }
        if (t == 0) atomicAdd(&scal[SC_FROB], red[0]);
    }
}

// ---------------- T stats ----------------
__global__ __launch_bounds__(256) void tstats_kernel(const float* __restrict__ Tm,
                                                     const float* __restrict__ mu_sum,
                                                     float* __restrict__ mu_T,
                                                     float* __restrict__ scal) {
    __shared__ float red[256];
    int j = threadIdx.x;
    float s = 0.f;
    for (int b = 0; b < BQ; ++b) s += Tm[b * DIMD + j];
    float mt = s * (1.0f / 256.0f);
    mu_T[j] = mt;
    float d = mt - mu_sum[j] * (1.0f / (float)NPTS);
    red[j] = d * d;
    __syncthreads();
    for (int s2 = 128; s2 > 0; s2 >>= 1) { if (j < s2) red[j] += red[j + s2]; __syncthreads(); }
    if (j == 0) scal[SC_LM] = red[0];
}

// ---------------- init Y = G/||G||_F (+images), Z = I (+images) ----------------
__global__ __launch_bounds__(256) void inityz2_kernel(const float* __restrict__ G,
                                                      const float* __restrict__ scal,
                                                      float* __restrict__ Y, float* __restrict__ Z,
                                                      unsigned short* __restrict__ YaH,
                                                      unsigned short* __restrict__ YaL,
                                                      unsigned short* __restrict__ ZaH,
                                                      unsigned short* __restrict__ ZaL) {
    int idx = blockIdx.x * 256 + threadIdx.x;
    float invs = rsqrtf(scal[SC_FROB]);
    float y = G[idx] * invs;
    Y[idx] = y;
    YaH[idx] = top16(y);
    YaL[idx] = top16(y - trunc_bf(y));
    bool dg = ((idx >> 8) == (idx & 255));
    Z[idx] = dg ? 1.0f : 0.0f;
    ZaH[idx] = dg ? (unsigned short)0x3F80 : (unsigned short)0;
    ZaL[idx] = 0;
}

// ---------------- fused Newton-Schulz iteration (one launch per iter) ----------------
// grid (8 col-slices of 32, 2 paths). path0: Yn = 1.5Y - 0.5*Y@(Z@Y[:,j])
//                                    path1: Zn = 1.5Z - 0.5*Z@(Y@Z[:,j])
__global__ __launch_bounds__(256) void nsfused_kernel(
        const float* __restrict__ Ycur, const float* __restrict__ Zcur,
        const unsigned short* __restrict__ YH, const unsigned short* __restrict__ YL,
        const unsigned short* __restrict__ ZH, const unsigned short* __restrict__ ZL,
        float* __restrict__ Yn, float* __restrict__ Zn,
        unsigned short* __restrict__ YnH, unsigned short* __restrict__ YnL,
        unsigned short* __restrict__ ZnH, unsigned short* __restrict__ ZnL) {
    __shared__ __align__(16) unsigned short VH[32 * 264];
    __shared__ __align__(16) unsigned short VL[32 * 264];
    __shared__ __align__(16) unsigned short IH[32 * 264];
    __shared__ __align__(16) unsigned short IL[32 * 264];
    const int t = threadIdx.x, w = t >> 6, lane = t & 63;
    const int l15 = lane & 15, l4 = lane >> 4;
    const int j0 = blockIdx.x * 32;
    const unsigned short *M1H, *M1L, *M2H, *M2L, *VsH, *VsL;
    const float* Dm; float* Out; unsigned short *OH, *OL;
    if (blockIdx.y == 0) { M1H = ZH; M1L = ZL; M2H = YH; M2L = YL; VsH = YH; VsL = YL;
                           Dm = Ycur; Out = Yn; OH = YnH; OL = YnL; }
    else                 { M1H = YH; M1L = YL; M2H = ZH; M2L = ZL; VsH = ZH; VsL = ZL;
                           Dm = Zcur; Out = Zn; OH = ZnH; OL = ZnL; }
    // stage V slice -> [col][k] LDS
    {
        const int col = t & 31, k0 = (t >> 5) * 32;
#pragma unroll
        for (int m = 0; m < 16; ++m) {
            const int k = k0 + 2 * m;
            unsigned h0 = VsH[(size_t)k * 256 + j0 + col];
            unsigned h1 = VsH[(size_t)(k + 1) * 256 + j0 + col];
            unsigned l0 = VsL[(size_t)k * 256 + j0 + col];
            unsigned l1 = VsL[(size_t)(k + 1) * 256 + j0 + col];
            *(unsigned*)&VH[col * 264 + k] = h0 | (h1 << 16);
            *(unsigned*)&VL[col * 264 + k] = l0 | (l1 << 16);
        }
    }
    __syncthreads();
    f32x4 acc[4][2];
#pragma unroll
    for (int f = 0; f < 4; ++f)
#pragma unroll
        for (int cf = 0; cf < 2; ++cf) { f32x4 z = {0.f, 0.f, 0.f, 0.f}; acc[f][cf] = z; }
    // GEMM1: I1 = M1 @ V
#pragma unroll
    for (int ks = 0; ks < 8; ++ks) {
        const int bo0 = l15 * 264 + ks * 32 + l4 * 8;
        const int bo1 = (16 + l15) * 264 + ks * 32 + l4 * 8;
        u16x8 bh0 = *(const u16x8*)&VH[bo0];
        u16x8 bl0 = *(const u16x8*)&VL[bo0];
        u16x8 bh1 = *(const u16x8*)&VH[bo1];
        u16x8 bl1 = *(const u16x8*)&VL[bo1];
#pragma unroll
        for (int f = 0; f < 4; ++f) {
            const size_t ro = (size_t)(w * 64 + f * 16 + l15) * 256 + ks * 32 + l4 * 8;
            u16x8 ah = *(const u16x8*)(M1H + ro);
            u16x8 al = *(const u16x8*)(M1L + ro);
            acc[f][0] = mfma16(ah, bh0, acc[f][0]);
            acc[f][0] = mfma16(ah, bl0, acc[f][0]);
            acc[f][0] = mfma16(al, bh0, acc[f][0]);
            acc[f][1] = mfma16(ah, bh1, acc[f][1]);
            acc[f][1] = mfma16(ah, bl1, acc[f][1]);
            acc[f][1] = mfma16(al, bh1, acc[f][1]);
        }
    }
    // I1 -> LDS (transposed, bf16 split)
#pragma unroll
    for (int f = 0; f < 4; ++f)
#pragma unroll
        for (int cf = 0; cf < 2; ++cf) {
            float v0 = acc[f][cf][0], v1 = acc[f][cf][1], v2 = acc[f][cf][2], v3 = acc[f][cf][3];
            unsigned h01 = pack_hi(v0, v1), h23 = pack_hi(v2, v3);
            unsigned l01 = pack_hi(v0 - trunc_bf(v0), v1 - trunc_bf(v1));
            unsigned l23 = pack_hi(v2 - trunc_bf(v2), v3 - trunc_bf(v3));
            const int ad = (cf * 16 + l15) * 264 + w * 64 + f * 16 + l4 * 4;
            *(uint2*)&IH[ad] = make_uint2(h01, h23);
            *(uint2*)&IL[ad] = make_uint2(l01, l23);
        }
    __syncthreads();
    // GEMM2: M2 @ I1
#pragma unroll
    for (int f = 0; f < 4; ++f)
#pragma unroll
        for (int cf = 0; cf < 2; ++cf) { f32x4 z = {0.f, 0.f, 0.f, 0.f}; acc[f][cf] = z; }
#pragma unroll
    for (int ks = 0; ks < 8; ++ks) {
        const int bo0 = l15 * 264 + ks * 32 + l4 * 8;
        const int bo1 = (16 + l15) * 264 + ks * 32 + l4 * 8;
        u16x8 bh0 = *(const u16x8*)&IH[bo0];
        u16x8 bl0 = *(const u16x8*)&IL[bo0];
        u16x8 bh1 = *(const u16x8*)&IH[bo1];
        u16x8 bl1 = *(const u16x8*)&IL[bo1];
#pragma unroll
        for (int f = 0; f < 4; ++f) {
            const size_t ro = (size_t)(w * 64 + f * 16 + l15) * 256 + ks * 32 + l4 * 8;
            u16x8 ah = *(const u16x8*)(M2H + ro);
            u16x8 al = *(const u16x8*)(M2L + ro);
            acc[f][0] = mfma16(ah, bh0, acc[f][0]);
            acc[f][0] = mfma16(ah, bl0, acc[f][0]);
            acc[f][0] = mfma16(al, bh0, acc[f][0]);
            acc[f][1] = mfma16(ah, bh1, acc[f][1]);
            acc[f][1] = mfma16(ah, bl1, acc[f][1]);
            acc[f][1] = mfma16(al, bh1, acc[f][1]);
        }
    }
    // epilogue: Out = 1.5*D - 0.5*acc, + bf16 images
#pragma unroll
    for (int f = 0; f < 4; ++f)
#pragma unroll
        for (int cf = 0; cf < 2; ++cf)
#pragma unroll
            for (int i = 0; i < 4; ++i) {
                const int r = w * 64 + f * 16 + l4 * 4 + i;
                const int c = j0 + cf * 16 + l15;
                float v = 1.5f * Dm[r * 256 + c] - 0.5f * acc[f][cf][i];
                Out[r * 256 + c] = v;
                OH[r * 256 + c] = top16(v);
                OL[r * 256 + c] = top16(v - trunc_bf(v));
            }
}

// ---------------- finalize loss_dist ----------------
__global__ __launch_bounds__(256) void findist_kernel(const float* __restrict__ Yfin,
                                                      float* __restrict__ scal) {
    __shared__ float red[256];
    int t = threadIdx.x;
    red[t] = Yfin[t * (DIMD + 1)];
    __syncthreads();
    for (int s2 = 128; s2 > 0; s2 >>= 1) { if (t < s2) red[t] += red[t + s2]; __syncthreads(); }
    if (t == 0) {
        float frobsq = scal[SC_FROB];
        float tr_sqrt = powf(frobsq, 0.25f) * red[0];
        float lc = scal[SC_TRCX] + scal[SC_TRCT] - 2.0f * tr_sqrt;
        scal[SC_LD] = fmaxf(0.0f, scal[SC_LM] + lc);
    }
}

// ---------------- reg: sum(W^2) ----------------
__global__ __launch_bounds__(256) void reg_kernel(const float* __restrict__ W, float* __restrict__ scal) {
    __shared__ float red[256];
    int t = threadIdx.x;
    float s = 0.f;
    int base = blockIdx.x * 1024;
    for (int m = 0; m < 4; ++m) { float w = W[base + m * 256 + t]; s += w * w; }
    red[t] = s;
    __syncthreads();
    for (int s2 = 128; s2 > 0; s2 >>= 1) { if (t < s2) red[t] += red[t + s2]; __syncthreads(); }
    if (t == 0) atomicAdd(&scal[SC_REG], red[0]);
}

// ---------------- KNN v3: MFMA + packed-key bitonic top-16 (spill-free) ----------------
__global__ __launch_bounds__(256, 2) void knn3_kernel(const unsigned short* __restrict__ TmH,
                                                      const unsigned short* __restrict__ TmL,
                                                      const unsigned short* __restrict__ XHs,
                                                      const unsigned short* __restrict__ XLs,
                                                      const float* __restrict__ xsq,
                                                      float* __restrict__ ck, int* __restrict__ ci) {
    __shared__ __align__(16) unsigned char sm2[69632];   // XH 16K | XL 16K | kt[256][36] u32
    unsigned* kt = (unsigned*)(sm2 + 32768);
    const int t = threadIdx.x;
    const int w = t >> 6, lane = t & 63;
    const int l15 = lane & 15, l4 = lane >> 4;
    const int p0 = blockIdx.x * PCHUNK;
    const int swz = (l15 & 7) << 4;

    unsigned sk[16];
#pragma unroll
    for (int s = 0; s < 16; ++s) sk[s] = 0xFFFFFFFFu;

    uint4 ph[4], pl[4];
    {
        const uint4* gh = (const uint4*)(XHs + (size_t)p0 * 256);
        const uint4* gl = (const uint4*)(XLs + (size_t)p0 * 256);
#pragma unroll
        for (int r = 0; r < 4; ++r) { ph[r] = gh[r * 256 + t]; pl[r] = gl[r * 256 + t]; }
    }

#pragma unroll 1
    for (int pc = 0; pc < 4; ++pc) {
        const int pbase = p0 + pc * 32;
#pragma unroll
        for (int r = 0; r < 4; ++r) {
            *(uint4*)(sm2 + (r * 256 + t) * 16) = ph[r];
            *(uint4*)(sm2 + 16384 + (r * 256 + t) * 16) = pl[r];
        }
        __syncthreads();
        f32x4 acc[4][2];
#pragma unroll
        for (int f = 0; f < 4; ++f)
#pragma unroll
            for (int pt = 0; pt < 2; ++pt) { f32x4 z = {0.f, 0.f, 0.f, 0.f}; acc[f][pt] = z; }
#pragma unroll
        for (int ks = 0; ks < 8; ++ks) {
            const int g = (((ks * 4 + l4) << 4)) ^ swz;
            const int b0 = l15 * 512 + g;
            const int b1 = (16 + l15) * 512 + g;
            u16x8 bh0 = *(const u16x8*)(sm2 + b0);
            u16x8 bl0 = *(const u16x8*)(sm2 + 16384 + b0);
            u16x8 bh1 = *(const u16x8*)(sm2 + b1);
            u16x8 bl1 = *(const u16x8*)(sm2 + 16384 + b1);
#pragma unroll
            for (int f = 0; f < 4; ++f) {
                const size_t ro = (size_t)(w * 64 + f * 16 + l15) * 256 + ks * 32 + l4 * 8;
                u16x8 ah = *(const u16x8*)(TmH + ro);
                u16x8 al = *(const u16x8*)(TmL + ro);
                acc[f][0] = mfma16(ah, bh0, acc[f][0]);
                acc[f][0] = mfma16(ah, bl0, acc[f][0]);
                acc[f][0] = mfma16(al, bh0, acc[f][0]);
                acc[f][1] = mfma16(ah, bh1, acc[f][1]);
                acc[f][1] = mfma16(ah, bl1, acc[f][1]);
                acc[f][1] = mfma16(al, bh1, acc[f][1]);
            }
        }
        // kt: packed sortable keys (25-bit key | 7-bit local idx)
#pragma unroll
        for (int pt = 0; pt < 2; ++pt) {
            const int p = pbase + pt * 16 + l15;
            const float xv = xsq[p];
            const bool ok = (p < NPTS);
            const unsigned lidx = (unsigned)(pc * 32 + pt * 16 + l15);
#pragma unroll
            for (int f = 0; f < 4; ++f)
#pragma unroll
                for (int i = 0; i < 4; ++i) {
                    float d2 = ok ? (xv - 2.0f * acc[f][pt][i]) : BIGF;
                    unsigned e = (enc_f32(d2) & 0xFFFFFF80u) | lidx;
                    kt[(w * 64 + f * 16 + l4 * 4 + i) * 36 + pt * 16 + l15] = e;
                }
        }
        __syncthreads();
        if (pc < 3) {
            const uint4* gh = (const uint4*)(XHs + (size_t)(p0 + (pc + 1) * 32) * 256);
            const uint4* gl = (const uint4*)(XLs + (size_t)(p0 + (pc + 1) * 32) * 256);
#pragma unroll
            for (int r = 0; r < 4; ++r) { ph[r] = gh[r * 256 + t]; pl[r] = gl[r * 256 + t]; }
        }
        // selection: bitonic batch-32 -> merge into sorted sk
        {
            unsigned b[32];
#pragma unroll
            for (int c4 = 0; c4 < 8; ++c4) {
                uint4 v = *(const uint4*)(kt + t * 36 + c4 * 4);
                b[c4 * 4 + 0] = v.x; b[c4 * 4 + 1] = v.y;
                b[c4 * 4 + 2] = v.z; b[c4 * 4 + 3] = v.w;
            }
            sort16(b);
            sort16(b + 16);
#pragma unroll
            for (int i = 0; i < 16; ++i) b[i] = umin32(b[i], b[31 - i]);
            clean16(b);
#pragma unroll
            for (int i = 0; i < 16; ++i) sk[i] = umin32(sk[i], b[15 - i]);
            clean16(sk);
        }
        // no extra barrier: next stage writes XH/XL (disjoint from kt); the post-stage
        // __syncthreads orders this phase's kt reads before the next kt writes.
    }
    const int base = t * NCAND + blockIdx.x * 16;
#pragma unroll
    for (int s = 0; s < 16; ++s) {
        ck[base + s] = dec_f32(sk[s] & 0xFFFFFF80u);
        ci[base + s] = p0 + (int)(sk[s] & 127u);
    }
}

// ---------------- KNN fallback (round-1 version, fp32 inputs) ----------------
static __device__ __forceinline__ void knn_load(const float* __restrict__ X, int p0, int pc, int t,
                                                float4 s0[2], float4 s1[2]) {
#pragma unroll
    for (int rep = 0; rep < 2; ++rep) {
        int g = t + rep * 512;
        int row = g >> 5, c0 = (g & 31) * 8;
        int p = p0 + pc * 32 + row;
        if (p < NPTS) {
            s0[rep] = *(const float4*)&X[p * DIMD + c0];
            s1[rep] = *(const float4*)&X[p * DIMD + c0 + 4];
        } else {
            float4 z = {0.f, 0.f, 0.f, 0.f};
            s0[rep] = z; s1[rep] = z;
        }
    }
}
static __device__ __forceinline__ void knn_write(unsigned short* XH, unsigned short* XL, int t,
                                                 const float4 s0[2], const float4 s1[2]) {
#pragma unroll
    for (int rep = 0; rep < 2; ++rep) {
        int g = t + rep * 512;
        int row = g >> 5, c0 = (g & 31) * 8;
        float f[8] = {s0[rep].x, s0[rep].y, s0[rep].z, s0[rep].w,
                      s1[rep].x, s1[rep].y, s1[rep].z, s1[rep].w};
        u16x8 h, lo;
#pragma unroll
        for (int j = 0; j < 8; ++j) {
            unsigned short hb = f2bf(f[j]);
            h[j] = hb;
            lo[j] = f2bf(f[j] - bf2f(hb));
        }
        *(u16x8*)&XH[row * 264 + c0] = h;
        *(u16x8*)&XL[row * 264 + c0] = lo;
    }
}
__global__ __launch_bounds__(512, 2) void knn_kernel(const float* __restrict__ Tm,
                                                     const float* __restrict__ X,
                                                     const float* __restrict__ xsq,
                                                     float* __restrict__ ck, int* __restrict__ ci) {
    __shared__ __align__(16) unsigned char smem[50688];
    unsigned short* XH = (unsigned short*)smem;
    unsigned short* XL = (unsigned short*)(smem + 16896);
    float* ktf = (float*)smem;
    float* tk  = (float*)(smem + 34304);
    int*   ti  = (int*)  (smem + 42496);
    const int t    = threadIdx.x;
    const int w    = t >> 6;
    const int lane = t & 63;
    const int l15  = lane & 15;
    const int l4   = lane >> 4;
    const int p0   = blockIdx.x * PCHUNK;
    const int q0   = blockIdx.y * 128;
    u16x8 aH[8], aL[8];
    {
        const int q = q0 + w * 16 + l15;
        const float* tq = Tm + q * DIMD + l4 * 8;
#pragma unroll
        for (int ks = 0; ks < 8; ++ks) {
            float4 v0 = *(const float4*)(tq + ks * 32);
            float4 v1 = *(const float4*)(tq + ks * 32 + 4);
            float f[8] = {v0.x, v0.y, v0.z, v0.w, v1.x, v1.y, v1.z, v1.w};
            u16x8 h, lo;
#pragma unroll
            for (int j = 0; j < 8; ++j) {
                unsigned short hb = f2bf(f[j]);
                h[j] = hb;
                lo[j] = f2bf(f[j] - bf2f(hb));
            }
            aH[ks] = h; aL[ks] = lo;
        }
    }
    float worst = BIGF; int wslot = 0;
    float4 s0[2], s1[2];
    knn_load(X, p0, 0, t, s0, s1);
    knn_write(XH, XL, t, s0, s1);
#pragma unroll
    for (int h = 0; h < 2; ++h) {
        f32x4 acc[4];
#pragma unroll
        for (int a2 = 0; a2 < 4; ++a2) { f32x4 z = {0.f, 0.f, 0.f, 0.f}; acc[a2] = z; }
#pragma unroll
        for (int pc2 = 0; pc2 < 2; ++pc2) {
            const int pc = 2 * h + pc2;
            __syncthreads();
            if (pc < 3) knn_load(X, p0, pc + 1, t, s0, s1);
#pragma unroll
            for (int ks = 0; ks < 8; ++ks) {
#pragma unroll
                for (int pt = 0; pt < 2; ++pt) {
                    const int off = (pt * 16 + l15) * 264 + ks * 32 + l4 * 8;
                    u16x8 bh = *(const u16x8*)&XH[off];
                    u16x8 bl = *(const u16x8*)&XL[off];
                    acc[pc2 * 2 + pt] = mfma16(aH[ks], bh, acc[pc2 * 2 + pt]);
                    acc[pc2 * 2 + pt] = mfma16(aH[ks], bl, acc[pc2 * 2 + pt]);
                    acc[pc2 * 2 + pt] = mfma16(aL[ks], bh, acc[pc2 * 2 + pt]);
                }
            }
            __syncthreads();
            if (pc2 == 0 && pc < 3) knn_write(XH, XL, t, s0, s1);
        }
#pragma unroll
        for (int pc2 = 0; pc2 < 2; ++pc2) {
#pragma unroll
            for (int pt = 0; pt < 2; ++pt) {
                const int pl = pc2 * 32 + pt * 16 + l15;
                const int p  = p0 + h * 64 + pl;
                const float xv = (p < NPTS) ? xsq[p] : 0.f;
#pragma unroll
                for (int i = 0; i < 4; ++i) {
                    float key = (p < NPTS) ? (xv - 2.0f * acc[pc2 * 2 + pt][i]) : BIGF;
                    ktf[(w * 16 + l4 * 4 + i) * 67 + pl] = key;
                }
            }
        }
        __syncthreads();
        if (t < 128) {
            if (h == 0) {
#pragma unroll
                for (int s = 0; s < 16; ++s) { tk[s * 128 + t] = BIGF; ti[s * 128 + t] = 0x7fffffff; }
            }
            for (int c = 0; c < 64; ++c) {
                float key = ktf[t * 67 + c];
                if (key < worst) {
                    tk[wslot * 128 + t] = key; ti[wslot * 128 + t] = p0 + h * 64 + c;
                    worst = tk[t]; wslot = 0;
#pragma unroll
                    for (int s = 1; s < 16; ++s) {
                        float v = tk[s * 128 + t];
                        if (v > worst) { worst = v; wslot = s; }
                    }
                }
            }
        }
        __syncthreads();
        if (h == 0) knn_write(XH, XL, t, s0, s1);
    }
    if (t < 128) {
        int base = (q0 + t) * NCAND + blockIdx.x * 16;
        for (int s = 0; s < 16; ++s) { ck[base + s] = tk[s * 128 + t]; ci[base + s] = ti[s * 128 + t]; }
    }
}

// ---------------- global top-16 merge per query ----------------
__global__ __launch_bounds__(256) void merge_kernel(const float* __restrict__ ck,
                                                    const int* __restrict__ ci,
                                                    int* __restrict__ post_idx) {
    __shared__ float tk[16][256];
    __shared__ int   ti[16][256];
    __shared__ float rk[256];
    __shared__ int   ri[256];
    __shared__ int   rt2[256];
    __shared__ int   rs2[256];
    int q = blockIdx.x, t = threadIdx.x;
    for (int s = 0; s < 16; ++s) { tk[s][t] = BIGF; ti[s][t] = 0x7fffffff; }
    float worst = BIGF; int wslot = 0;
    for (int e = t; e < NCAND; e += 256) {
        float key = ck[q * NCAND + e];
        if (key < worst) {
            tk[wslot][t] = key; ti[wslot][t] = ci[q * NCAND + e];
            worst = tk[0][t]; wslot = 0;
            for (int s = 1; s < 16; ++s)
                if (tk[s][t] > worst) { worst = tk[s][t]; wslot = s; }
        }
    }
    __syncthreads();
    for (int r = 0; r < 16; ++r) {
        float bk = tk[0][t]; int bi = ti[0][t], bs = 0;
        for (int s = 1; s < 16; ++s) {
            float k2 = tk[s][t]; int i2 = ti[s][t];
            if (k2 < bk || (k2 == bk && i2 < bi)) { bk = k2; bi = i2; bs = s; }
        }
        rk[t] = bk; ri[t] = bi; rt2[t] = t; rs2[t] = bs;
        __syncthreads();
        for (int s2 = 128; s2 > 0; s2 >>= 1) {
            if (t < s2) {
                float ko = rk[t + s2]; int io = ri[t + s2];
                if (ko < rk[t] || (ko == rk[t] && io < ri[t])) {
                    rk[t] = ko; ri[t] = io; rt2[t] = rt2[t + s2]; rs2[t] = rs2[t + s2];
                }
            }
            __syncthreads();
        }
        if (t == rt2[0]) { tk[rs2[0]][t] = BIGF; ti[rs2[0]][t] = 0x7fffffff; }
        if (t == 0) post_idx[q * 16 + r] = ri[0];
        __syncthreads();
    }
}

// ---------------- exact l2 + softmax weights ----------------
__global__ __launch_bounds__(256) void l2sm_kernel(const float* __restrict__ Tm,
                                                   const float* __restrict__ X,
                                                   const int* __restrict__ post_idx,
                                                   float* __restrict__ post_w) {
    __shared__ float l2s[16];
    int b = blockIdx.x, t = threadIdx.x;
    int k = t >> 4, j = t & 15;
    int idx = post_idx[b * 16 + k];
    float s = 0.f;
    for (int i = 0; i < 16; ++i) {
        int d = j + 16 * i;
        float df = Tm[b * DIMD + d] - X[idx * DIMD + d];
        s += df * df;
    }
    for (int off = 8; off; off >>= 1) s += __shfl_down(s, off, 16);
    if (j == 0) l2s[k] = s;
    __syncthreads();
    if (t < 16) {
        float x = -l2s[t] * 10.0f;
        float m = x;
        for (int mm = 8; mm; mm >>= 1) m = fmaxf(m, __shfl_xor(m, mm, 16));
        float e = expf(x - m);
        float ssum = e;
        for (int mm = 8; mm; mm >>= 1) ssum += __shfl_xor(ssum, mm, 16);
        post_w[b * 16 + t] = e / ssum;
    }
}

// ---------------- KL per sample ----------------
__global__ __launch_bounds__(256) void kl_kernel(const int* __restrict__ q_indices,
                                                 const int* __restrict__ pre_indices,
                                                 const float* __restrict__ pre_weights,
                                                 const int* __restrict__ post_idx,
                                                 const float* __restrict__ post_w,
                                                 float* __restrict__ scal) {
    int b = threadIdx.x;
    int qi = q_indices[b];
    int pid[16]; float pw[16]; int sid[16]; float sw[16];
    for (int k = 0; k < 16; ++k) {
        pid[k] = pre_indices[qi * 16 + k];
        pw[k]  = pre_weights[qi * 16 + k];
        sid[k] = post_idx[b * 16 + k];
        sw[k]  = post_w[b * 16 + k];
    }
    float psum = 0.f, qsum = 0.f, kl = 0.f;
    for (int pass = 0; pass < 2; ++pass) {
        for (int i = 0; i < 32; ++i) {
            int c = (i < 16) ? pid[i] : sid[i - 16];
            bool first = true;
            for (int jj = 0; jj < i; ++jj) {
                int cj = (jj < 16) ? pid[jj] : sid[jj - 16];
                if (cj == c) { first = false; break; }
            }
            if (!first) continue;
            float p = 0.f, q = 0.f;
            for (int k2 = 0; k2 < 16; ++k2) {
                if (pid[k2] == c) p += pw[k2];
                if (sid[k2] == c) q += sw[k2];
            }
            p = fmaxf(p, 1e-8f); q = fmaxf(q, 1e-8f);
            if (pass == 0) { psum += p; qsum += q; }
            else {
                float pn = p / psum, qn = q / qsum;
                kl += pn * (logf(pn) - logf(qn));
            }
        }
    }
    atomicAdd(&scal[SC_KNN], kl * (1.0f / 256.0f));
}

// ---------------- final assembly ----------------
__global__ void assemble_kernel(const float* __restrict__ scal, float* __restrict__ out) {
    if (threadIdx.x == 0) {
        float ld = scal[SC_LD], lk = scal[SC_KNN], reg = scal[SC_REG];
        out[0] = ld + lk + 1e-4f * 0.5f * reg;
        out[1] = ld;
        out[2] = lk;
    }
}

extern "C" void kernel_launch(void* const* d_in, const int* in_sizes, int n_in,
                              void* d_out, int out_size, void* d_ws, size_t ws_size,
                              hipStream_t stream) {
    (void)in_sizes; (void)n_in; (void)out_size;
    const float* X           = (const float*)d_in[0];
    const float* W           = (const float*)d_in[1];
    const float* q_batch     = (const float*)d_in[2];
    const float* pre_weights = (const float*)d_in[3];
    const int*   q_indices   = (const int*)d_in[4];
    const int*   pre_indices = (const int*)d_in[5];
    float* out = (float*)d_out;
    float* ws  = (float*)d_ws;

    float* mu_sum = ws + 0;
    float* scal   = ws + 256;
    float* mu_T   = ws + 512;
    float* covX   = ws + 1024;        // raw X^T X accumulator
    float* Tm     = ws + 66560;
    float* cov    = ws + 132096;
    float* G      = ws + 197632;
    float* Ya     = ws + 263168;
    float* Za     = ws + 328704;
    float* Yb     = ws + 394240;
    float* Zb     = ws + 459776;
    float* covXf  = ws + 525312;      // finalized covX (old P region, now free)
    float* xsq    = ws + 590848;
    float* post_w = ws + 691200;
    int*   post_idx = (int*)(ws + 695296);
    float* ck     = ws + 699392;
    int*   ci     = (int*)(ws + 3902464);
    // NS bf16 images overlay the ck region (ck fully consumed by merge before NS runs).
    // FIX (round 3 bug): each 256x256 bf16 image = 131072 B = 32768 FLOAT slots; round-3
    // spaced them 16384 apart -> images overlapped and NS diverged (absmax 128).
    unsigned short* YaH = (unsigned short*)(ws + 699392);
    unsigned short* YaL = (unsigned short*)(ws + 732160);
    unsigned short* ZaH = (unsigned short*)(ws + 764928);
    unsigned short* ZaL = (unsigned short*)(ws + 797696);
    unsigned short* YbH = (unsigned short*)(ws + 830464);
    unsigned short* YbL = (unsigned short*)(ws + 863232);
    unsigned short* ZbH = (unsigned short*)(ws + 896000);
    unsigned short* ZbL = (unsigned short*)(ws + 928768);   // ends 961536 < 3902464 (ck region)
    // bf16 trunc-split images (tier >= 1)
    unsigned short* XHs = (unsigned short*)(ws + 7105536);   // 100352 x 256, row-swizzled
    unsigned short* XLs = (unsigned short*)(ws + 19950592);
    unsigned short* TmH = (unsigned short*)(ws + 32795648);  // 256 x 256 row-major
    unsigned short* TmL = (unsigned short*)(ws + 32828416);
    // transposed image (tier 2)
    unsigned short* XTH = (unsigned short*)(ws + 32845824);  // 256 x 100352
    unsigned short* XTL = (unsigned short*)(ws + 45690880);
    const bool haveIMG = (ws_size >= (size_t)131444736);
    const bool haveXT  = (ws_size >= (size_t)234143744);

    // 0. zero accumulators
    zero_kernel<<<260, 256, 0, stream>>>(ws);
    reg_kernel<<<64, 256, 0, stream>>>(W, scal);
    // 1. X stats (+ bf16 image)
    statsx_kernel<<<196, 256, 0, stream>>>(X, xsq, mu_sum,
                                           haveIMG ? XHs : nullptr, haveIMG ? XLs : nullptr);
    // 2. covX accumulate
    if (haveXT) {
        xtk_kernel<<<392, 256, 0, stream>>>(XHs, XLs, XTH, XTL);
        covx2_kernel<<<dim3(4, NZ2), 256, 0, stream>>>(XTH, XTL, covX);
    } else {
        covx_kernel<<<dim3(4, 4, KSPLIT), 256, 0, stream>>>(X, covX);
    }
    covxfin2_kernel<<<256, 256, 0, stream>>>(covX, mu_sum, covXf, scal);
    // 3. T = q_batch @ W (+ TmH/TmL)
    mm32_kernel<<<dim3(8, 8, 1), 256, 0, stream>>>(q_batch, W, Tm, nullptr,
                                                   nullptr, nullptr,
                                                   haveIMG ? (float*)TmH : nullptr,
                                                   haveIMG ? (float*)TmL : nullptr, 0, nullptr, scal);
    // 4. T stats
    tstats_kernel<<<1, 256, 0, stream>>>(Tm, mu_sum, mu_T, scal);
    // 5. cov = T^T T /256 - muT muT^T + dI
    mm32_kernel<<<dim3(8, 8, 1), 256, 0, stream>>>(Tm, Tm, cov, nullptr,
                                                   nullptr, nullptr, nullptr, nullptr, 2, mu_T, scal);
    // 6. G = cov @ covXf (+frobenius)
    mm32_kernel<<<dim3(8, 8, 1), 256, 0, stream>>>(cov, covXf, G, nullptr,
                                                   nullptr, nullptr, nullptr, nullptr, 1, nullptr, scal);
    // 7. KNN chain (runs before NS so the NS images can overlay ck)
    if (haveIMG) {
        knn3_kernel<<<NPCH, 256, 0, stream>>>(TmH, TmL, XHs, XLs, xsq, ck, ci);
    } else {
        knn_kernel<<<dim3(NPCH, 2, 1), 512, 0, stream>>>(Tm, X, xsq, ck, ci);
    }
    merge_kernel<<<256, 256, 0, stream>>>(ck, ci, post_idx);
    l2sm_kernel<<<256, 256, 0, stream>>>(Tm, X, post_idx, post_w);
    kl_kernel<<<1, 256, 0, stream>>>(q_indices, pre_indices, pre_weights, post_idx, post_w, scal);
    // 8. Newton-Schulz (fused: one launch per iteration)
    inityz2_kernel<<<256, 256, 0, stream>>>(G, scal, Ya, Za, YaH, YaL, ZaH, ZaL);
    {
        float *Yc = Ya, *Zc = Za, *Yn = Yb, *Zn = Zb;
        unsigned short *cYH = YaH, *cYL = YaL, *cZH = ZaH, *cZL = ZaL;
        unsigned short *nYH = YbH, *nYL = YbL, *nZH = ZbH, *nZL = ZbL;
        for (int it = 0; it < NS_ITERS; ++it) {
            nsfused_kernel<<<dim3(8, 2), 256, 0, stream>>>(Yc, Zc, cYH, cYL, cZH, cZL,
                                                           Yn, Zn, nYH, nYL, nZH, nZL);
            float* tf;
            tf = Yc; Yc = Yn; Yn = tf;
            tf = Zc; Zc = Zn; Zn = tf;
            unsigned short* tu;
            tu = cYH; cYH = nYH; nYH = tu;
            tu = cYL; cYL = nYL; nYL = tu;
            tu = cZH; cZH = nZH; nZH = tu;
            tu = cZL; cZL = nZL; nZL = tu;
        }
        findist_kernel<<<1, 256, 0, stream>>>(Yc, scal);
    }
    // 9. assemble
    assemble_kernel<<<1, 64, 0, stream>>>(scal, out);
}

// Round 5
// 1662.378 us; speedup vs baseline: 1.1456x; 1.0253x over previous
//
#include <hip/hip_runtime.h>

// ---------------- problem constants ----------------
#define NPTS   100000
#define DIMD   256
#define BQ     256
#define PCHUNK 128
#define NPCH   782           // ceil(100000/128)
#define NCAND  (NPCH*16)     // candidates per query for final merge
#define NS_ITERS 26
#define KSPLIT  32
#define KSLICE  3136         // old covx: 32*3136 >= 100000
#define KS2    576           // covx2 k-slice (multiple of 32)
#define NZ2    175           // ceil(100352/576)

// scal[] slots
#define SC_LM   0
#define SC_TRCX 1
#define SC_TRCT 2
#define SC_FROB 3
#define SC_KNN  4
#define SC_REG  5
#define SC_LD   6

#define BIGF 3.4e38f

typedef __attribute__((ext_vector_type(4))) float f32x4;
typedef __attribute__((ext_vector_type(8))) unsigned short u16x8;
typedef __attribute__((ext_vector_type(8))) __bf16 bf16x8;

static __device__ __forceinline__ unsigned short f2bf(float f) {
    unsigned u = __float_as_uint(f);
    unsigned r = (u + 0x7fffu + ((u >> 16) & 1u)) >> 16;   // RNE
    return (unsigned short)r;
}
static __device__ __forceinline__ float bf2f(unsigned short h) {
    return __uint_as_float(((unsigned)h) << 16);
}
// truncation-based split: f = hi + lo + O(2^-16 |f|)
static __device__ __forceinline__ unsigned pack_hi(float a, float b) {
    return (__float_as_uint(a) >> 16) | (__float_as_uint(b) & 0xffff0000u);
}
static __device__ __forceinline__ float trunc_bf(float a) {
    return __uint_as_float(__float_as_uint(a) & 0xffff0000u);
}
static __device__ __forceinline__ unsigned short top16(float v) {
    return (unsigned short)(__float_as_uint(v) >> 16);
}
static __device__ __forceinline__ f32x4 mfma16(u16x8 a, u16x8 b, f32x4 c) {
    return __builtin_amdgcn_mfma_f32_16x16x32_bf16(
        __builtin_bit_cast(bf16x8, a), __builtin_bit_cast(bf16x8, b), c, 0, 0, 0);
}

// sortable float<->uint (monotone increasing)
static __device__ __forceinline__ unsigned enc_f32(float f) {
    unsigned u = __float_as_uint(f);
    return u ^ (unsigned)(((int)u >> 31) | 0x80000000);
}
static __device__ __forceinline__ float dec_f32(unsigned e) {
    unsigned u = e ^ ((e & 0x80000000u) ? 0x80000000u : 0xFFFFFFFFu);
    return __uint_as_float(u);
}
static __device__ __forceinline__ unsigned umin32(unsigned a, unsigned b) { return a < b ? a : b; }
static __device__ __forceinline__ void ceu(unsigned& a, unsigned& b) {
    unsigned lo = a < b ? a : b;
    unsigned hi = a < b ? b : a;
    a = lo; b = hi;
}
// bitonic sort ascending, 16 elems, fully static
static __device__ __forceinline__ void sort16(unsigned* r) {
#pragma unroll
    for (int k = 2; k <= 16; k <<= 1)
#pragma unroll
        for (int j = k >> 1; j > 0; j >>= 1)
#pragma unroll
            for (int i = 0; i < 16; ++i) {
                int l = i ^ j;
                if (l > i) {
                    if ((i & k) == 0) ceu(r[i], r[l]);
                    else              ceu(r[l], r[i]);
                }
            }
}
// clean a bitonic 16-sequence into ascending order
static __device__ __forceinline__ void clean16(unsigned* r) {
#pragma unroll
    for (int j = 8; j > 0; j >>= 1)
#pragma unroll
        for (int i = 0; i < 16; ++i) {
            int l = i ^ j;
            if (l > i) ceu(r[i], r[l]);
        }
}
// (key,id) lexicographic helpers for merge2
static __device__ __forceinline__ int lessp(float ka, int ia, float kb, int ib) {
    return (ka < kb) || (ka == kb && ia < ib);
}
static __device__ __forceinline__ void ceup(float& ka, int& ia, float& kb, int& ib) {
    bool sw = lessp(kb, ib, ka, ia);
    float t0 = sw ? kb : ka, t1 = sw ? ka : kb;
    int   u0 = sw ? ib : ia, u1 = sw ? ia : ib;
    ka = t0; kb = t1; ia = u0; ib = u1;
}
static __device__ __forceinline__ void cleanp16(float* k, int* i) {
#pragma unroll
    for (int j = 8; j > 0; j >>= 1)
#pragma unroll
        for (int x = 0; x < 16; ++x) {
            int l = x ^ j;
            if (l > x) ceup(k[x], i[x], k[l], i[l]);
        }
}

// ---------------- zero init ----------------
__global__ __launch_bounds__(256) void zero_kernel(float* ws) {
    int idx = blockIdx.x * 256 + threadIdx.x;
    if (idx < 66560) ws[idx] = 0.0f;   // mu_sum + scal + pad + covX accumulator
}

// ---------------- X stats: column sums + row sq-norms + (opt) swizzled bf16 hi/lo image ----
// 784 blocks x 128 rows (was 196x512): >3 blocks/CU so the serial shfl chain latency hides.
__global__ __launch_bounds__(256) void statsx_kernel(const float* __restrict__ X,
                                                     float* __restrict__ xsq,
                                                     float* __restrict__ mu_sum,
                                                     unsigned short* __restrict__ XHs,
                                                     unsigned short* __restrict__ XLs) {
    int w    = threadIdx.x >> 6;   // wave 0..3
    int lane = threadIdx.x & 63;
    int rbase = blockIdx.x * 128;
    float cs0 = 0.f, cs1 = 0.f, cs2 = 0.f, cs3 = 0.f;
    for (int m = 0; m < 32; ++m) {
        int r = rbase + w + 4 * m;
        if (r < NPTS) {
            float4 v = *(const float4*)&X[r * DIMD + 4 * lane];
            cs0 += v.x; cs1 += v.y; cs2 += v.z; cs3 += v.w;
            float ss = v.x * v.x + v.y * v.y + v.z * v.z + v.w * v.w;
            for (int off = 32; off; off >>= 1) ss += __shfl_down(ss, off);
            if (lane == 0) xsq[r] = ss;
            if (XHs) {
                int g = (lane >> 1) ^ (r & 7);
                int h = lane & 1;
                uint2 hv = { pack_hi(v.x, v.y), pack_hi(v.z, v.w) };
                uint2 lv = { pack_hi(v.x - trunc_bf(v.x), v.y - trunc_bf(v.y)),
                             pack_hi(v.z - trunc_bf(v.z), v.w - trunc_bf(v.w)) };
                *(uint2*)(XHs + (size_t)r * 256 + g * 8 + h * 4) = hv;
                *(uint2*)(XLs + (size_t)r * 256 + g * 8 + h * 4) = lv;
            }
        } else if (XHs) {
            int g = (lane >> 1) ^ (r & 7);
            int h = lane & 1;
            uint2 z2 = {0u, 0u};
            *(uint2*)(XHs + (size_t)r * 256 + g * 8 + h * 4) = z2;
            *(uint2*)(XLs + (size_t)r * 256 + g * 8 + h * 4) = z2;
        }
    }
    atomicAdd(&mu_sum[4 * lane + 0], cs0);
    atomicAdd(&mu_sum[4 * lane + 1], cs1);
    atomicAdd(&mu_sum[4 * lane + 2], cs2);
    atomicAdd(&mu_sum[4 * lane + 3], cs3);
}

// ---------------- transpose bf16 image: XHs[r][d] -> XTH[d][r] (and L) ----------------
__global__ __launch_bounds__(256) void xtk_kernel(const unsigned short* __restrict__ XHs,
                                                  const unsigned short* __restrict__ XLs,
                                                  unsigned short* __restrict__ XTH,
                                                  unsigned short* __restrict__ XTL) {
    __shared__ unsigned short LH[32][268];
    __shared__ unsigned short LL[32][268];
    const int t = threadIdx.x;
#pragma unroll 1
    for (int st = 0; st < 8; ++st) {
        const int r0 = blockIdx.x * 256 + st * 32;
        const int row = t >> 3;
        const int r = r0 + row;
#pragma unroll
        for (int gg = 0; gg < 4; ++gg) {
            int glog = (t & 7) + gg * 8;
            int gphys = glog ^ (r & 7);
            u16x8 h = *(const u16x8*)(XHs + (size_t)r * 256 + gphys * 8);
            u16x8 l = *(const u16x8*)(XLs + (size_t)r * 256 + gphys * 8);
            *(u16x8*)&LH[row][glog * 8] = h;
            *(u16x8*)&LL[row][glog * 8] = l;
        }
        __syncthreads();
        {
            unsigned pk[16];
#pragma unroll
            for (int m = 0; m < 16; ++m)
                pk[m] = (unsigned)LH[2 * m][t] | ((unsigned)LH[2 * m + 1][t] << 16);
            uint4* oh = (uint4*)(XTH + (size_t)t * 100352 + r0);
#pragma unroll
            for (int q = 0; q < 4; ++q)
                oh[q] = make_uint4(pk[4 * q], pk[4 * q + 1], pk[4 * q + 2], pk[4 * q + 3]);
#pragma unroll
            for (int m = 0; m < 16; ++m)
                pk[m] = (unsigned)LL[2 * m][t] | ((unsigned)LL[2 * m + 1][t] << 16);
            uint4* ol = (uint4*)(XTL + (size_t)t * 100352 + r0);
#pragma unroll
            for (int q = 0; q < 4; ++q)
                ol[q] = make_uint4(pk[4 * q], pk[4 * q + 1], pk[4 * q + 2], pk[4 * q + 3]);
        }
        __syncthreads();
    }
}

// ---------------- covX via MFMA (split-bf16, reads transposed image) ----------------
__global__ __launch_bounds__(256) void covx2_kernel(const unsigned short* __restrict__ XTH,
                                                    const unsigned short* __restrict__ XTL,
                                                    float* __restrict__ acc_out) {
    const int quad = blockIdx.x;
    const int qi = quad >> 1, qj = quad & 1;
    const int t = threadIdx.x, w = t >> 6, lane = t & 63;
    const int l15 = lane & 15, l4 = lane >> 4;
    const int k0 = blockIdx.y * KS2;
    const int kend = (k0 + KS2 < 100352) ? (k0 + KS2) : 100352;
    f32x4 acc[2][8];
#pragma unroll
    for (int f = 0; f < 2; ++f)
#pragma unroll
        for (int cf = 0; cf < 8; ++cf) { f32x4 z = {0.f, 0.f, 0.f, 0.f}; acc[f][cf] = z; }
    const size_t rowA0 = (size_t)(qi * 128 + w * 32 + l15) * 100352;
    const size_t rowA1 = (size_t)(qi * 128 + w * 32 + 16 + l15) * 100352;
#pragma unroll 1
    for (int k = k0; k < kend; k += 32) {
        const int ko = k + l4 * 8;
        u16x8 ah0 = *(const u16x8*)(XTH + rowA0 + ko);
        u16x8 al0 = *(const u16x8*)(XTL + rowA0 + ko);
        u16x8 ah1 = *(const u16x8*)(XTH + rowA1 + ko);
        u16x8 al1 = *(const u16x8*)(XTL + rowA1 + ko);
#pragma unroll
        for (int cf = 0; cf < 8; ++cf) {
            const size_t rb = (size_t)(qj * 128 + cf * 16 + l15) * 100352 + ko;
            u16x8 bh = *(const u16x8*)(XTH + rb);
            u16x8 bl = *(const u16x8*)(XTL + rb);
            acc[0][cf] = mfma16(ah0, bh, acc[0][cf]);
            acc[0][cf] = mfma16(ah0, bl, acc[0][cf]);
            acc[0][cf] = mfma16(al0, bh, acc[0][cf]);
            acc[1][cf] = mfma16(ah1, bh, acc[1][cf]);
            acc[1][cf] = mfma16(ah1, bl, acc[1][cf]);
            acc[1][cf] = mfma16(al1, bh, acc[1][cf]);
        }
    }
#pragma unroll
    for (int f = 0; f < 2; ++f)
#pragma unroll
        for (int cf = 0; cf < 8; ++cf)
#pragma unroll
            for (int i = 0; i < 4; ++i) {
                const int r = qi * 128 + w * 32 + f * 16 + l4 * 4 + i;
                const int c = qj * 128 + cf * 16 + l15;
                atomicAdd(&acc_out[r * DIMD + c], acc[f][cf][i]);
            }
}

// ---------------- old covX accumulate (fallback, fp32 VALU) ----------------
__global__ __launch_bounds__(256) void covx_kernel(const float* __restrict__ X,
                                                   float* __restrict__ acc_out) {
    __shared__ float Ais[16][64];
    __shared__ float Ajs[16][64];
    int t = threadIdx.x;
    int i0 = blockIdx.x * 64, j0 = blockIdx.y * 64;
    int ks = blockIdx.z * KSLICE;
    int lr = t >> 4, lc = (t & 15) * 4;
    int tx = t & 15, ty = t >> 4;
    float acc[4][4] = {};
    for (int kb = 0; kb < KSLICE; kb += 16) {
        int k = ks + kb + lr;
        if (k < NPTS) {
            float4 vi = *(const float4*)&X[k * DIMD + i0 + lc];
            float4 vj = *(const float4*)&X[k * DIMD + j0 + lc];
            *(float4*)&Ais[lr][lc] = vi;
            *(float4*)&Ajs[lr][lc] = vj;
        } else {
            float4 z = {0.f, 0.f, 0.f, 0.f};
            *(float4*)&Ais[lr][lc] = z;
            *(float4*)&Ajs[lr][lc] = z;
        }
        __syncthreads();
#pragma unroll
        for (int kk = 0; kk < 16; ++kk) {
            float4 a = *(float4*)&Ais[kk][tx * 4];
            float4 b = *(float4*)&Ajs[kk][ty * 4];
            float av[4] = {a.x, a.y, a.z, a.w};
            float bv[4] = {b.x, b.y, b.z, b.w};
#pragma unroll
            for (int m = 0; m < 4; ++m)
#pragma unroll
                for (int n = 0; n < 4; ++n) acc[m][n] += av[m] * bv[n];
        }
        __syncthreads();
    }
#pragma unroll
    for (int m = 0; m < 4; ++m)
#pragma unroll
        for (int n = 0; n < 4; ++n)
            atomicAdd(&acc_out[(i0 + 4 * tx + m) * DIMD + j0 + 4 * ty + n], acc[m][n]);
}

// ---------------- covX finalize: acc -> covXf (+trace) ----------------
__global__ __launch_bounds__(256) void covxfin2_kernel(const float* __restrict__ acc,
                                                       const float* __restrict__ mu_sum,
                                                       float* __restrict__ covXf,
                                                       float* __restrict__ scal) {
    int idx = blockIdx.x * 256 + threadIdx.x;
    int i = idx >> 8, j = idx & 255;
    const float invN = 1.0f / (float)NPTS;
    float v = acc[idx] * invN - (mu_sum[i] * invN) * (mu_sum[j] * invN) + ((i == j) ? 1e-4f : 0.0f);
    covXf[idx] = v;
    if (i == j) atomicAdd(&scal[SC_TRCX], v);
}

// ---------------- generic 256x256x256 matmul, 32x32 tiles (fp32) ----------------
__global__ __launch_bounds__(256) void mm32_kernel(const float* A, const float* B, float* C, const float* D,
                                                   const float* A2, const float* B2, float* C2, const float* D2,
                                                   int mode, const float* mu, float* scal) {
    __shared__ float As[32][32];
    __shared__ float Bs[32][32];
    __shared__ float red[256];
    int t = threadIdx.x;
    int tx = t & 15, ty = t >> 4;
    int i0 = blockIdx.x * 32, j0 = blockIdx.y * 32;
    int lr = t >> 3, lc = (t & 7) * 4;
    float acc[2][2] = {};
    for (int kb = 0; kb < 256; kb += 32) {
        if (mode == 2) {
            float4 v = *(const float4*)&A[(kb + lr) * DIMD + i0 + lc];
            *(float4*)&As[lr][lc] = v;
        } else {
            float4 v = *(const float4*)&A[(i0 + lr) * DIMD + kb + lc];
            As[lc + 0][lr] = v.x; As[lc + 1][lr] = v.y; As[lc + 2][lr] = v.z; As[lc + 3][lr] = v.w;
        }
        {
            float4 v = *(const float4*)&B[(kb + lr) * DIMD + j0 + lc];
            *(float4*)&Bs[lr][lc] = v;
        }
        __syncthreads();
#pragma unroll
        for (int kk = 0; kk < 32; ++kk) {
            float a0 = As[kk][2 * tx], a1 = As[kk][2 * tx + 1];
            float b0 = Bs[kk][2 * ty], b1 = Bs[kk][2 * ty + 1];
            acc[0][0] += a0 * b0; acc[0][1] += a0 * b1;
            acc[1][0] += a1 * b0; acc[1][1] += a1 * b1;
        }
        __syncthreads();
    }
    float fr = 0.f;
#pragma unroll
    for (int ii = 0; ii < 2; ++ii)
#pragma unroll
        for (int jj = 0; jj < 2; ++jj) {
            int i = i0 + 2 * tx + ii, j = j0 + 2 * ty + jj;
            float v = acc[ii][jj];
            if (mode == 2) {
                v = v * (1.0f / 256.0f) - mu[i] * mu[j] + ((i == j) ? 1e-4f : 0.0f);
                if (i == j) atomicAdd(&scal[SC_TRCT], v);
            }
            C[i * DIMD + j] = v;
            if (mode == 1) fr += v * v;
        }
    if (mode == 0 && C2 != nullptr) {
        unsigned short* TH = (unsigned short*)C2;
        unsigned short* TL = (unsigned short*)const_cast<float*>(D2);
#pragma unroll
        for (int ii = 0; ii < 2; ++ii) {
            int i = i0 + 2 * tx + ii;
            int jc = j0 + 2 * ty;
            float x0 = acc[ii][0], x1 = acc[ii][1];
            *(unsigned*)&TH[i * DIMD + jc] = pack_hi(x0, x1);
            *(unsigned*)&TL[i * DIMD + jc] = pack_hi(x0 - trunc_bf(x0), x1 - trunc_bf(x1));
        }
    }
    if (mode == 1) {
        red[t] = fr; __syncthreads();
        for (int s2 = 128; s2 > 0; s2 >>= 1) { if (t < s2) red[t] += red[t + s2]; __syncthreads(); }
        if (t == 0) atomicAdd(&scal[SC_FROB], red[0]);
    }
}

// ---------------- T stats ----------------
__global__ __launch_bounds__(256) void tstats_kernel(const float* __restrict__ Tm,
                                                     const float* __restrict__ mu_sum,
                                                     float* __restrict__ mu_T,
                                                     float* __restrict__ scal) {
    __shared__ float red[256];
    int j = threadIdx.x;
    float s = 0.f;
    for (int b = 0; b < BQ; ++b) s += Tm[b * DIMD + j];
    float mt = s * (1.0f / 256.0f);
    mu_T[j] = mt;
    float d = mt - mu_sum[j] * (1.0f / (float)NPTS);
    red[j] = d * d;
    __syncthreads();
    for (int s2 = 128; s2 > 0; s2 >>= 1) { if (j < s2) red[j] += red[j + s2]; __syncthreads(); }
    if (j == 0) scal[SC_LM] = red[0];
}

// ---------------- init Y = G/||G||_F (+images), Z = I (+images) ----------------
__global__ __launch_bounds__(256) void inityz2_kernel(const float* __restrict__ G,
                                                      const float* __restrict__ scal,
                                                      float* __restrict__ Y, float* __restrict__ Z,
                                                      unsigned short* __restrict__ YaH,
                                                      unsigned short* __restrict__ YaL,
                                                      unsigned short* __restrict__ ZaH,
                                                      unsigned short* __restrict__ ZaL) {
    int idx = blockIdx.x * 256 + threadIdx.x;
    float invs = rsqrtf(scal[SC_FROB]);
    float y = G[idx] * invs;
    Y[idx] = y;
    YaH[idx] = top16(y);
    YaL[idx] = top16(y - trunc_bf(y));
    bool dg = ((idx >> 8) == (idx & 255));
    Z[idx] = dg ? 1.0f : 0.0f;
    ZaH[idx] = dg ? (unsigned short)0x3F80 : (unsigned short)0;
    ZaL[idx] = 0;
}

// ---------------- fused Newton-Schulz iteration, 16-col slices (32 blocks/launch) ------
// grid (16 col-slices, 2 paths). path0: Yn = 1.5Y - 0.5*Y@(Z@Y[:,j])
//                                path1: Zn = 1.5Z - 0.5*Z@(Y@Z[:,j])
__global__ __launch_bounds__(256) void nsfused_kernel(
        const float* __restrict__ Ycur, const float* __restrict__ Zcur,
        const unsigned short* __restrict__ YH, const unsigned short* __restrict__ YL,
        const unsigned short* __restrict__ ZH, const unsigned short* __restrict__ ZL,
        float* __restrict__ Yn, float* __restrict__ Zn,
        unsigned short* __restrict__ YnH, unsigned short* __restrict__ YnL,
        unsigned short* __restrict__ ZnH, unsigned short* __restrict__ ZnL) {
    __shared__ __align__(16) unsigned short VH[16 * 264];
    __shared__ __align__(16) unsigned short VL[16 * 264];
    __shared__ __align__(16) unsigned short IH[16 * 264];
    __shared__ __align__(16) unsigned short IL[16 * 264];
    const int t = threadIdx.x, w = t >> 6, lane = t & 63;
    const int l15 = lane & 15, l4 = lane >> 4;
    const int j0 = blockIdx.x * 16;
    const unsigned short *M1H, *M1L, *M2H, *M2L, *VsH, *VsL;
    const float* Dm; float* Out; unsigned short *OH, *OL;
    if (blockIdx.y == 0) { M1H = ZH; M1L = ZL; M2H = YH; M2L = YL; VsH = YH; VsL = YL;
                           Dm = Ycur; Out = Yn; OH = YnH; OL = YnL; }
    else                 { M1H = YH; M1L = YL; M2H = ZH; M2L = ZL; VsH = ZH; VsL = ZL;
                           Dm = Zcur; Out = Zn; OH = ZnH; OL = ZnL; }
    // stage V slice -> [col][k] LDS (16 cols x 256 k)
    {
        const int col = t >> 4, k0 = (t & 15) * 16;
#pragma unroll
        for (int m = 0; m < 8; ++m) {
            const int k = k0 + 2 * m;
            unsigned h0 = VsH[(size_t)k * 256 + j0 + col];
            unsigned h1 = VsH[(size_t)(k + 1) * 256 + j0 + col];
            unsigned l0 = VsL[(size_t)k * 256 + j0 + col];
            unsigned l1 = VsL[(size_t)(k + 1) * 256 + j0 + col];
            *(unsigned*)&VH[col * 264 + k] = h0 | (h1 << 16);
            *(unsigned*)&VL[col * 264 + k] = l0 | (l1 << 16);
        }
    }
    __syncthreads();
    f32x4 acc[4];
#pragma unroll
    for (int f = 0; f < 4; ++f) { f32x4 z = {0.f, 0.f, 0.f, 0.f}; acc[f] = z; }
    // GEMM1: I1 = M1 @ V
#pragma unroll
    for (int ks = 0; ks < 8; ++ks) {
        const int bo = l15 * 264 + ks * 32 + l4 * 8;
        u16x8 bh = *(const u16x8*)&VH[bo];
        u16x8 bl = *(const u16x8*)&VL[bo];
#pragma unroll
        for (int f = 0; f < 4; ++f) {
            const size_t ro = (size_t)(w * 64 + f * 16 + l15) * 256 + ks * 32 + l4 * 8;
            u16x8 ah = *(const u16x8*)(M1H + ro);
            u16x8 al = *(const u16x8*)(M1L + ro);
            acc[f] = mfma16(ah, bh, acc[f]);
            acc[f] = mfma16(ah, bl, acc[f]);
            acc[f] = mfma16(al, bh, acc[f]);
        }
    }
    // I1 -> LDS (transposed, bf16 split)
#pragma unroll
    for (int f = 0; f < 4; ++f) {
        float v0 = acc[f][0], v1 = acc[f][1], v2 = acc[f][2], v3 = acc[f][3];
        unsigned h01 = pack_hi(v0, v1), h23 = pack_hi(v2, v3);
        unsigned l01 = pack_hi(v0 - trunc_bf(v0), v1 - trunc_bf(v1));
        unsigned l23 = pack_hi(v2 - trunc_bf(v2), v3 - trunc_bf(v3));
        const int ad = l15 * 264 + w * 64 + f * 16 + l4 * 4;
        *(uint2*)&IH[ad] = make_uint2(h01, h23);
        *(uint2*)&IL[ad] = make_uint2(l01, l23);
    }
    __syncthreads();
    // GEMM2: M2 @ I1
#pragma unroll
    for (int f = 0; f < 4; ++f) { f32x4 z = {0.f, 0.f, 0.f, 0.f}; acc[f] = z; }
#pragma unroll
    for (int ks = 0; ks < 8; ++ks) {
        const int bo = l15 * 264 + ks * 32 + l4 * 8;
        u16x8 bh = *(const u16x8*)&IH[bo];
        u16x8 bl = *(const u16x8*)&IL[bo];
#pragma unroll
        for (int f = 0; f < 4; ++f) {
            const size_t ro = (size_t)(w * 64 + f * 16 + l15) * 256 + ks * 32 + l4 * 8;
            u16x8 ah = *(const u16x8*)(M2H + ro);
            u16x8 al = *(const u16x8*)(M2L + ro);
            acc[f] = mfma16(ah, bh, acc[f]);
            acc[f] = mfma16(ah, bl, acc[f]);
            acc[f] = mfma16(al, bh, acc[f]);
        }
    }
    // epilogue: Out = 1.5*D - 0.5*acc, + bf16 images
#pragma unroll
    for (int f = 0; f < 4; ++f)
#pragma unroll
        for (int i = 0; i < 4; ++i) {
            const int r = w * 64 + f * 16 + l4 * 4 + i;
            const int c = j0 + l15;
            float v = 1.5f * Dm[r * 256 + c] - 0.5f * acc[f][i];
            Out[r * 256 + c] = v;
            OH[r * 256 + c] = top16(v);
            OL[r * 256 + c] = top16(v - trunc_bf(v));
        }
}

// ---------------- finalize loss_dist ----------------
__global__ __launch_bounds__(256) void findist_kernel(const float* __restrict__ Yfin,
                                                      float* __restrict__ scal) {
    __shared__ float red[256];
    int t = threadIdx.x;
    red[t] = Yfin[t * (DIMD + 1)];
    __syncthreads();
    for (int s2 = 128; s2 > 0; s2 >>= 1) { if (t < s2) red[t] += red[t + s2]; __syncthreads(); }
    if (t == 0) {
        float frobsq = scal[SC_FROB];
        float tr_sqrt = powf(frobsq, 0.25f) * red[0];
        float lc = scal[SC_TRCX] + scal[SC_TRCT] - 2.0f * tr_sqrt;
        scal[SC_LD] = fmaxf(0.0f, scal[SC_LM] + lc);
    }
}

// ---------------- reg: sum(W^2) ----------------
__global__ __launch_bounds__(256) void reg_kernel(const float* __restrict__ W, float* __restrict__ scal) {
    __shared__ float red[256];
    int t = threadIdx.x;
    float s = 0.f;
    int base = blockIdx.x * 1024;
    for (int m = 0; m < 4; ++m) { float w = W[base + m * 256 + t]; s += w * w; }
    red[t] = s;
    __syncthreads();
    for (int s2 = 128; s2 > 0; s2 >>= 1) { if (t < s2) red[t] += red[t + s2]; __syncthreads(); }
    if (t == 0) atomicAdd(&scal[SC_REG], red[0]);
}

// ---------------- KNN v3b: MFMA + packed-key bitonic top-16, spill-free ----------------
// vs round-4: no register prefetch (stage global->LDS with short live range), selection in
// two 16-batches (b[16] not b[32]).  Peak ~100 VGPR -> no scratch.
__global__ __launch_bounds__(256, 2) void knn3_kernel(const unsigned short* __restrict__ TmH,
                                                      const unsigned short* __restrict__ TmL,
                                                      const unsigned short* __restrict__ XHs,
                                                      const unsigned short* __restrict__ XLs,
                                                      const float* __restrict__ xsq,
                                                      float* __restrict__ ck, int* __restrict__ ci) {
    __shared__ __align__(16) unsigned char sm2[69632];   // XH 16K | XL 16K | kt[256][36] u32
    unsigned* kt = (unsigned*)(sm2 + 32768);
    const int t = threadIdx.x;
    const int w = t >> 6, lane = t & 63;
    const int l15 = lane & 15, l4 = lane >> 4;
    const int p0 = blockIdx.x * PCHUNK;
    const int swz = (l15 & 7) << 4;

    unsigned sk[16];
#pragma unroll
    for (int s = 0; s < 16; ++s) sk[s] = 0xFFFFFFFFu;

#pragma unroll 1
    for (int pc = 0; pc < 4; ++pc) {
        const int pbase = p0 + pc * 32;
        {
            const uint4* gh = (const uint4*)(XHs + (size_t)pbase * 256);
            const uint4* gl = (const uint4*)(XLs + (size_t)pbase * 256);
#pragma unroll
            for (int r = 0; r < 4; ++r) {
                uint4 vh = gh[r * 256 + t];
                uint4 vl = gl[r * 256 + t];
                *(uint4*)(sm2 + (r * 256 + t) * 16) = vh;
                *(uint4*)(sm2 + 16384 + (r * 256 + t) * 16) = vl;
            }
        }
        __syncthreads();
        f32x4 acc[4][2];
#pragma unroll
        for (int f = 0; f < 4; ++f)
#pragma unroll
            for (int pt = 0; pt < 2; ++pt) { f32x4 z = {0.f, 0.f, 0.f, 0.f}; acc[f][pt] = z; }
#pragma unroll
        for (int ks = 0; ks < 8; ++ks) {
            const int g = (((ks * 4 + l4) << 4)) ^ swz;
            const int b0 = l15 * 512 + g;
            const int b1 = (16 + l15) * 512 + g;
            u16x8 bh0 = *(const u16x8*)(sm2 + b0);
            u16x8 bl0 = *(const u16x8*)(sm2 + 16384 + b0);
            u16x8 bh1 = *(const u16x8*)(sm2 + b1);
            u16x8 bl1 = *(const u16x8*)(sm2 + 16384 + b1);
#pragma unroll
            for (int f = 0; f < 4; ++f) {
                const size_t ro = (size_t)(w * 64 + f * 16 + l15) * 256 + ks * 32 + l4 * 8;
                u16x8 ah = *(const u16x8*)(TmH + ro);
                u16x8 al = *(const u16x8*)(TmL + ro);
                acc[f][0] = mfma16(ah, bh0, acc[f][0]);
                acc[f][0] = mfma16(ah, bl0, acc[f][0]);
                acc[f][0] = mfma16(al, bh0, acc[f][0]);
                acc[f][1] = mfma16(ah, bh1, acc[f][1]);
                acc[f][1] = mfma16(ah, bl1, acc[f][1]);
                acc[f][1] = mfma16(al, bh1, acc[f][1]);
            }
        }
        // kt: packed sortable keys (25-bit key | 7-bit local idx)
#pragma unroll
        for (int pt = 0; pt < 2; ++pt) {
            const int p = pbase + pt * 16 + l15;
            const float xv = xsq[p];
            const bool ok = (p < NPTS);
            const unsigned lidx = (unsigned)(pc * 32 + pt * 16 + l15);
#pragma unroll
            for (int f = 0; f < 4; ++f)
#pragma unroll
                for (int i = 0; i < 4; ++i) {
                    float d2 = ok ? (xv - 2.0f * acc[f][pt][i]) : BIGF;
                    unsigned e = (enc_f32(d2) & 0xFFFFFF80u) | lidx;
                    kt[(w * 64 + f * 16 + l4 * 4 + i) * 36 + pt * 16 + l15] = e;
                }
        }
        __syncthreads();
        // selection: two sorted 16-batches merged into sk
#pragma unroll
        for (int hb = 0; hb < 2; ++hb) {
            unsigned b[16];
#pragma unroll
            for (int c4 = 0; c4 < 4; ++c4) {
                uint4 v = *(const uint4*)(kt + t * 36 + hb * 16 + c4 * 4);
                b[c4 * 4 + 0] = v.x; b[c4 * 4 + 1] = v.y;
                b[c4 * 4 + 2] = v.z; b[c4 * 4 + 3] = v.w;
            }
            sort16(b);
#pragma unroll
            for (int i = 0; i < 16; ++i) sk[i] = umin32(sk[i], b[15 - i]);
            clean16(sk);
        }
        // next stage writes XH/XL (disjoint from kt); barrier above orders kt reads.
    }
    const int base = t * NCAND + blockIdx.x * 16;
#pragma unroll
    for (int s = 0; s < 16; ++s) {
        ck[base + s] = dec_f32(sk[s] & 0xFFFFFF80u);
        ci[base + s] = p0 + (int)(sk[s] & 127u);
    }
}

// ---------------- KNN fallback (round-1 version, fp32 inputs) ----------------
static __device__ __forceinline__ void knn_load(const float* __restrict__ X, int p0, int pc, int t,
                                                float4 s0[2], float4 s1[2]) {
#pragma unroll
    for (int rep = 0; rep < 2; ++rep) {
        int g = t + rep * 512;
        int row = g >> 5, c0 = (g & 31) * 8;
        int p = p0 + pc * 32 + row;
        if (p < NPTS) {
            s0[rep] = *(const float4*)&X[p * DIMD + c0];
            s1[rep] = *(const float4*)&X[p * DIMD + c0 + 4];
        } else {
            float4 z = {0.f, 0.f, 0.f, 0.f};
            s0[rep] = z; s1[rep] = z;
        }
    }
}
static __device__ __forceinline__ void knn_write(unsigned short* XH, unsigned short* XL, int t,
                                                 const float4 s0[2], const float4 s1[2]) {
#pragma unroll
    for (int rep = 0; rep < 2; ++rep) {
        int g = t + rep * 512;
        int row = g >> 5, c0 = (g & 31) * 8;
        float f[8] = {s0[rep].x, s0[rep].y, s0[rep].z, s0[rep].w,
                      s1[rep].x, s1[rep].y, s1[rep].z, s1[rep].w};
        u16x8 h, lo;
#pragma unroll
        for (int j = 0; j < 8; ++j) {
            unsigned short hb = f2bf(f[j]);
            h[j] = hb;
            lo[j] = f2bf(f[j] - bf2f(hb));
        }
        *(u16x8*)&XH[row * 264 + c0] = h;
        *(u16x8*)&XL[row * 264 + c0] = lo;
    }
}
__global__ __launch_bounds__(512, 2) void knn_kernel(const float* __restrict__ Tm,
                                                     const float* __restrict__ X,
                                                     const float* __restrict__ xsq,
                                                     float* __restrict__ ck, int* __restrict__ ci) {
    __shared__ __align__(16) unsigned char smem[50688];
    unsigned short* XH = (unsigned short*)smem;
    unsigned short* XL = (unsigned short*)(smem + 16896);
    float* ktf = (float*)smem;
    float* tk  = (float*)(smem + 34304);
    int*   ti  = (int*)  (smem + 42496);
    const int t    = threadIdx.x;
    const int w    = t >> 6;
    const int lane = t & 63;
    const int l15  = lane & 15;
    const int l4   = lane >> 4;
    const int p0   = blockIdx.x * PCHUNK;
    const int q0   = blockIdx.y * 128;
    u16x8 aH[8], aL[8];
    {
        const int q = q0 + w * 16 + l15;
        const float* tq = Tm + q * DIMD + l4 * 8;
#pragma unroll
        for (int ks = 0; ks < 8; ++ks) {
            float4 v0 = *(const float4*)(tq + ks * 32);
            float4 v1 = *(const float4*)(tq + ks * 32 + 4);
            float f[8] = {v0.x, v0.y, v0.z, v0.w, v1.x, v1.y, v1.z, v1.w};
            u16x8 h, lo;
#pragma unroll
            for (int j = 0; j < 8; ++j) {
                unsigned short hb = f2bf(f[j]);
                h[j] = hb;
                lo[j] = f2bf(f[j] - bf2f(hb));
            }
            aH[ks] = h; aL[ks] = lo;
        }
    }
    float worst = BIGF; int wslot = 0;
    float4 s0[2], s1[2];
    knn_load(X, p0, 0, t, s0, s1);
    knn_write(XH, XL, t, s0, s1);
#pragma unroll
    for (int h = 0; h < 2; ++h) {
        f32x4 acc[4];
#pragma unroll
        for (int a2 = 0; a2 < 4; ++a2) { f32x4 z = {0.f, 0.f, 0.f, 0.f}; acc[a2] = z; }
#pragma unroll
        for (int pc2 = 0; pc2 < 2; ++pc2) {
            const int pc = 2 * h + pc2;
            __syncthreads();
            if (pc < 3) knn_load(X, p0, pc + 1, t, s0, s1);
#pragma unroll
            for (int ks = 0; ks < 8; ++ks) {
#pragma unroll
                for (int pt = 0; pt < 2; ++pt) {
                    const int off = (pt * 16 + l15) * 264 + ks * 32 + l4 * 8;
                    u16x8 bh = *(const u16x8*)&XH[off];
                    u16x8 bl = *(const u16x8*)&XL[off];
                    acc[pc2 * 2 + pt] = mfma16(aH[ks], bh, acc[pc2 * 2 + pt]);
                    acc[pc2 * 2 + pt] = mfma16(aH[ks], bl, acc[pc2 * 2 + pt]);
                    acc[pc2 * 2 + pt] = mfma16(aL[ks], bh, acc[pc2 * 2 + pt]);
                }
            }
            __syncthreads();
            if (pc2 == 0 && pc < 3) knn_write(XH, XL, t, s0, s1);
        }
#pragma unroll
        for (int pc2 = 0; pc2 < 2; ++pc2) {
#pragma unroll
            for (int pt = 0; pt < 2; ++pt) {
                const int pl = pc2 * 32 + pt * 16 + l15;
                const int p  = p0 + h * 64 + pl;
                const float xv = (p < NPTS) ? xsq[p] : 0.f;
#pragma unroll
                for (int i = 0; i < 4; ++i) {
                    float key = (p < NPTS) ? (xv - 2.0f * acc[pc2 * 2 + pt][i]) : BIGF;
                    ktf[(w * 16 + l4 * 4 + i) * 67 + pl] = key;
                }
            }
        }
        __syncthreads();
        if (t < 128) {
            if (h == 0) {
#pragma unroll
                for (int s = 0; s < 16; ++s) { tk[s * 128 + t] = BIGF; ti[s * 128 + t] = 0x7fffffff; }
            }
            for (int c = 0; c < 64; ++c) {
                float key = ktf[t * 67 + c];
                if (key < worst) {
                    tk[wslot * 128 + t] = key; ti[wslot * 128 + t] = p0 + h * 64 + c;
                    worst = tk[t]; wslot = 0;
#pragma unroll
                    for (int s = 1; s < 16; ++s) {
                        float v = tk[s * 128 + t];
                        if (v > worst) { worst = v; wslot = s; }
                    }
                }
            }
        }
        __syncthreads();
        if (h == 0) knn_write(XH, XL, t, s0, s1);
    }
    if (t < 128) {
        int base = (q0 + t) * NCAND + blockIdx.x * 16;
        for (int s = 0; s < 16; ++s) { ck[base + s] = tk[s * 128 + t]; ci[base + s] = ti[s * 128 + t]; }
    }
}

// ---------------- merge v2: sorted-run early-exit scan + LDS bitonic tree ----------------
// Requires each 16-run of ck/ci sorted ascending by (key,id) -- knn3 guarantees this.
__global__ __launch_bounds__(256) void merge2_kernel(const float* __restrict__ ck,
                                                     const int* __restrict__ ci,
                                                     int* __restrict__ post_idx) {
    __shared__ float km[16 * 256];
    __shared__ int   im[16 * 256];
    const int q = blockIdx.x, t = threadIdx.x;
    float sk[16]; int si[16];
#pragma unroll
    for (int s = 0; s < 16; ++s) { sk[s] = BIGF; si[s] = 0x7fffffff; }
    // scan whole sorted runs per thread, early exit when run elem >= local worst
#pragma unroll 1
    for (int run = t; run < NPCH; run += 256) {
        const float* rk = ck + (size_t)q * NCAND + run * 16;
        const int*   ri = ci + (size_t)q * NCAND + run * 16;
#pragma unroll 1
        for (int s = 0; s < 16; ++s) {
            float k = rk[s]; int id = ri[s];
            if (!lessp(k, id, sk[15], si[15])) break;   // rest of run is >= worst
            // sorted insert (shift down from slot 15)
#pragma unroll
            for (int j = 15; j > 0; --j) {
                bool a = lessp(k, id, sk[j - 1], si[j - 1]);
                bool b = lessp(k, id, sk[j], si[j]);
                float nk = a ? sk[j - 1] : (b ? k : sk[j]);
                int   ni = a ? si[j - 1] : (b ? id : si[j]);
                sk[j] = nk; si[j] = ni;
            }
            bool c = lessp(k, id, sk[0], si[0]);
            float nk0 = c ? k : sk[0]; int ni0 = c ? id : si[0];
            sk[0] = nk0; si[0] = ni0;
        }
    }
    // tree-merge 256 sorted lists -> 1
#pragma unroll
    for (int s = 0; s < 16; ++s) { km[s * 256 + t] = sk[s]; im[s * 256 + t] = si[s]; }
    __syncthreads();
    for (int off = 128; off > 0; off >>= 1) {
        if (t < off) {
            float bk[16]; int bi[16];
#pragma unroll
            for (int s = 0; s < 16; ++s) { bk[s] = km[s * 256 + t + off]; bi[s] = im[s * 256 + t + off]; }
#pragma unroll
            for (int s = 0; s < 16; ++s) {
                float ak = sk[s];  int ai = si[s];
                float ok = bk[15 - s]; int oi = bi[15 - s];
                bool a = lessp(ak, ai, ok, oi);
                sk[s] = a ? ak : ok; si[s] = a ? ai : oi;
            }
            cleanp16(sk, si);
#pragma unroll
            for (int s = 0; s < 16; ++s) { km[s * 256 + t] = sk[s]; im[s * 256 + t] = si[s]; }
        }
        __syncthreads();
    }
    if (t == 0) {
#pragma unroll
        for (int r = 0; r < 16; ++r) post_idx[q * 16 + r] = si[r];
    }
}

// ---------------- old merge (fallback path: runs unsorted) ----------------
__global__ __launch_bounds__(256) void merge_kernel(const float* __restrict__ ck,
                                                    const int* __restrict__ ci,
                                                    int* __restrict__ post_idx) {
    __shared__ float tk[16][256];
    __shared__ int   ti[16][256];
    __shared__ float rk[256];
    __shared__ int   ri[256];
    __shared__ int   rt2[256];
    __shared__ int   rs2[256];
    int q = blockIdx.x, t = threadIdx.x;
    for (int s = 0; s < 16; ++s) { tk[s][t] = BIGF; ti[s][t] = 0x7fffffff; }
    float worst = BIGF; int wslot = 0;
    for (int e = t; e < NCAND; e += 256) {
        float key = ck[q * NCAND + e];
        if (key < worst) {
            tk[wslot][t] = key; ti[wslot][t] = ci[q * NCAND + e];
            worst = tk[0][t]; wslot = 0;
            for (int s = 1; s < 16; ++s)
                if (tk[s][t] > worst) { worst = tk[s][t]; wslot = s; }
        }
    }
    __syncthreads();
    for (int r = 0; r < 16; ++r) {
        float bk = tk[0][t]; int bi = ti[0][t], bs = 0;
        for (int s = 1; s < 16; ++s) {
            float k2 = tk[s][t]; int i2 = ti[s][t];
            if (k2 < bk || (k2 == bk && i2 < bi)) { bk = k2; bi = i2; bs = s; }
        }
        rk[t] = bk; ri[t] = bi; rt2[t] = t; rs2[t] = bs;
        __syncthreads();
        for (int s2 = 128; s2 > 0; s2 >>= 1) {
            if (t < s2) {
                float ko = rk[t + s2]; int io = ri[t + s2];
                if (ko < rk[t] || (ko == rk[t] && io < ri[t])) {
                    rk[t] = ko; ri[t] = io; rt2[t] = rt2[t + s2]; rs2[t] = rs2[t + s2];
                }
            }
            __syncthreads();
        }
        if (t == rt2[0]) { tk[rs2[0]][t] = BIGF; ti[rs2[0]][t] = 0x7fffffff; }
        if (t == 0) post_idx[q * 16 + r] = ri[0];
        __syncthreads();
    }
}

// ---------------- exact l2 + softmax weights ----------------
__global__ __launch_bounds__(256) void l2sm_kernel(const float* __restrict__ Tm,
                                                   const float* __restrict__ X,
                                                   const int* __restrict__ post_idx,
                                                   float* __restrict__ post_w) {
    __shared__ float l2s[16];
    int b = blockIdx.x, t = threadIdx.x;
    int k = t >> 4, j = t & 15;
    int idx = post_idx[b * 16 + k];
    float s = 0.f;
    for (int i = 0; i < 16; ++i) {
        int d = j + 16 * i;
        float df = Tm[b * DIMD + d] - X[idx * DIMD + d];
        s += df * df;
    }
    for (int off = 8; off; off >>= 1) s += __shfl_down(s, off, 16);
    if (j == 0) l2s[k] = s;
    __syncthreads();
    if (t < 16) {
        float x = -l2s[t] * 10.0f;
        float m = x;
        for (int mm = 8; mm; mm >>= 1) m = fmaxf(m, __shfl_xor(m, mm, 16));
        float e = expf(x - m);
        float ssum = e;
        for (int mm = 8; mm; mm >>= 1) ssum += __shfl_xor(ssum, mm, 16);
        post_w[b * 16 + t] = e / ssum;
    }
}

// ---------------- KL per sample ----------------
__global__ __launch_bounds__(256) void kl_kernel(const int* __restrict__ q_indices,
                                                 const int* __restrict__ pre_indices,
                                                 const float* __restrict__ pre_weights,
                                                 const int* __restrict__ post_idx,
                                                 const float* __restrict__ post_w,
                                                 float* __restrict__ scal) {
    int b = threadIdx.x;
    int qi = q_indices[b];
    int pid[16]; float pw[16]; int sid[16]; float sw[16];
    for (int k = 0; k < 16; ++k) {
        pid[k] = pre_indices[qi * 16 + k];
        pw[k]  = pre_weights[qi * 16 + k];
        sid[k] = post_idx[b * 16 + k];
        sw[k]  = post_w[b * 16 + k];
    }
    float psum = 0.f, qsum = 0.f, kl = 0.f;
    for (int pass = 0; pass < 2; ++pass) {
        for (int i = 0; i < 32; ++i) {
            int c = (i < 16) ? pid[i] : sid[i - 16];
            bool first = true;
            for (int jj = 0; jj < i; ++jj) {
                int cj = (jj < 16) ? pid[jj] : sid[jj - 16];
                if (cj == c) { first = false; break; }
            }
            if (!first) continue;
            float p = 0.f, q = 0.f;
            for (int k2 = 0; k2 < 16; ++k2) {
                if (pid[k2] == c) p += pw[k2];
                if (sid[k2] == c) q += sw[k2];
            }
            p = fmaxf(p, 1e-8f); q = fmaxf(q, 1e-8f);
            if (pass == 0) { psum += p; qsum += q; }
            else {
                float pn = p / psum, qn = q / qsum;
                kl += pn * (logf(pn) - logf(qn));
            }
        }
    }
    atomicAdd(&scal[SC_KNN], kl * (1.0f / 256.0f));
}

// ---------------- final assembly ----------------
__global__ void assemble_kernel(const float* __restrict__ scal, float* __restrict__ out) {
    if (threadIdx.x == 0) {
        float ld = scal[SC_LD], lk = scal[SC_KNN], reg = scal[SC_REG];
        out[0] = ld + lk + 1e-4f * 0.5f * reg;
        out[1] = ld;
        out[2] = lk;
    }
}

extern "C" void kernel_launch(void* const* d_in, const int* in_sizes, int n_in,
                              void* d_out, int out_size, void* d_ws, size_t ws_size,
                              hipStream_t stream) {
    (void)in_sizes; (void)n_in; (void)out_size;
    const float* X           = (const float*)d_in[0];
    const float* W           = (const float*)d_in[1];
    const float* q_batch     = (const float*)d_in[2];
    const float* pre_weights = (const float*)d_in[3];
    const int*   q_indices   = (const int*)d_in[4];
    const int*   pre_indices = (const int*)d_in[5];
    float* out = (float*)d_out;
    float* ws  = (float*)d_ws;

    float* mu_sum = ws + 0;
    float* scal   = ws + 256;
    float* mu_T   = ws + 512;
    float* covX   = ws + 1024;        // raw X^T X accumulator
    float* Tm     = ws + 66560;
    float* cov    = ws + 132096;
    float* G      = ws + 197632;
    float* Ya     = ws + 263168;
    float* Za     = ws + 328704;
    float* Yb     = ws + 394240;
    float* Zb     = ws + 459776;
    float* covXf  = ws + 525312;
    float* xsq    = ws + 590848;
    float* post_w = ws + 691200;
    int*   post_idx = (int*)(ws + 695296);
    float* ck     = ws + 699392;
    int*   ci     = (int*)(ws + 3902464);
    // NS bf16 images overlay the ck region (ck fully consumed by merge before NS runs).
    // Each 256x256 bf16 image = 32768 FLOAT slots (round-3 bug: was 16384 -> overlap).
    unsigned short* YaH = (unsigned short*)(ws + 699392);
    unsigned short* YaL = (unsigned short*)(ws + 732160);
    unsigned short* ZaH = (unsigned short*)(ws + 764928);
    unsigned short* ZaL = (unsigned short*)(ws + 797696);
    unsigned short* YbH = (unsigned short*)(ws + 830464);
    unsigned short* YbL = (unsigned short*)(ws + 863232);
    unsigned short* ZbH = (unsigned short*)(ws + 896000);
    unsigned short* ZbL = (unsigned short*)(ws + 928768);   // ends 961536 < 3902464
    // bf16 trunc-split images (tier >= 1)
    unsigned short* XHs = (unsigned short*)(ws + 7105536);   // 100352 x 256, row-swizzled
    unsigned short* XLs = (unsigned short*)(ws + 19950592);
    unsigned short* TmH = (unsigned short*)(ws + 32795648);  // 256 x 256 row-major
    unsigned short* TmL = (unsigned short*)(ws + 32828416);
    // transposed image (tier 2)
    unsigned short* XTH = (unsigned short*)(ws + 32845824);  // 256 x 100352
    unsigned short* XTL = (unsigned short*)(ws + 45690880);
    const bool haveIMG = (ws_size >= (size_t)131444736);
    const bool haveXT  = (ws_size >= (size_t)234143744);

    // 0. zero accumulators
    zero_kernel<<<260, 256, 0, stream>>>(ws);
    reg_kernel<<<64, 256, 0, stream>>>(W, scal);
    // 1. X stats (+ bf16 image)
    statsx_kernel<<<784, 256, 0, stream>>>(X, xsq, mu_sum,
                                           haveIMG ? XHs : nullptr, haveIMG ? XLs : nullptr);
    // 2. covX accumulate
    if (haveXT) {
        xtk_kernel<<<392, 256, 0, stream>>>(XHs, XLs, XTH, XTL);
        covx2_kernel<<<dim3(4, NZ2), 256, 0, stream>>>(XTH, XTL, covX);
    } else {
        covx_kernel<<<dim3(4, 4, KSPLIT), 256, 0, stream>>>(X, covX);
    }
    covxfin2_kernel<<<256, 256, 0, stream>>>(covX, mu_sum, covXf, scal);
    // 3. T = q_batch @ W (+ TmH/TmL)
    mm32_kernel<<<dim3(8, 8, 1), 256, 0, stream>>>(q_batch, W, Tm, nullptr,
                                                   nullptr, nullptr,
                                                   haveIMG ? (float*)TmH : nullptr,
                                                   haveIMG ? (float*)TmL : nullptr, 0, nullptr, scal);
    // 4. T stats
    tstats_kernel<<<1, 256, 0, stream>>>(Tm, mu_sum, mu_T, scal);
    // 5. cov = T^T T /256 - muT muT^T + dI
    mm32_kernel<<<dim3(8, 8, 1), 256, 0, stream>>>(Tm, Tm, cov, nullptr,
                                                   nullptr, nullptr, nullptr, nullptr, 2, mu_T, scal);
    // 6. G = cov @ covXf (+frobenius)
    mm32_kernel<<<dim3(8, 8, 1), 256, 0, stream>>>(cov, covXf, G, nullptr,
                                                   nullptr, nullptr, nullptr, nullptr, 1, nullptr, scal);
    // 7. KNN chain (runs before NS so the NS images can overlay ck)
    if (haveIMG) {
        knn3_kernel<<<NPCH, 256, 0, stream>>>(TmH, TmL, XHs, XLs, xsq, ck, ci);
        merge2_kernel<<<256, 256, 0, stream>>>(ck, ci, post_idx);
    } else {
        knn_kernel<<<dim3(NPCH, 2, 1), 512, 0, stream>>>(Tm, X, xsq, ck, ci);
        merge_kernel<<<256, 256, 0, stream>>>(ck, ci, post_idx);
    }
    l2sm_kernel<<<256, 256, 0, stream>>>(Tm, X, post_idx, post_w);
    kl_kernel<<<1, 256, 0, stream>>>(q_indices, pre_indices, pre_weights, post_idx, post_w, scal);
    // 8. Newton-Schulz (fused: one launch per iteration, 32 blocks)
    inityz2_kernel<<<256, 256, 0, stream>>>(G, scal, Ya, Za, YaH, YaL, ZaH, ZaL);
    {
        float *Yc = Ya, *Zc = Za, *Yn = Yb, *Zn = Zb;
        unsigned short *cYH = YaH, *cYL = YaL, *cZH = ZaH, *cZL = ZaL;
        unsigned short *nYH = YbH, *nYL = YbL, *nZH = ZbH, *nZL = ZbL;
        for (int it = 0; it < NS_ITERS; ++it) {
            nsfused_kernel<<<dim3(16, 2), 256, 0, stream>>>(Yc, Zc, cYH, cYL, cZH, cZL,
                                                            Yn, Zn, nYH, nYL, nZH, nZL);
            float* tf;
            tf = Yc; Yc = Yn; Yn = tf;
            tf = Zc; Zc = Zn; Zn = tf;
            unsigned short* tu;
            tu = cYH; cYH = nYH; nYH = tu;
            tu = cYL; cYL = nYL; nYL = tu;
            tu = cZH; cZH = nZH; nZH = tu;
            tu = cZL; cZL = nZL; nZL = tu;
        }
        findist_kernel<<<1, 256, 0, stream>>>(Yc, scal);
    }
    // 9. assemble
    assemble_kernel<<<1, 64, 0, stream>>>(scal, out);
}

// Round 6
// 1379.219 us; speedup vs baseline: 1.3808x; 1.2053x over previous
//
#include <hip/hip_runtime.h>

// ---------------- problem constants ----------------
#define NPTS   100000
#define DIMD   256
#define BQ     256
#define PCHUNK 128
#define NPCH   782           // ceil(100000/128)
#define NCAND  (NPCH*16)     // candidates per query for final merge
#define NS_ITERS 26
#define KSPLIT  32
#define KSLICE  3136         // old covx: 32*3136 >= 100000
#define KS2    576           // covx2 k-slice (multiple of 32)
#define NZ2    175           // ceil(100352/576)

// scal[] slots
#define SC_LM   0
#define SC_TRCX 1
#define SC_TRCT 2
#define SC_FROB 3
#define SC_KNN  4
#define SC_REG  5
#define SC_LD   6

#define BIGF 3.4e38f

typedef __attribute__((ext_vector_type(4))) float f32x4;
typedef __attribute__((ext_vector_type(8))) unsigned short u16x8;
typedef __attribute__((ext_vector_type(8))) __bf16 bf16x8;

static __device__ __forceinline__ unsigned short f2bf(float f) {
    unsigned u = __float_as_uint(f);
    unsigned r = (u + 0x7fffu + ((u >> 16) & 1u)) >> 16;   // RNE
    return (unsigned short)r;
}
static __device__ __forceinline__ float bf2f(unsigned short h) {
    return __uint_as_float(((unsigned)h) << 16);
}
// truncation-based split: f = hi + lo + O(2^-16 |f|)
static __device__ __forceinline__ unsigned pack_hi(float a, float b) {
    return (__float_as_uint(a) >> 16) | (__float_as_uint(b) & 0xffff0000u);
}
static __device__ __forceinline__ float trunc_bf(float a) {
    return __uint_as_float(__float_as_uint(a) & 0xffff0000u);
}
static __device__ __forceinline__ unsigned short top16(float v) {
    return (unsigned short)(__float_as_uint(v) >> 16);
}
static __device__ __forceinline__ f32x4 mfma16(u16x8 a, u16x8 b, f32x4 c) {
    return __builtin_amdgcn_mfma_f32_16x16x32_bf16(
        __builtin_bit_cast(bf16x8, a), __builtin_bit_cast(bf16x8, b), c, 0, 0, 0);
}

// sortable float<->uint (monotone increasing)
static __device__ __forceinline__ unsigned enc_f32(float f) {
    unsigned u = __float_as_uint(f);
    return u ^ (unsigned)(((int)u >> 31) | 0x80000000);
}
static __device__ __forceinline__ float dec_f32(unsigned e) {
    unsigned u = e ^ ((e & 0x80000000u) ? 0x80000000u : 0xFFFFFFFFu);
    return __uint_as_float(u);
}
static __device__ __forceinline__ unsigned umin32(unsigned a, unsigned b) { return a < b ? a : b; }
static __device__ __forceinline__ void ceu(unsigned& a, unsigned& b) {
    unsigned lo = a < b ? a : b;
    unsigned hi = a < b ? b : a;
    a = lo; b = hi;
}
// bitonic sort ascending, 16 elems, fully static
static __device__ __forceinline__ void sort16(unsigned* r) {
#pragma unroll
    for (int k = 2; k <= 16; k <<= 1)
#pragma unroll
        for (int j = k >> 1; j > 0; j >>= 1)
#pragma unroll
            for (int i = 0; i < 16; ++i) {
                int l = i ^ j;
                if (l > i) {
                    if ((i & k) == 0) ceu(r[i], r[l]);
                    else              ceu(r[l], r[i]);
                }
            }
}
// clean a bitonic 16-sequence into ascending order
static __device__ __forceinline__ void clean16(unsigned* r) {
#pragma unroll
    for (int j = 8; j > 0; j >>= 1)
#pragma unroll
        for (int i = 0; i < 16; ++i) {
            int l = i ^ j;
            if (l > i) ceu(r[i], r[l]);
        }
}
// (key,id) lexicographic helpers for merge2
static __device__ __forceinline__ int lessp(float ka, int ia, float kb, int ib) {
    return (ka < kb) || (ka == kb && ia < ib);
}
static __device__ __forceinline__ void ceup(float& ka, int& ia, float& kb, int& ib) {
    bool sw = lessp(kb, ib, ka, ia);
    float t0 = sw ? kb : ka, t1 = sw ? ka : kb;
    int   u0 = sw ? ib : ia, u1 = sw ? ia : ib;
    ka = t0; kb = t1; ia = u0; ib = u1;
}
static __device__ __forceinline__ void cleanp16(float* k, int* i) {
#pragma unroll
    for (int j = 8; j > 0; j >>= 1)
#pragma unroll
        for (int x = 0; x < 16; ++x) {
            int l = x ^ j;
            if (l > x) ceup(k[x], i[x], k[l], i[l]);
        }
}

// ---------------- zero init ----------------
__global__ __launch_bounds__(256) void zero_kernel(float* ws) {
    int idx = blockIdx.x * 256 + threadIdx.x;
    if (idx < 66560) ws[idx] = 0.0f;   // mu_sum + scal + pad + covX accumulator
}

// ---------------- X stats v3: coalesced uint4 image writes + LDS-prereduced colsums ----
// 784 blocks x 128 rows. Lane owns 8 consecutive cols of a row (32 lanes/row, 2 rows/wave).
// XHs/XLs are LINEAR row-major bf16 (swizzle now applied at knn3's LDS-write stage).
// Column sums: 8 per-lane partials -> half-combine -> LDS[4][256] -> 256 atomics/block.
__global__ __launch_bounds__(256) void statsx_kernel(const float* __restrict__ X,
                                                     float* __restrict__ xsq,
                                                     float* __restrict__ mu_sum,
                                                     unsigned short* __restrict__ XHs,
                                                     unsigned short* __restrict__ XLs) {
    __shared__ float colred[4][256];
    const int t = threadIdx.x;
    const int w = t >> 6, lane = t & 63;
    const int half = lane >> 5;      // 0/1: which of the wave's two rows
    const int g = lane & 31;         // 8-col group within the row
    const int rbase = blockIdx.x * 128;
    float cs[8] = {0.f, 0.f, 0.f, 0.f, 0.f, 0.f, 0.f, 0.f};
#pragma unroll 2
    for (int m = 0; m < 16; ++m) {
        const int r = rbase + m * 8 + w * 2 + half;
        if (r < NPTS) {
            float4 v0 = *(const float4*)&X[r * DIMD + g * 8];
            float4 v1 = *(const float4*)&X[r * DIMD + g * 8 + 4];
            cs[0] += v0.x; cs[1] += v0.y; cs[2] += v0.z; cs[3] += v0.w;
            cs[4] += v1.x; cs[5] += v1.y; cs[6] += v1.z; cs[7] += v1.w;
            float ss = v0.x * v0.x + v0.y * v0.y + v0.z * v0.z + v0.w * v0.w
                     + v1.x * v1.x + v1.y * v1.y + v1.z * v1.z + v1.w * v1.w;
#pragma unroll
            for (int off = 16; off; off >>= 1) ss += __shfl_down(ss, off, 32);
            if (g == 0) xsq[r] = ss;
            if (XHs) {
                uint4 hv = make_uint4(pack_hi(v0.x, v0.y), pack_hi(v0.z, v0.w),
                                      pack_hi(v1.x, v1.y), pack_hi(v1.z, v1.w));
                uint4 lv = make_uint4(
                    pack_hi(v0.x - trunc_bf(v0.x), v0.y - trunc_bf(v0.y)),
                    pack_hi(v0.z - trunc_bf(v0.z), v0.w - trunc_bf(v0.w)),
                    pack_hi(v1.x - trunc_bf(v1.x), v1.y - trunc_bf(v1.y)),
                    pack_hi(v1.z - trunc_bf(v1.z), v1.w - trunc_bf(v1.w)));
                *(uint4*)(XHs + (size_t)r * 256 + g * 8) = hv;
                *(uint4*)(XLs + (size_t)r * 256 + g * 8) = lv;
            }
        } else if (XHs) {
            uint4 z4 = make_uint4(0u, 0u, 0u, 0u);
            *(uint4*)(XHs + (size_t)r * 256 + g * 8) = z4;
            *(uint4*)(XLs + (size_t)r * 256 + g * 8) = z4;
        }
    }
    // combine the wave's two row-halves (same columns)
#pragma unroll
    for (int j = 0; j < 8; ++j) cs[j] += __shfl_down(cs[j], 32);
    if (half == 0) {
#pragma unroll
        for (int j = 0; j < 8; ++j) colred[w][g * 8 + j] = cs[j];
    }
    __syncthreads();
    float s = colred[0][t] + colred[1][t] + colred[2][t] + colred[3][t];
    atomicAdd(&mu_sum[t], s);
}

// ---------------- transpose bf16 image: XHs[r][d] -> XTH[d][r] (and L); linear input ----
__global__ __launch_bounds__(256) void xtk_kernel(const unsigned short* __restrict__ XHs,
                                                  const unsigned short* __restrict__ XLs,
                                                  unsigned short* __restrict__ XTH,
                                                  unsigned short* __restrict__ XTL) {
    __shared__ unsigned short LH[32][268];
    __shared__ unsigned short LL[32][268];
    const int t = threadIdx.x;
#pragma unroll 1
    for (int st = 0; st < 8; ++st) {
        const int r0 = blockIdx.x * 256 + st * 32;
        const int row = t >> 3;
        const int r = r0 + row;
#pragma unroll
        for (int gg = 0; gg < 4; ++gg) {
            int glog = (t & 7) + gg * 8;
            u16x8 h = *(const u16x8*)(XHs + (size_t)r * 256 + glog * 8);
            u16x8 l = *(const u16x8*)(XLs + (size_t)r * 256 + glog * 8);
            *(u16x8*)&LH[row][glog * 8] = h;
            *(u16x8*)&LL[row][glog * 8] = l;
        }
        __syncthreads();
        {
            unsigned pk[16];
#pragma unroll
            for (int m = 0; m < 16; ++m)
                pk[m] = (unsigned)LH[2 * m][t] | ((unsigned)LH[2 * m + 1][t] << 16);
            uint4* oh = (uint4*)(XTH + (size_t)t * 100352 + r0);
#pragma unroll
            for (int q = 0; q < 4; ++q)
                oh[q] = make_uint4(pk[4 * q], pk[4 * q + 1], pk[4 * q + 2], pk[4 * q + 3]);
#pragma unroll
            for (int m = 0; m < 16; ++m)
                pk[m] = (unsigned)LL[2 * m][t] | ((unsigned)LL[2 * m + 1][t] << 16);
            uint4* ol = (uint4*)(XTL + (size_t)t * 100352 + r0);
#pragma unroll
            for (int q = 0; q < 4; ++q)
                ol[q] = make_uint4(pk[4 * q], pk[4 * q + 1], pk[4 * q + 2], pk[4 * q + 3]);
        }
        __syncthreads();
    }
}

// ---------------- covX via MFMA (split-bf16, reads transposed image) ----------------
__global__ __launch_bounds__(256) void covx2_kernel(const unsigned short* __restrict__ XTH,
                                                    const unsigned short* __restrict__ XTL,
                                                    float* __restrict__ acc_out) {
    const int quad = blockIdx.x;
    const int qi = quad >> 1, qj = quad & 1;
    const int t = threadIdx.x, w = t >> 6, lane = t & 63;
    const int l15 = lane & 15, l4 = lane >> 4;
    const int k0 = blockIdx.y * KS2;
    const int kend = (k0 + KS2 < 100352) ? (k0 + KS2) : 100352;
    f32x4 acc[2][8];
#pragma unroll
    for (int f = 0; f < 2; ++f)
#pragma unroll
        for (int cf = 0; cf < 8; ++cf) { f32x4 z = {0.f, 0.f, 0.f, 0.f}; acc[f][cf] = z; }
    const size_t rowA0 = (size_t)(qi * 128 + w * 32 + l15) * 100352;
    const size_t rowA1 = (size_t)(qi * 128 + w * 32 + 16 + l15) * 100352;
#pragma unroll 1
    for (int k = k0; k < kend; k += 32) {
        const int ko = k + l4 * 8;
        u16x8 ah0 = *(const u16x8*)(XTH + rowA0 + ko);
        u16x8 al0 = *(const u16x8*)(XTL + rowA0 + ko);
        u16x8 ah1 = *(const u16x8*)(XTH + rowA1 + ko);
        u16x8 al1 = *(const u16x8*)(XTL + rowA1 + ko);
#pragma unroll
        for (int cf = 0; cf < 8; ++cf) {
            const size_t rb = (size_t)(qj * 128 + cf * 16 + l15) * 100352 + ko;
            u16x8 bh = *(const u16x8*)(XTH + rb);
            u16x8 bl = *(const u16x8*)(XTL + rb);
            acc[0][cf] = mfma16(ah0, bh, acc[0][cf]);
            acc[0][cf] = mfma16(ah0, bl, acc[0][cf]);
            acc[0][cf] = mfma16(al0, bh, acc[0][cf]);
            acc[1][cf] = mfma16(ah1, bh, acc[1][cf]);
            acc[1][cf] = mfma16(ah1, bl, acc[1][cf]);
            acc[1][cf] = mfma16(al1, bh, acc[1][cf]);
        }
    }
#pragma unroll
    for (int f = 0; f < 2; ++f)
#pragma unroll
        for (int cf = 0; cf < 8; ++cf)
#pragma unroll
            for (int i = 0; i < 4; ++i) {
                const int r = qi * 128 + w * 32 + f * 16 + l4 * 4 + i;
                const int c = qj * 128 + cf * 16 + l15;
                atomicAdd(&acc_out[r * DIMD + c], acc[f][cf][i]);
            }
}

// ---------------- old covX accumulate (fallback, fp32 VALU) ----------------
__global__ __launch_bounds__(256) void covx_kernel(const float* __restrict__ X,
                                                   float* __restrict__ acc_out) {
    __shared__ float Ais[16][64];
    __shared__ float Ajs[16][64];
    int t = threadIdx.x;
    int i0 = blockIdx.x * 64, j0 = blockIdx.y * 64;
    int ks = blockIdx.z * KSLICE;
    int lr = t >> 4, lc = (t & 15) * 4;
    int tx = t & 15, ty = t >> 4;
    float acc[4][4] = {};
    for (int kb = 0; kb < KSLICE; kb += 16) {
        int k = ks + kb + lr;
        if (k < NPTS) {
            float4 vi = *(const float4*)&X[k * DIMD + i0 + lc];
            float4 vj = *(const float4*)&X[k * DIMD + j0 + lc];
            *(float4*)&Ais[lr][lc] = vi;
            *(float4*)&Ajs[lr][lc] = vj;
        } else {
            float4 z = {0.f, 0.f, 0.f, 0.f};
            *(float4*)&Ais[lr][lc] = z;
            *(float4*)&Ajs[lr][lc] = z;
        }
        __syncthreads();
#pragma unroll
        for (int kk = 0; kk < 16; ++kk) {
            float4 a = *(float4*)&Ais[kk][tx * 4];
            float4 b = *(float4*)&Ajs[kk][ty * 4];
            float av[4] = {a.x, a.y, a.z, a.w};
            float bv[4] = {b.x, b.y, b.z, b.w};
#pragma unroll
            for (int m = 0; m < 4; ++m)
#pragma unroll
                for (int n = 0; n < 4; ++n) acc[m][n] += av[m] * bv[n];
        }
        __syncthreads();
    }
#pragma unroll
    for (int m = 0; m < 4; ++m)
#pragma unroll
        for (int n = 0; n < 4; ++n)
            atomicAdd(&acc_out[(i0 + 4 * tx + m) * DIMD + j0 + 4 * ty + n], acc[m][n]);
}

// ---------------- covX finalize: acc -> covXf (+trace) ----------------
__global__ __launch_bounds__(256) void covxfin2_kernel(const float* __restrict__ acc,
                                                       const float* __restrict__ mu_sum,
                                                       float* __restrict__ covXf,
                                                       float* __restrict__ scal) {
    int idx = blockIdx.x * 256 + threadIdx.x;
    int i = idx >> 8, j = idx & 255;
    const float invN = 1.0f / (float)NPTS;
    float v = acc[idx] * invN - (mu_sum[i] * invN) * (mu_sum[j] * invN) + ((i == j) ? 1e-4f : 0.0f);
    covXf[idx] = v;
    if (i == j) atomicAdd(&scal[SC_TRCX], v);
}

// ---------------- generic 256x256x256 matmul, 32x32 tiles (fp32) ----------------
__global__ __launch_bounds__(256) void mm32_kernel(const float* A, const float* B, float* C, const float* D,
                                                   const float* A2, const float* B2, float* C2, const float* D2,
                                                   int mode, const float* mu, float* scal) {
    __shared__ float As[32][32];
    __shared__ float Bs[32][32];
    __shared__ float red[256];
    int t = threadIdx.x;
    int tx = t & 15, ty = t >> 4;
    int i0 = blockIdx.x * 32, j0 = blockIdx.y * 32;
    int lr = t >> 3, lc = (t & 7) * 4;
    float acc[2][2] = {};
    for (int kb = 0; kb < 256; kb += 32) {
        if (mode == 2) {
            float4 v = *(const float4*)&A[(kb + lr) * DIMD + i0 + lc];
            *(float4*)&As[lr][lc] = v;
        } else {
            float4 v = *(const float4*)&A[(i0 + lr) * DIMD + kb + lc];
            As[lc + 0][lr] = v.x; As[lc + 1][lr] = v.y; As[lc + 2][lr] = v.z; As[lc + 3][lr] = v.w;
        }
        {
            float4 v = *(const float4*)&B[(kb + lr) * DIMD + j0 + lc];
            *(float4*)&Bs[lr][lc] = v;
        }
        __syncthreads();
#pragma unroll
        for (int kk = 0; kk < 32; ++kk) {
            float a0 = As[kk][2 * tx], a1 = As[kk][2 * tx + 1];
            float b0 = Bs[kk][2 * ty], b1 = Bs[kk][2 * ty + 1];
            acc[0][0] += a0 * b0; acc[0][1] += a0 * b1;
            acc[1][0] += a1 * b0; acc[1][1] += a1 * b1;
        }
        __syncthreads();
    }
    float fr = 0.f;
#pragma unroll
    for (int ii = 0; ii < 2; ++ii)
#pragma unroll
        for (int jj = 0; jj < 2; ++jj) {
            int i = i0 + 2 * tx + ii, j = j0 + 2 * ty + jj;
            float v = acc[ii][jj];
            if (mode == 2) {
                v = v * (1.0f / 256.0f) - mu[i] * mu[j] + ((i == j) ? 1e-4f : 0.0f);
                if (i == j) atomicAdd(&scal[SC_TRCT], v);
            }
            C[i * DIMD + j] = v;
            if (mode == 1) fr += v * v;
        }
    if (mode == 0 && C2 != nullptr) {
        unsigned short* TH = (unsigned short*)C2;
        unsigned short* TL = (unsigned short*)const_cast<float*>(D2);
#pragma unroll
        for (int ii = 0; ii < 2; ++ii) {
            int i = i0 + 2 * tx + ii;
            int jc = j0 + 2 * ty;
            float x0 = acc[ii][0], x1 = acc[ii][1];
            *(unsigned*)&TH[i * DIMD + jc] = pack_hi(x0, x1);
            *(unsigned*)&TL[i * DIMD + jc] = pack_hi(x0 - trunc_bf(x0), x1 - trunc_bf(x1));
        }
    }
    if (mode == 1) {
        red[t] = fr; __syncthreads();
        for (int s2 = 128; s2 > 0; s2 >>= 1) { if (t < s2) red[t] += red[t + s2]; __syncthreads(); }
        if (t == 0) atomicAdd(&scal[SC_FROB], red[0]);
    }
}

// ---------------- T stats ----------------
__global__ __launch_bounds__(256) void tstats_kernel(const float* __restrict__ Tm,
                                                     const float* __restrict__ mu_sum,
                                                     float* __restrict__ mu_T,
                                                     float* __restrict__ scal) {
    __shared__ float red[256];
    int j = threadIdx.x;
    float s = 0.f;
    for (int b = 0; b < BQ; ++b) s += Tm[b * DIMD + j];
    float mt = s * (1.0f / 256.0f);
    mu_T[j] = mt;
    float d = mt - mu_sum[j] * (1.0f / (float)NPTS);
    red[j] = d * d;
    __syncthreads();
    for (int s2 = 128; s2 > 0; s2 >>= 1) { if (j < s2) red[j] += red[j + s2]; __syncthreads(); }
    if (j == 0) scal[SC_LM] = red[0];
}

// ---------------- init Y = G/||G||_F (+images), Z = I (+images) ----------------
__global__ __launch_bounds__(256) void inityz2_kernel(const float* __restrict__ G,
                                                      const float* __restrict__ scal,
                                                      float* __restrict__ Y, float* __restrict__ Z,
                                                      unsigned short* __restrict__ YaH,
                                                      unsigned short* __restrict__ YaL,
                                                      unsigned short* __restrict__ ZaH,
                                                      unsigned short* __restrict__ ZaL) {
    int idx = blockIdx.x * 256 + threadIdx.x;
    float invs = rsqrtf(scal[SC_FROB]);
    float y = G[idx] * invs;
    Y[idx] = y;
    YaH[idx] = top16(y);
    YaL[idx] = top16(y - trunc_bf(y));
    bool dg = ((idx >> 8) == (idx & 255));
    Z[idx] = dg ? 1.0f : 0.0f;
    ZaH[idx] = dg ? (unsigned short)0x3F80 : (unsigned short)0;
    ZaL[idx] = 0;
}

// ---------------- fused Newton-Schulz iteration, 16-col slices (32 blocks/launch) ------
__global__ __launch_bounds__(256) void nsfused_kernel(
        const float* __restrict__ Ycur, const float* __restrict__ Zcur,
        const unsigned short* __restrict__ YH, const unsigned short* __restrict__ YL,
        const unsigned short* __restrict__ ZH, const unsigned short* __restrict__ ZL,
        float* __restrict__ Yn, float* __restrict__ Zn,
        unsigned short* __restrict__ YnH, unsigned short* __restrict__ YnL,
        unsigned short* __restrict__ ZnH, unsigned short* __restrict__ ZnL) {
    __shared__ __align__(16) unsigned short VH[16 * 264];
    __shared__ __align__(16) unsigned short VL[16 * 264];
    __shared__ __align__(16) unsigned short IH[16 * 264];
    __shared__ __align__(16) unsigned short IL[16 * 264];
    const int t = threadIdx.x, w = t >> 6, lane = t & 63;
    const int l15 = lane & 15, l4 = lane >> 4;
    const int j0 = blockIdx.x * 16;
    const unsigned short *M1H, *M1L, *M2H, *M2L, *VsH, *VsL;
    const float* Dm; float* Out; unsigned short *OH, *OL;
    if (blockIdx.y == 0) { M1H = ZH; M1L = ZL; M2H = YH; M2L = YL; VsH = YH; VsL = YL;
                           Dm = Ycur; Out = Yn; OH = YnH; OL = YnL; }
    else                 { M1H = YH; M1L = YL; M2H = ZH; M2L = ZL; VsH = ZH; VsL = ZL;
                           Dm = Zcur; Out = Zn; OH = ZnH; OL = ZnL; }
    {
        const int col = t >> 4, k0 = (t & 15) * 16;
#pragma unroll
        for (int m = 0; m < 8; ++m) {
            const int k = k0 + 2 * m;
            unsigned h0 = VsH[(size_t)k * 256 + j0 + col];
            unsigned h1 = VsH[(size_t)(k + 1) * 256 + j0 + col];
            unsigned l0 = VsL[(size_t)k * 256 + j0 + col];
            unsigned l1 = VsL[(size_t)(k + 1) * 256 + j0 + col];
            *(unsigned*)&VH[col * 264 + k] = h0 | (h1 << 16);
            *(unsigned*)&VL[col * 264 + k] = l0 | (l1 << 16);
        }
    }
    __syncthreads();
    f32x4 acc[4];
#pragma unroll
    for (int f = 0; f < 4; ++f) { f32x4 z = {0.f, 0.f, 0.f, 0.f}; acc[f] = z; }
#pragma unroll
    for (int ks = 0; ks < 8; ++ks) {
        const int bo = l15 * 264 + ks * 32 + l4 * 8;
        u16x8 bh = *(const u16x8*)&VH[bo];
        u16x8 bl = *(const u16x8*)&VL[bo];
#pragma unroll
        for (int f = 0; f < 4; ++f) {
            const size_t ro = (size_t)(w * 64 + f * 16 + l15) * 256 + ks * 32 + l4 * 8;
            u16x8 ah = *(const u16x8*)(M1H + ro);
            u16x8 al = *(const u16x8*)(M1L + ro);
            acc[f] = mfma16(ah, bh, acc[f]);
            acc[f] = mfma16(ah, bl, acc[f]);
            acc[f] = mfma16(al, bh, acc[f]);
        }
    }
#pragma unroll
    for (int f = 0; f < 4; ++f) {
        float v0 = acc[f][0], v1 = acc[f][1], v2 = acc[f][2], v3 = acc[f][3];
        unsigned h01 = pack_hi(v0, v1), h23 = pack_hi(v2, v3);
        unsigned l01 = pack_hi(v0 - trunc_bf(v0), v1 - trunc_bf(v1));
        unsigned l23 = pack_hi(v2 - trunc_bf(v2), v3 - trunc_bf(v3));
        const int ad = l15 * 264 + w * 64 + f * 16 + l4 * 4;
        *(uint2*)&IH[ad] = make_uint2(h01, h23);
        *(uint2*)&IL[ad] = make_uint2(l01, l23);
    }
    __syncthreads();
#pragma unroll
    for (int f = 0; f < 4; ++f) { f32x4 z = {0.f, 0.f, 0.f, 0.f}; acc[f] = z; }
#pragma unroll
    for (int ks = 0; ks < 8; ++ks) {
        const int bo = l15 * 264 + ks * 32 + l4 * 8;
        u16x8 bh = *(const u16x8*)&IH[bo];
        u16x8 bl = *(const u16x8*)&IL[bo];
#pragma unroll
        for (int f = 0; f < 4; ++f) {
            const size_t ro = (size_t)(w * 64 + f * 16 + l15) * 256 + ks * 32 + l4 * 8;
            u16x8 ah = *(const u16x8*)(M2H + ro);
            u16x8 al = *(const u16x8*)(M2L + ro);
            acc[f] = mfma16(ah, bh, acc[f]);
            acc[f] = mfma16(ah, bl, acc[f]);
            acc[f] = mfma16(al, bh, acc[f]);
        }
    }
#pragma unroll
    for (int f = 0; f < 4; ++f)
#pragma unroll
        for (int i = 0; i < 4; ++i) {
            const int r = w * 64 + f * 16 + l4 * 4 + i;
            const int c = j0 + l15;
            float v = 1.5f * Dm[r * 256 + c] - 0.5f * acc[f][i];
            Out[r * 256 + c] = v;
            OH[r * 256 + c] = top16(v);
            OL[r * 256 + c] = top16(v - trunc_bf(v));
        }
}

// ---------------- finalize loss_dist ----------------
__global__ __launch_bounds__(256) void findist_kernel(const float* __restrict__ Yfin,
                                                      float* __restrict__ scal) {
    __shared__ float red[256];
    int t = threadIdx.x;
    red[t] = Yfin[t * (DIMD + 1)];
    __syncthreads();
    for (int s2 = 128; s2 > 0; s2 >>= 1) { if (t < s2) red[t] += red[t + s2]; __syncthreads(); }
    if (t == 0) {
        float frobsq = scal[SC_FROB];
        float tr_sqrt = powf(frobsq, 0.25f) * red[0];
        float lc = scal[SC_TRCX] + scal[SC_TRCT] - 2.0f * tr_sqrt;
        scal[SC_LD] = fmaxf(0.0f, scal[SC_LM] + lc);
    }
}

// ---------------- reg: sum(W^2) ----------------
__global__ __launch_bounds__(256) void reg_kernel(const float* __restrict__ W, float* __restrict__ scal) {
    __shared__ float red[256];
    int t = threadIdx.x;
    float s = 0.f;
    int base = blockIdx.x * 1024;
    for (int m = 0; m < 4; ++m) { float w = W[base + m * 256 + t]; s += w * w; }
    red[t] = s;
    __syncthreads();
    for (int s2 = 128; s2 > 0; s2 >>= 1) { if (t < s2) red[t] += red[t + s2]; __syncthreads(); }
    if (t == 0) atomicAdd(&scal[SC_REG], red[0]);
}

// ---------------- KNN v3c: MFMA + packed-key bitonic top-16; swizzle at LDS write ------
// XHs/XLs are LINEAR now; the bank-conflict XOR swizzle is applied on the LDS destination
// (row*512 + ((gi^(row&7))<<4)) and undone by the read-side ^swz — a consistent involution.
__global__ __launch_bounds__(256, 2) void knn3_kernel(const unsigned short* __restrict__ TmH,
                                                      const unsigned short* __restrict__ TmL,
                                                      const unsigned short* __restrict__ XHs,
                                                      const unsigned short* __restrict__ XLs,
                                                      const float* __restrict__ xsq,
                                                      float* __restrict__ ck, int* __restrict__ ci) {
    __shared__ __align__(16) unsigned char sm2[69632];   // XH 16K | XL 16K | kt[256][36] u32
    unsigned* kt = (unsigned*)(sm2 + 32768);
    const int t = threadIdx.x;
    const int w = t >> 6, lane = t & 63;
    const int l15 = lane & 15, l4 = lane >> 4;
    const int p0 = blockIdx.x * PCHUNK;
    const int swz = (l15 & 7) << 4;

    unsigned sk[16];
#pragma unroll
    for (int s = 0; s < 16; ++s) sk[s] = 0xFFFFFFFFu;

#pragma unroll 1
    for (int pc = 0; pc < 4; ++pc) {
        const int pbase = p0 + pc * 32;
        {
            const uint4* gh = (const uint4*)(XHs + (size_t)pbase * 256);
            const uint4* gl = (const uint4*)(XLs + (size_t)pbase * 256);
#pragma unroll
            for (int r = 0; r < 4; ++r) {
                const int slot = r * 256 + t;
                const int row = slot >> 5, gi = slot & 31;
                const int dst = row * 512 + (((gi ^ (row & 7))) << 4);
                uint4 vh = gh[slot];
                uint4 vl = gl[slot];
                *(uint4*)(sm2 + dst) = vh;
                *(uint4*)(sm2 + 16384 + dst) = vl;
            }
        }
        __syncthreads();
        f32x4 acc[4][2];
#pragma unroll
        for (int f = 0; f < 4; ++f)
#pragma unroll
            for (int pt = 0; pt < 2; ++pt) { f32x4 z = {0.f, 0.f, 0.f, 0.f}; acc[f][pt] = z; }
#pragma unroll
        for (int ks = 0; ks < 8; ++ks) {
            const int g = (((ks * 4 + l4) << 4)) ^ swz;
            const int b0 = l15 * 512 + g;
            const int b1 = (16 + l15) * 512 + g;
            u16x8 bh0 = *(const u16x8*)(sm2 + b0);
            u16x8 bl0 = *(const u16x8*)(sm2 + 16384 + b0);
            u16x8 bh1 = *(const u16x8*)(sm2 + b1);
            u16x8 bl1 = *(const u16x8*)(sm2 + 16384 + b1);
#pragma unroll
            for (int f = 0; f < 4; ++f) {
                const size_t ro = (size_t)(w * 64 + f * 16 + l15) * 256 + ks * 32 + l4 * 8;
                u16x8 ah = *(const u16x8*)(TmH + ro);
                u16x8 al = *(const u16x8*)(TmL + ro);
                acc[f][0] = mfma16(ah, bh0, acc[f][0]);
                acc[f][0] = mfma16(ah, bl0, acc[f][0]);
                acc[f][0] = mfma16(al, bh0, acc[f][0]);
                acc[f][1] = mfma16(ah, bh1, acc[f][1]);
                acc[f][1] = mfma16(ah, bl1, acc[f][1]);
                acc[f][1] = mfma16(al, bh1, acc[f][1]);
            }
        }
        // kt: packed sortable keys (25-bit key | 7-bit local idx)
#pragma unroll
        for (int pt = 0; pt < 2; ++pt) {
            const int p = pbase + pt * 16 + l15;
            const float xv = xsq[p];
            const bool ok = (p < NPTS);
            const unsigned lidx = (unsigned)(pc * 32 + pt * 16 + l15);
#pragma unroll
            for (int f = 0; f < 4; ++f)
#pragma unroll
                for (int i = 0; i < 4; ++i) {
                    float d2 = ok ? (xv - 2.0f * acc[f][pt][i]) : BIGF;
                    unsigned e = (enc_f32(d2) & 0xFFFFFF80u) | lidx;
                    kt[(w * 64 + f * 16 + l4 * 4 + i) * 36 + pt * 16 + l15] = e;
                }
        }
        __syncthreads();
        // selection: two sorted 16-batches merged into sk
#pragma unroll
        for (int hb = 0; hb < 2; ++hb) {
            unsigned b[16];
#pragma unroll
            for (int c4 = 0; c4 < 4; ++c4) {
                uint4 v = *(const uint4*)(kt + t * 36 + hb * 16 + c4 * 4);
                b[c4 * 4 + 0] = v.x; b[c4 * 4 + 1] = v.y;
                b[c4 * 4 + 2] = v.z; b[c4 * 4 + 3] = v.w;
            }
            sort16(b);
#pragma unroll
            for (int i = 0; i < 16; ++i) sk[i] = umin32(sk[i], b[15 - i]);
            clean16(sk);
        }
    }
    const int base = t * NCAND + blockIdx.x * 16;
#pragma unroll
    for (int s = 0; s < 16; ++s) {
        ck[base + s] = dec_f32(sk[s] & 0xFFFFFF80u);
        ci[base + s] = p0 + (int)(sk[s] & 127u);
    }
}

// ---------------- KNN fallback (round-1 version, fp32 inputs) ----------------
static __device__ __forceinline__ void knn_load(const float* __restrict__ X, int p0, int pc, int t,
                                                float4 s0[2], float4 s1[2]) {
#pragma unroll
    for (int rep = 0; rep < 2; ++rep) {
        int g = t + rep * 512;
        int row = g >> 5, c0 = (g & 31) * 8;
        int p = p0 + pc * 32 + row;
        if (p < NPTS) {
            s0[rep] = *(const float4*)&X[p * DIMD + c0];
            s1[rep] = *(const float4*)&X[p * DIMD + c0 + 4];
        } else {
            float4 z = {0.f, 0.f, 0.f, 0.f};
            s0[rep] = z; s1[rep] = z;
        }
    }
}
static __device__ __forceinline__ void knn_write(unsigned short* XH, unsigned short* XL, int t,
                                                 const float4 s0[2], const float4 s1[2]) {
#pragma unroll
    for (int rep = 0; rep < 2; ++rep) {
        int g = t + rep * 512;
        int row = g >> 5, c0 = (g & 31) * 8;
        float f[8] = {s0[rep].x, s0[rep].y, s0[rep].z, s0[rep].w,
                      s1[rep].x, s1[rep].y, s1[rep].z, s1[rep].w};
        u16x8 h, lo;
#pragma unroll
        for (int j = 0; j < 8; ++j) {
            unsigned short hb = f2bf(f[j]);
            h[j] = hb;
            lo[j] = f2bf(f[j] - bf2f(hb));
        }
        *(u16x8*)&XH[row * 264 + c0] = h;
        *(u16x8*)&XL[row * 264 + c0] = lo;
    }
}
__global__ __launch_bounds__(512, 2) void knn_kernel(const float* __restrict__ Tm,
                                                     const float* __restrict__ X,
                                                     const float* __restrict__ xsq,
                                                     float* __restrict__ ck, int* __restrict__ ci) {
    __shared__ __align__(16) unsigned char smem[50688];
    unsigned short* XH = (unsigned short*)smem;
    unsigned short* XL = (unsigned short*)(smem + 16896);
    float* ktf = (float*)smem;
    float* tk  = (float*)(smem + 34304);
    int*   ti  = (int*)  (smem + 42496);
    const int t    = threadIdx.x;
    const int w    = t >> 6;
    const int lane = t & 63;
    const int l15  = lane & 15;
    const int l4   = lane >> 4;
    const int p0   = blockIdx.x * PCHUNK;
    const int q0   = blockIdx.y * 128;
    u16x8 aH[8], aL[8];
    {
        const int q = q0 + w * 16 + l15;
        const float* tq = Tm + q * DIMD + l4 * 8;
#pragma unroll
        for (int ks = 0; ks < 8; ++ks) {
            float4 v0 = *(const float4*)(tq + ks * 32);
            float4 v1 = *(const float4*)(tq + ks * 32 + 4);
            float f[8] = {v0.x, v0.y, v0.z, v0.w, v1.x, v1.y, v1.z, v1.w};
            u16x8 h, lo;
#pragma unroll
            for (int j = 0; j < 8; ++j) {
                unsigned short hb = f2bf(f[j]);
                h[j] = hb;
                lo[j] = f2bf(f[j] - bf2f(hb));
            }
            aH[ks] = h; aL[ks] = lo;
        }
    }
    float worst = BIGF; int wslot = 0;
    float4 s0[2], s1[2];
    knn_load(X, p0, 0, t, s0, s1);
    knn_write(XH, XL, t, s0, s1);
#pragma unroll
    for (int h = 0; h < 2; ++h) {
        f32x4 acc[4];
#pragma unroll
        for (int a2 = 0; a2 < 4; ++a2) { f32x4 z = {0.f, 0.f, 0.f, 0.f}; acc[a2] = z; }
#pragma unroll
        for (int pc2 = 0; pc2 < 2; ++pc2) {
            const int pc = 2 * h + pc2;
            __syncthreads();
            if (pc < 3) knn_load(X, p0, pc + 1, t, s0, s1);
#pragma unroll
            for (int ks = 0; ks < 8; ++ks) {
#pragma unroll
                for (int pt = 0; pt < 2; ++pt) {
                    const int off = (pt * 16 + l15) * 264 + ks * 32 + l4 * 8;
                    u16x8 bh = *(const u16x8*)&XH[off];
                    u16x8 bl = *(const u16x8*)&XL[off];
                    acc[pc2 * 2 + pt] = mfma16(aH[ks], bh, acc[pc2 * 2 + pt]);
                    acc[pc2 * 2 + pt] = mfma16(aH[ks], bl, acc[pc2 * 2 + pt]);
                    acc[pc2 * 2 + pt] = mfma16(aL[ks], bh, acc[pc2 * 2 + pt]);
                }
            }
            __syncthreads();
            if (pc2 == 0 && pc < 3) knn_write(XH, XL, t, s0, s1);
        }
#pragma unroll
        for (int pc2 = 0; pc2 < 2; ++pc2) {
#pragma unroll
            for (int pt = 0; pt < 2; ++pt) {
                const int pl = pc2 * 32 + pt * 16 + l15;
                const int p  = p0 + h * 64 + pl;
                const float xv = (p < NPTS) ? xsq[p] : 0.f;
#pragma unroll
                for (int i = 0; i < 4; ++i) {
                    float key = (p < NPTS) ? (xv - 2.0f * acc[pc2 * 2 + pt][i]) : BIGF;
                    ktf[(w * 16 + l4 * 4 + i) * 67 + pl] = key;
                }
            }
        }
        __syncthreads();
        if (t < 128) {
            if (h == 0) {
#pragma unroll
                for (int s = 0; s < 16; ++s) { tk[s * 128 + t] = BIGF; ti[s * 128 + t] = 0x7fffffff; }
            }
            for (int c = 0; c < 64; ++c) {
                float key = ktf[t * 67 + c];
                if (key < worst) {
                    tk[wslot * 128 + t] = key; ti[wslot * 128 + t] = p0 + h * 64 + c;
                    worst = tk[t]; wslot = 0;
#pragma unroll
                    for (int s = 1; s < 16; ++s) {
                        float v = tk[s * 128 + t];
                        if (v > worst) { worst = v; wslot = s; }
                    }
                }
            }
        }
        __syncthreads();
        if (h == 0) knn_write(XH, XL, t, s0, s1);
    }
    if (t < 128) {
        int base = (q0 + t) * NCAND + blockIdx.x * 16;
        for (int s = 0; s < 16; ++s) { ck[base + s] = tk[s * 128 + t]; ci[base + s] = ti[s * 128 + t]; }
    }
}

// ---------------- merge v2: sorted-run early-exit scan + LDS bitonic tree ----------------
__global__ __launch_bounds__(256) void merge2_kernel(const float* __restrict__ ck,
                                                     const int* __restrict__ ci,
                                                     int* __restrict__ post_idx) {
    __shared__ float km[16 * 256];
    __shared__ int   im[16 * 256];
    const int q = blockIdx.x, t = threadIdx.x;
    float sk[16]; int si[16];
#pragma unroll
    for (int s = 0; s < 16; ++s) { sk[s] = BIGF; si[s] = 0x7fffffff; }
#pragma unroll 1
    for (int run = t; run < NPCH; run += 256) {
        const float* rk = ck + (size_t)q * NCAND + run * 16;
        const int*   ri = ci + (size_t)q * NCAND + run * 16;
#pragma unroll 1
        for (int s = 0; s < 16; ++s) {
            float k = rk[s]; int id = ri[s];
            if (!lessp(k, id, sk[15], si[15])) break;
#pragma unroll
            for (int j = 15; j > 0; --j) {
                bool a = lessp(k, id, sk[j - 1], si[j - 1]);
                bool b = lessp(k, id, sk[j], si[j]);
                float nk = a ? sk[j - 1] : (b ? k : sk[j]);
                int   ni = a ? si[j - 1] : (b ? id : si[j]);
                sk[j] = nk; si[j] = ni;
            }
            bool c = lessp(k, id, sk[0], si[0]);
            float nk0 = c ? k : sk[0]; int ni0 = c ? id : si[0];
            sk[0] = nk0; si[0] = ni0;
        }
    }
#pragma unroll
    for (int s = 0; s < 16; ++s) { km[s * 256 + t] = sk[s]; im[s * 256 + t] = si[s]; }
    __syncthreads();
    for (int off = 128; off > 0; off >>= 1) {
        if (t < off) {
            float bk[16]; int bi[16];
#pragma unroll
            for (int s = 0; s < 16; ++s) { bk[s] = km[s * 256 + t + off]; bi[s] = im[s * 256 + t + off]; }
#pragma unroll
            for (int s = 0; s < 16; ++s) {
                float ak = sk[s];  int ai = si[s];
                float ok = bk[15 - s]; int oi = bi[15 - s];
                bool a = lessp(ak, ai, ok, oi);
                sk[s] = a ? ak : ok; si[s] = a ? ai : oi;
            }
            cleanp16(sk, si);
#pragma unroll
            for (int s = 0; s < 16; ++s) { km[s * 256 + t] = sk[s]; im[s * 256 + t] = si[s]; }
        }
        __syncthreads();
    }
    if (t == 0) {
#pragma unroll
        for (int r = 0; r < 16; ++r) post_idx[q * 16 + r] = si[r];
    }
}

// ---------------- old merge (fallback path: runs unsorted) ----------------
__global__ __launch_bounds__(256) void merge_kernel(const float* __restrict__ ck,
                                                    const int* __restrict__ ci,
                                                    int* __restrict__ post_idx) {
    __shared__ float tk[16][256];
    __shared__ int   ti[16][256];
    __shared__ float rk[256];
    __shared__ int   ri[256];
    __shared__ int   rt2[256];
    __shared__ int   rs2[256];
    int q = blockIdx.x, t = threadIdx.x;
    for (int s = 0; s < 16; ++s) { tk[s][t] = BIGF; ti[s][t] = 0x7fffffff; }
    float worst = BIGF; int wslot = 0;
    for (int e = t; e < NCAND; e += 256) {
        float key = ck[q * NCAND + e];
        if (key < worst) {
            tk[wslot][t] = key; ti[wslot][t] = ci[q * NCAND + e];
            worst = tk[0][t]; wslot = 0;
            for (int s = 1; s < 16; ++s)
                if (tk[s][t] > worst) { worst = tk[s][t]; wslot = s; }
        }
    }
    __syncthreads();
    for (int r = 0; r < 16; ++r) {
        float bk = tk[0][t]; int bi = ti[0][t], bs = 0;
        for (int s = 1; s < 16; ++s) {
            float k2 = tk[s][t]; int i2 = ti[s][t];
            if (k2 < bk || (k2 == bk && i2 < bi)) { bk = k2; bi = i2; bs = s; }
        }
        rk[t] = bk; ri[t] = bi; rt2[t] = t; rs2[t] = bs;
        __syncthreads();
        for (int s2 = 128; s2 > 0; s2 >>= 1) {
            if (t < s2) {
                float ko = rk[t + s2]; int io = ri[t + s2];
                if (ko < rk[t] || (ko == rk[t] && io < ri[t])) {
                    rk[t] = ko; ri[t] = io; rt2[t] = rt2[t + s2]; rs2[t] = rs2[t + s2];
                }
            }
            __syncthreads();
        }
        if (t == rt2[0]) { tk[rs2[0]][t] = BIGF; ti[rs2[0]][t] = 0x7fffffff; }
        if (t == 0) post_idx[q * 16 + r] = ri[0];
        __syncthreads();
    }
}

// ---------------- exact l2 + softmax weights ----------------
__global__ __launch_bounds__(256) void l2sm_kernel(const float* __restrict__ Tm,
                                                   const float* __restrict__ X,
                                                   const int* __restrict__ post_idx,
                                                   float* __restrict__ post_w) {
    __shared__ float l2s[16];
    int b = blockIdx.x, t = threadIdx.x;
    int k = t >> 4, j = t & 15;
    int idx = post_idx[b * 16 + k];
    float s = 0.f;
    for (int i = 0; i < 16; ++i) {
        int d = j + 16 * i;
        float df = Tm[b * DIMD + d] - X[idx * DIMD + d];
        s += df * df;
    }
    for (int off = 8; off; off >>= 1) s += __shfl_down(s, off, 16);
    if (j == 0) l2s[k] = s;
    __syncthreads();
    if (t < 16) {
        float x = -l2s[t] * 10.0f;
        float m = x;
        for (int mm = 8; mm; mm >>= 1) m = fmaxf(m, __shfl_xor(m, mm, 16));
        float e = expf(x - m);
        float ssum = e;
        for (int mm = 8; mm; mm >>= 1) ssum += __shfl_xor(ssum, mm, 16);
        post_w[b * 16 + t] = e / ssum;
    }
}

// ---------------- KL per sample ----------------
__global__ __launch_bounds__(256) void kl_kernel(const int* __restrict__ q_indices,
                                                 const int* __restrict__ pre_indices,
                                                 const float* __restrict__ pre_weights,
                                                 const int* __restrict__ post_idx,
                                                 const float* __restrict__ post_w,
                                                 float* __restrict__ scal) {
    int b = threadIdx.x;
    int qi = q_indices[b];
    int pid[16]; float pw[16]; int sid[16]; float sw[16];
    for (int k = 0; k < 16; ++k) {
        pid[k] = pre_indices[qi * 16 + k];
        pw[k]  = pre_weights[qi * 16 + k];
        sid[k] = post_idx[b * 16 + k];
        sw[k]  = post_w[b * 16 + k];
    }
    float psum = 0.f, qsum = 0.f, kl = 0.f;
    for (int pass = 0; pass < 2; ++pass) {
        for (int i = 0; i < 32; ++i) {
            int c = (i < 16) ? pid[i] : sid[i - 16];
            bool first = true;
            for (int jj = 0; jj < i; ++jj) {
                int cj = (jj < 16) ? pid[jj] : sid[jj - 16];
                if (cj == c) { first = false; break; }
            }
            if (!first) continue;
            float p = 0.f, q = 0.f;
            for (int k2 = 0; k2 < 16; ++k2) {
                if (pid[k2] == c) p += pw[k2];
                if (sid[k2] == c) q += sw[k2];
            }
            p = fmaxf(p, 1e-8f); q = fmaxf(q, 1e-8f);
            if (pass == 0) { psum += p; qsum += q; }
            else {
                float pn = p / psum, qn = q / qsum;
                kl += pn * (logf(pn) - logf(qn));
            }
        }
    }
    atomicAdd(&scal[SC_KNN], kl * (1.0f / 256.0f));
}

// ---------------- final assembly ----------------
__global__ void assemble_kernel(const float* __restrict__ scal, float* __restrict__ out) {
    if (threadIdx.x == 0) {
        float ld = scal[SC_LD], lk = scal[SC_KNN], reg = scal[SC_REG];
        out[0] = ld + lk + 1e-4f * 0.5f * reg;
        out[1] = ld;
        out[2] = lk;
    }
}

extern "C" void kernel_launch(void* const* d_in, const int* in_sizes, int n_in,
                              void* d_out, int out_size, void* d_ws, size_t ws_size,
                              hipStream_t stream) {
    (void)in_sizes; (void)n_in; (void)out_size;
    const float* X           = (const float*)d_in[0];
    const float* W           = (const float*)d_in[1];
    const float* q_batch     = (const float*)d_in[2];
    const float* pre_weights = (const float*)d_in[3];
    const int*   q_indices   = (const int*)d_in[4];
    const int*   pre_indices = (const int*)d_in[5];
    float* out = (float*)d_out;
    float* ws  = (float*)d_ws;

    float* mu_sum = ws + 0;
    float* scal   = ws + 256;
    float* mu_T   = ws + 512;
    float* covX   = ws + 1024;        // raw X^T X accumulator
    float* Tm     = ws + 66560;
    float* cov    = ws + 132096;
    float* G      = ws + 197632;
    float* Ya     = ws + 263168;
    float* Za     = ws + 328704;
    float* Yb     = ws + 394240;
    float* Zb     = ws + 459776;
    float* covXf  = ws + 525312;
    float* xsq    = ws + 590848;
    float* post_w = ws + 691200;
    int*   post_idx = (int*)(ws + 695296);
    float* ck     = ws + 699392;
    int*   ci     = (int*)(ws + 3902464);
    // NS bf16 images overlay the ck region (ck fully consumed by merge before NS runs).
    unsigned short* YaH = (unsigned short*)(ws + 699392);
    unsigned short* YaL = (unsigned short*)(ws + 732160);
    unsigned short* ZaH = (unsigned short*)(ws + 764928);
    unsigned short* ZaL = (unsigned short*)(ws + 797696);
    unsigned short* YbH = (unsigned short*)(ws + 830464);
    unsigned short* YbL = (unsigned short*)(ws + 863232);
    unsigned short* ZbH = (unsigned short*)(ws + 896000);
    unsigned short* ZbL = (unsigned short*)(ws + 928768);   // ends 961536 < 3902464
    // bf16 trunc-split images (tier >= 1); XHs/XLs are LINEAR row-major now
    unsigned short* XHs = (unsigned short*)(ws + 7105536);   // 100352 x 256
    unsigned short* XLs = (unsigned short*)(ws + 19950592);
    unsigned short* TmH = (unsigned short*)(ws + 32795648);  // 256 x 256 row-major
    unsigned short* TmL = (unsigned short*)(ws + 32828416);
    // transposed image (tier 2)
    unsigned short* XTH = (unsigned short*)(ws + 32845824);  // 256 x 100352
    unsigned short* XTL = (unsigned short*)(ws + 45690880);
    const bool haveIMG = (ws_size >= (size_t)131444736);
    const bool haveXT  = (ws_size >= (size_t)234143744);

    // 0. zero accumulators
    zero_kernel<<<260, 256, 0, stream>>>(ws);
    reg_kernel<<<64, 256, 0, stream>>>(W, scal);
    // 1. X stats (+ bf16 image)
    statsx_kernel<<<784, 256, 0, stream>>>(X, xsq, mu_sum,
                                           haveIMG ? XHs : nullptr, haveIMG ? XLs : nullptr);
    // 2. covX accumulate
    if (haveXT) {
        xtk_kernel<<<392, 256, 0, stream>>>(XHs, XLs, XTH, XTL);
        covx2_kernel<<<dim3(4, NZ2), 256, 0, stream>>>(XTH, XTL, covX);
    } else {
        covx_kernel<<<dim3(4, 4, KSPLIT), 256, 0, stream>>>(X, covX);
    }
    covxfin2_kernel<<<256, 256, 0, stream>>>(covX, mu_sum, covXf, scal);
    // 3. T = q_batch @ W (+ TmH/TmL)
    mm32_kernel<<<dim3(8, 8, 1), 256, 0, stream>>>(q_batch, W, Tm, nullptr,
                                                   nullptr, nullptr,
                                                   haveIMG ? (float*)TmH : nullptr,
                                                   haveIMG ? (float*)TmL : nullptr, 0, nullptr, scal);
    // 4. T stats
    tstats_kernel<<<1, 256, 0, stream>>>(Tm, mu_sum, mu_T, scal);
    // 5. cov = T^T T /256 - muT muT^T + dI
    mm32_kernel<<<dim3(8, 8, 1), 256, 0, stream>>>(Tm, Tm, cov, nullptr,
                                                   nullptr, nullptr, nullptr, nullptr, 2, mu_T, scal);
    // 6. G = cov @ covXf (+frobenius)
    mm32_kernel<<<dim3(8, 8, 1), 256, 0, stream>>>(cov, covXf, G, nullptr,
                                                   nullptr, nullptr, nullptr, nullptr, 1, nullptr, scal);
    // 7. KNN chain (runs before NS so the NS images can overlay ck)
    if (haveIMG) {
        knn3_kernel<<<NPCH, 256, 0, stream>>>(TmH, TmL, XHs, XLs, xsq, ck, ci);
        merge2_kernel<<<256, 256, 0, stream>>>(ck, ci, post_idx);
    } else {
        knn_kernel<<<dim3(NPCH, 2, 1), 512, 0, stream>>>(Tm, X, xsq, ck, ci);
        merge_kernel<<<256, 256, 0, stream>>>(ck, ci, post_idx);
    }
    l2sm_kernel<<<256, 256, 0, stream>>>(Tm, X, post_idx, post_w);
    kl_kernel<<<1, 256, 0, stream>>>(q_indices, pre_indices, pre_weights, post_idx, post_w, scal);
    // 8. Newton-Schulz (fused: one launch per iteration, 32 blocks)
    inityz2_kernel<<<256, 256, 0, stream>>>(G, scal, Ya, Za, YaH, YaL, ZaH, ZaL);
    {
        float *Yc = Ya, *Zc = Za, *Yn = Yb, *Zn = Zb;
        unsigned short *cYH = YaH, *cYL = YaL, *cZH = ZaH, *cZL = ZaL;
        unsigned short *nYH = YbH, *nYL = YbL, *nZH = ZbH, *nZL = ZbL;
        for (int it = 0; it < NS_ITERS; ++it) {
            nsfused_kernel<<<dim3(16, 2), 256, 0, stream>>>(Yc, Zc, cYH, cYL, cZH, cZL,
                                                            Yn, Zn, nYH, nYL, nZH, nZL);
            float* tf;
            tf = Yc; Yc = Yn; Yn = tf;
            tf = Zc; Zc = Zn; Zn = tf;
            unsigned short* tu;
            tu = cYH; cYH = nYH; nYH = tu;
            tu = cYL; cYL = nYL; nYL = tu;
            tu = cZH; cZH = nZH; nZH = tu;
            tu = cZL; cZL = nZL; nZL = tu;
        }
        findist_kernel<<<1, 256, 0, stream>>>(Yc, scal);
    }
    // 9. assemble
    assemble_kernel<<<1, 64, 0, stream>>>(scal, out);
}